// Round 4
// baseline (49404.688 us; speedup 1.0000x reference)
//
#include <hip/hip_runtime.h>
#include <stdint.h>

#define NN 30000
#define NE 480000
#define HID 128
#define NG 128
#define NC 6
#define BN_EPS 1e-5f

typedef unsigned int u32;
typedef unsigned long long u64;

// ---------------- init ----------------
__global__ void k_init(const int* __restrict__ ei, int* srcA, int* dstA, int* nvb,
                       int* scal, int* b3) {
  int t = blockIdx.x * 256 + threadIdx.x;
  if (t < NE) { srcA[t] = ei[t]; dstA[t] = ei[NE + t]; }
  if (t < NN) nvb[t] = 1;
  if (t < 2 * NN) b3[t] = 0;            // bcount, bcursor
  if (t == 0) { scal[0] = NE; scal[1] = 0; }
}

// ---------------- CSR build (by dst) + valid-node count ----------------
__global__ void k_csr_count(const int* __restrict__ pE, const int* __restrict__ dst,
                            int* __restrict__ cnt, const int* __restrict__ nvb,
                            int* __restrict__ pcnt) {
  int t = blockIdx.x * 256 + threadIdx.x;
  if (t < NN && nvb[t]) atomicAdd(pcnt, 1);
  if (t < *pE) atomicAdd(&cnt[dst[t]], 1);
}

__global__ void k_csr_scatter(const int* __restrict__ pE, const int* __restrict__ dst,
                              const int* __restrict__ coff, int* __restrict__ cursor,
                              int* __restrict__ eids) {
  int e = blockIdx.x * 256 + threadIdx.x;
  if (e >= *pE) return;
  int d = dst[e];
  int pos = coff[d] + atomicAdd(&cursor[d], 1);
  eids[pos] = e;
}

// ---------------- SAGE mean aggregation: CSR gather, 32 lanes/node ----------------
__global__ __launch_bounds__(256) void k_sage_gather(
    const int* __restrict__ coff, const int* __restrict__ eids,
    const int* __restrict__ src, const float* __restrict__ x,
    float* __restrict__ mean) {
  int grp = threadIdx.x >> 5;           // 8 nodes per block
  int lane = threadIdx.x & 31;
  int n = blockIdx.x * 8 + grp;
  if (n >= NN) return;
  int b = coff[n], e2 = coff[n + 1];
  float4 acc = make_float4(0.f, 0.f, 0.f, 0.f);
  for (int i = b; i < e2; i++) {
    int s = src[eids[i]];
    float4 v = *(const float4*)(x + (size_t)s * HID + lane * 4);
    acc.x += v.x; acc.y += v.y; acc.z += v.z; acc.w += v.w;
  }
  float inv = 1.0f / fmaxf((float)(e2 - b), 1.0f);
  acc.x *= inv; acc.y *= inv; acc.z *= inv; acc.w *= inv;
  *(float4*)(mean + (size_t)n * HID + lane * 4) = acc;
}

// out[n][j] = A1@W1^T + A2@W2^T + bias; optional relu. Also zeroes bnsum (block 0).
__global__ __launch_bounds__(256) void gemm_dual(
    const float* __restrict__ A1, const float* __restrict__ W1,
    const float* __restrict__ A2, const float* __restrict__ W2,
    const float* __restrict__ bias, float* __restrict__ out,
    int M, int ldw, int relu, double* __restrict__ bnsum) {
  if (blockIdx.x == 0 && threadIdx.x < 2 * HID) bnsum[threadIdx.x] = 0.0;
  __shared__ float As[64][33];
  __shared__ float Ws[32][132];  // transposed: Ws[kk][j]
  int row0 = blockIdx.x * 64;
  int tid = threadIdx.x;
  int cid = tid & 31;
  int rid = tid >> 5;
  float acc[8][4];
#pragma unroll
  for (int r = 0; r < 8; r++)
#pragma unroll
    for (int c = 0; c < 4; c++) acc[r][c] = 0.f;

  for (int srcI = 0; srcI < 2; ++srcI) {
    const float* A = srcI ? A2 : A1;
    const float* W = srcI ? W2 : W1;
    for (int kc = 0; kc < 128; kc += 32) {
#pragma unroll
      for (int i = 0; i < 2; ++i) {
        int idx = tid + i * 256;
        int r = idx >> 3;
        int c4 = (idx & 7) << 2;
        int gr = row0 + r;
        float4 v = make_float4(0.f, 0.f, 0.f, 0.f);
        if (gr < M) v = *(const float4*)(A + (size_t)gr * 128 + kc + c4);
        As[r][c4 + 0] = v.x; As[r][c4 + 1] = v.y; As[r][c4 + 2] = v.z; As[r][c4 + 3] = v.w;
      }
#pragma unroll
      for (int i = 0; i < 4; ++i) {
        int idx = tid + i * 256;
        int j = idx >> 3;
        int c4 = (idx & 7) << 2;
        float4 v = *(const float4*)(W + (size_t)j * ldw + kc + c4);
        Ws[c4 + 0][j] = v.x; Ws[c4 + 1][j] = v.y; Ws[c4 + 2][j] = v.z; Ws[c4 + 3][j] = v.w;
      }
      __syncthreads();
#pragma unroll
      for (int kk = 0; kk < 32; ++kk) {
        float4 w = *(const float4*)(&Ws[kk][cid * 4]);
#pragma unroll
        for (int r = 0; r < 8; ++r) {
          float a = As[rid * 8 + r][kk];
          acc[r][0] += a * w.x; acc[r][1] += a * w.y; acc[r][2] += a * w.z; acc[r][3] += a * w.w;
        }
      }
      __syncthreads();
    }
  }
#pragma unroll
  for (int r = 0; r < 8; ++r) {
    int gr = row0 + rid * 8 + r;
    if (gr >= M) continue;
#pragma unroll
    for (int c = 0; c < 4; ++c) {
      float v = acc[r][c] + bias[cid * 4 + c];
      if (relu) v = fmaxf(v, 0.f);
      out[(size_t)gr * 128 + cid * 4 + c] = v;
    }
  }
}

__global__ __launch_bounds__(128) void k_bn_stats(const float* __restrict__ x,
                                                  const int* __restrict__ nvb,
                                                  double* __restrict__ sums) {
  int k = threadIdx.x;
  int n0 = blockIdx.x * 128;
  float s = 0.f, q = 0.f;
  for (int r = 0; r < 128; r++) {
    int n = n0 + r;
    if (n >= NN) break;
    if (!nvb[n]) continue;
    float v = x[(size_t)n * HID + k];
    s += v; q += v * v;
  }
  atomicAdd(&sums[k], (double)s);
  atomicAdd(&sums[HID + k], (double)q);
}

__global__ void k_bn_apply(float* __restrict__ x, const double* __restrict__ sums,
                           const int* __restrict__ cnt, const float* __restrict__ gamma,
                           const float* __restrict__ beta) {
  int t = blockIdx.x * 256 + threadIdx.x;
  if (t >= NN * HID) return;
  int k = t & 127;
  double c = (double)((*cnt > 1) ? *cnt : 1);
  double mu = sums[k] / c;
  double var = sums[HID + k] / c - mu * mu;
  if (var < 0.0) var = 0.0;
  float inv = (float)(1.0 / sqrt(var + (double)BN_EPS));
  x[t] = gamma[k] * (x[t] - (float)mu) * inv + beta[k];
}

// ---------------- edge pool ----------------
__global__ void k_node_proj(const float* __restrict__ x, const float* __restrict__ Wp,
                            float* __restrict__ px1, float* __restrict__ px2,
                            int* __restrict__ wcount) {
  int n = blockIdx.x * 256 + threadIdx.x;
  if (blockIdx.x == 0 && threadIdx.x < 2) wcount[threadIdx.x] = 0;
  if (n >= NN) return;
  const float* xr = x + (size_t)n * HID;
  float s1 = 0.f, s2 = 0.f;
#pragma unroll 8
  for (int k = 0; k < HID; k += 4) {
    float4 v = *(const float4*)(xr + k);
    float4 w1 = *(const float4*)(Wp + k);
    float4 w2 = *(const float4*)(Wp + HID + k);
    s1 += v.x * w1.x + v.y * w1.y + v.z * w1.z + v.w * w1.w;
    s2 += v.x * w2.x + v.y * w2.y + v.z * w2.z + v.w * w2.w;
  }
  px1[n] = s1; px2[n] = s2;
}

// fused: pool state init + per-dst softmax + worklist seed
__global__ void k_edge_softmax_seed(
    const int* __restrict__ coff, const int* __restrict__ eids,
    const int* __restrict__ src, const float* __restrict__ px1,
    const float* __restrict__ px2, const float* __restrict__ bp,
    float* __restrict__ score, const int* __restrict__ nvb,
    int* __restrict__ matched, int* __restrict__ cluster, int* __restrict__ chosen,
    u64* __restrict__ top, int* __restrict__ wl0, int* __restrict__ wcount) {
  int n = blockIdx.x * 256 + threadIdx.x;
  if (n >= NN) return;
  matched[n] = nvb[n] ? 0 : 1;
  cluster[n] = n;
  chosen[n] = -1;
  top[n] = 0ull;
  int b = coff[n], e2 = coff[n + 1];
  if (b == e2) return;
  float p2 = px2[n] + *bp;
  float mx = -3.4e38f;
  for (int i = b; i < e2; i++) {
    float r = px1[src[eids[i]]] + p2;
    mx = fmaxf(mx, r);
  }
  double den = 0.0;
  for (int i = b; i < e2; i++) {
    int eid = eids[i];
    float z = expf(px1[src[eid]] + p2 - mx);
    score[eid] = z;
    den += (double)z;
  }
  if (den < 1e-16) den = 1e-16;
  double invd = 1.0 / den;
  for (int i = b; i < e2; i++) {
    int eid = eids[i];
    score[eid] = (float)((double)score[eid] * invd) + 0.5f;
    if (src[eid] != n) {
      int idx = atomicAdd(&wcount[0], 1);
      wl0[idx] = eid;
    }
  }
}

__device__ __forceinline__ u64 make_key(int r, float sc, int e) {
  return ((u64)(r + 1) << 51) | ((u64)__float_as_uint(sc) << 19) | (u64)(0x7FFFFu - (u32)e);
}

// propose: scan worklist, drop dead edges, atomicMax keys, append survivors
__global__ void k_match_a(int r, const int* __restrict__ src, const int* __restrict__ dst,
                          const float* __restrict__ score, const int* __restrict__ matched,
                          u64* __restrict__ top, const int* __restrict__ cntIn,
                          const int* __restrict__ wlIn, int* __restrict__ cntOut,
                          int* __restrict__ wlOut) {
  int cnt = *cntIn;
  for (int i = blockIdx.x * blockDim.x + threadIdx.x; i < cnt; i += gridDim.x * blockDim.x) {
    int e = wlIn[i];
    int s = src[e], d = dst[e];
    if (matched[s] | matched[d]) continue;
    u64 key = make_key(r, score[e], e);
    atomicMax(&top[s], key);
    atomicMax(&top[d], key);
    int idx = atomicAdd(cntOut, 1);
    wlOut[idx] = e;
  }
}

// resolve winners among proposers; zero the spent counter for reuse next round
__global__ void k_match_b(int r, const int* __restrict__ src, const int* __restrict__ dst,
                          const float* __restrict__ score, int* __restrict__ matched,
                          int* __restrict__ cluster, int* __restrict__ chosen,
                          const u64* __restrict__ top, const int* __restrict__ cntProp,
                          const int* __restrict__ wlProp, int* __restrict__ cntZero) {
  if (blockIdx.x == 0 && threadIdx.x == 0) *cntZero = 0;
  int cnt = *cntProp;
  for (int i = blockIdx.x * blockDim.x + threadIdx.x; i < cnt; i += gridDim.x * blockDim.x) {
    int e = wlProp[i];
    int s = src[e], d = dst[e];
    u64 key = make_key(r, score[e], e);
    if (top[s] == key && top[d] == key) {
      matched[s] = 1; matched[d] = 1;
      int rep = s < d ? s : d;
      int oth = s < d ? d : s;
      cluster[oth] = rep;
      chosen[rep] = e;
    }
  }
}

// single-block tail: loops remaining rounds with __syncthreads as the barrier.
// atomics bypass L1, so top/matched reads use agent-scope atomic loads.
__global__ __launch_bounds__(1024) void k_match_finish(
    const int* __restrict__ src, const int* __restrict__ dst,
    const float* __restrict__ score, int* __restrict__ matched,
    int* __restrict__ cluster, int* __restrict__ chosen, u64* __restrict__ top,
    int* __restrict__ wl0, int* __restrict__ wl1, int* __restrict__ wcount,
    int baseRound) {
  for (int r = baseRound; r < baseRound + 56; r++) {
    int p = r & 1;
    __syncthreads();
    int cnt = __hip_atomic_load(&wcount[p], __ATOMIC_RELAXED, __HIP_MEMORY_SCOPE_AGENT);
    if (cnt == 0) break;
    if (threadIdx.x == 0) wcount[p ^ 1] = 0;
    __syncthreads();
    const int* wlIn = p ? wl1 : wl0;
    int* wlOut = p ? wl0 : wl1;
    for (int i = threadIdx.x; i < cnt; i += 1024) {
      int e = wlIn[i];
      int s = src[e], d = dst[e];
      int ms = __hip_atomic_load(&matched[s], __ATOMIC_RELAXED, __HIP_MEMORY_SCOPE_AGENT);
      int md = __hip_atomic_load(&matched[d], __ATOMIC_RELAXED, __HIP_MEMORY_SCOPE_AGENT);
      if (ms | md) continue;
      u64 key = make_key(r, score[e], e);
      atomicMax(&top[s], key);
      atomicMax(&top[d], key);
      int idx = atomicAdd(&wcount[p ^ 1], 1);
      wlOut[idx] = e;
    }
    __syncthreads();
    int ncnt = __hip_atomic_load(&wcount[p ^ 1], __ATOMIC_RELAXED, __HIP_MEMORY_SCOPE_AGENT);
    for (int i = threadIdx.x; i < ncnt; i += 1024) {
      int e = wlOut[i];
      int s = src[e], d = dst[e];
      u64 key = make_key(r, score[e], e);
      u64 ts = __hip_atomic_load(&top[s], __ATOMIC_RELAXED, __HIP_MEMORY_SCOPE_AGENT);
      u64 td = __hip_atomic_load(&top[d], __ATOMIC_RELAXED, __HIP_MEMORY_SCOPE_AGENT);
      if (ts == key && td == key) {
        __hip_atomic_store(&matched[s], 1, __ATOMIC_RELAXED, __HIP_MEMORY_SCOPE_AGENT);
        __hip_atomic_store(&matched[d], 1, __ATOMIC_RELAXED, __HIP_MEMORY_SCOPE_AGENT);
        int rep = s < d ? s : d;
        int oth = s < d ? d : s;
        cluster[oth] = rep;
        chosen[rep] = e;
      }
    }
    __syncthreads();
  }
}

// new_x gather (clusters have <=2 members) + nvb update + zero bcount/bcursor
__global__ __launch_bounds__(256) void k_new_x(
    const int* __restrict__ cluster, const int* __restrict__ chosen,
    const int* __restrict__ src, const int* __restrict__ dst,
    const float* __restrict__ score, const float* __restrict__ x,
    float* __restrict__ out, int* __restrict__ nvb, int* __restrict__ b3zero) {
  int gt = blockIdx.x * 256 + threadIdx.x;
  if (gt < 2 * NN) b3zero[gt] = 0;
  int grp = threadIdx.x >> 5;
  int lane = threadIdx.x & 31;
  int n = blockIdx.x * 8 + grp;
  if (n >= NN) return;
  float4 v = make_float4(0.f, 0.f, 0.f, 0.f);
  bool rep = (cluster[n] == n);
  if (rep) {
    v = *(const float4*)(x + (size_t)n * HID + lane * 4);
    int ch = chosen[n];
    if (ch >= 0) {
      int s = src[ch], d = dst[ch];
      int partner = (s == n) ? d : s;
      float4 w = *(const float4*)(x + (size_t)partner * HID + lane * 4);
      float sc = score[ch];
      v.x = (v.x + w.x) * sc; v.y = (v.y + w.y) * sc;
      v.z = (v.z + w.z) * sc; v.w = (v.w + w.w) * sc;
    }
  }
  *(float4*)(out + (size_t)n * HID + lane * 4) = v;
  if (lane == 0) nvb[n] = (nvb[n] && rep) ? 1 : 0;
}

// ---------------- dedup (sorted unique of (cs,cd)) ----------------
__global__ void k_bucket_count(const int* __restrict__ pE, const int* __restrict__ src,
                               const int* __restrict__ cluster, int* __restrict__ bcount) {
  int e = blockIdx.x * 256 + threadIdx.x;
  if (e >= *pE) return;
  atomicAdd(&bcount[cluster[src[e]]], 1);
}

__global__ __launch_bounds__(1024) void k_scan(const int* __restrict__ in, int* __restrict__ out,
                                               int n, int* totalDst) {
  __shared__ int part[1024];
  int t = threadIdx.x;
  int chunk = (n + 1023) / 1024;
  int b = t * chunk, e = b + chunk;
  if (b > n) b = n;
  if (e > n) e = n;
  int s = 0;
  for (int i = b; i < e; i++) s += in[i];
  part[t] = s;
  __syncthreads();
  for (int off = 1; off < 1024; off <<= 1) {
    int v = (t >= off) ? part[t - off] : 0;
    __syncthreads();
    part[t] += v;
    __syncthreads();
  }
  int excl = (t == 0) ? 0 : part[t - 1];
  int total = part[1023];
  for (int i = b; i < e; i++) { out[i] = excl; excl += in[i]; }
  if (t == 0) {
    out[n] = total;
    if (totalDst) *totalDst = total;
  }
}

__global__ void k_bucket_scatter(const int* __restrict__ pE, const int* __restrict__ src,
                                 const int* __restrict__ dst, const int* __restrict__ cluster,
                                 const int* __restrict__ boffs, int* __restrict__ bcursor,
                                 int* __restrict__ bucket) {
  int e = blockIdx.x * 256 + threadIdx.x;
  if (e >= *pE) return;
  int cs = cluster[src[e]], cd = cluster[dst[e]];
  int pos = boffs[cs] + atomicAdd(&bcursor[cs], 1);
  bucket[pos] = cd;
}

__global__ void k_sort_dedup(const int* __restrict__ boffs, int* __restrict__ bucket,
                             int* __restrict__ ucount) {
  int v = blockIdx.x * 256 + threadIdx.x;
  if (v >= NN) return;
  int b = boffs[v], e = boffs[v + 1];
  for (int i = b + 1; i < e; i++) {
    int key = bucket[i];
    int j = i - 1;
    while (j >= b && bucket[j] > key) { bucket[j + 1] = bucket[j]; j--; }
    bucket[j + 1] = key;
  }
  int u = 0, prev = -2147483648;
  for (int i = b; i < e; i++) {
    int x = bucket[i];
    if (x != prev) { bucket[b + u] = x; u++; prev = x; }
  }
  ucount[v] = u;
}

// emit compacted edges + zero bcount/bcursor/pcnt/gbuf for next phase
// NOTE: zeroing is grid-stride so coverage never depends on grid size
// (round-3 abort: 118-block launch left bcursor[30208..60000) stale -> OOB scatter).
__global__ void k_emit(const int* __restrict__ boffs, const int* __restrict__ bucket,
                       const int* __restrict__ bucount, const int* __restrict__ bnoffs,
                       int* __restrict__ srcO, int* __restrict__ dstO,
                       int* __restrict__ b3zero, int* __restrict__ pcnt,
                       float* __restrict__ gbuf) {
  int t = blockIdx.x * 256 + threadIdx.x;
  int stride = gridDim.x * 256;
  for (int z = t; z < 2 * NN; z += stride) b3zero[z] = 0;
  for (int z = t; z < NG * HID + NG; z += stride) gbuf[z] = 0.f;
  if (t == 0) *pcnt = 0;
  if (t >= NN) return;
  int u = bucount[t], b = boffs[t], o = bnoffs[t];
  for (int i = 0; i < u; i++) { srcO[o + i] = t; dstO[o + i] = bucket[b + i]; }
}

// ---------------- readout ----------------
__global__ void k_graph_pool(const int* __restrict__ nvb, const int* __restrict__ batch,
                             const float* __restrict__ x, float* __restrict__ gsum,
                             float* __restrict__ gcnt) {
  int t = blockIdx.x * 256 + threadIdx.x;
  int n = t >> 2;
  if (n >= NN) return;
  if (!nvb[n]) return;
  int sub = t & 3;
  int g = batch[n];
  const float* xr = x + (size_t)n * HID + sub * 32;
  float* o = gsum + (size_t)g * HID + sub * 32;
#pragma unroll
  for (int i = 0; i < 8; i++) {
    float4 v = *(const float4*)(xr + i * 4);
    atomicAdd(o + i * 4 + 0, v.x); atomicAdd(o + i * 4 + 1, v.y);
    atomicAdd(o + i * 4 + 2, v.z); atomicAdd(o + i * 4 + 3, v.w);
  }
  if (sub == 0) atomicAdd(&gcnt[g], 1.0f);
}

__global__ __launch_bounds__(128) void k_head1(const float* __restrict__ gsum,
                                               const float* __restrict__ gcnt,
                                               const float* __restrict__ Wf1,
                                               const float* __restrict__ bf1,
                                               float* __restrict__ hfc) {
  int g = blockIdx.x;
  int j = threadIdx.x;
  __shared__ float p[HID];
  float c = fmaxf(gcnt[g], 1.f);
  p[j] = gsum[g * HID + j] / c;
  __syncthreads();
  float s = bf1[j];
  const float* w = Wf1 + (size_t)j * HID;
  for (int k = 0; k < HID; k++) s += p[k] * w[k];
  hfc[g * HID + j] = fmaxf(s, 0.f);
}

__global__ void k_head2(const float* __restrict__ hfc, const float* __restrict__ Wf2,
                        const float* __restrict__ bf2, float* __restrict__ out) {
  int g = blockIdx.x;
  int t = threadIdx.x;
  __shared__ float lg[NC];
  if (t < NC) {
    float s = bf2[t];
    const float* w = Wf2 + (size_t)t * HID;
    const float* h = hfc + (size_t)g * HID;
    for (int k = 0; k < HID; k++) s += h[k] * w[k];
    lg[t] = s;
  }
  __syncthreads();
  if (t == 0) {
    float m = lg[0];
    for (int c = 1; c < NC; c++) m = fmaxf(m, lg[c]);
    float se = 0.f;
    for (int c = 0; c < NC; c++) se += expf(lg[c] - m);
    float lse = m + logf(se);
    for (int c = 0; c < NC; c++) out[g * NC + c] = lg[c] - lse;
  }
}

extern "C" void kernel_launch(void* const* d_in, const int* in_sizes, int n_in,
                              void* d_out, int out_size, void* d_ws, size_t ws_size,
                              hipStream_t stream) {
  const float* x0 = (const float*)d_in[0];
  const int* ei = (const int*)d_in[1];
  const int* batch = (const int*)d_in[2];
  const float* Wl = (const float*)d_in[3];
  const float* bl = (const float*)d_in[4];
  const float* Wr = (const float*)d_in[5];
  const float* gamma = (const float*)d_in[6];
  const float* beta = (const float*)d_in[7];
  const float* Wlin = (const float*)d_in[8];
  const float* blin = (const float*)d_in[9];
  const float* Wp = (const float*)d_in[10];
  const float* bp = (const float*)d_in[11];
  const float* Wf1 = (const float*)d_in[12];
  const float* bf1 = (const float*)d_in[13];
  const float* Wf2 = (const float*)d_in[14];
  const float* bf2 = (const float*)d_in[15];
  float* out = (float*)d_out;

  const int NH = NN * HID;
  size_t off = 0;
  char* base = (char*)d_ws;
  auto carve = [&](size_t bytes) -> char* {
    char* p = base + off;
    off += (bytes + 255) & ~(size_t)255;
    return p;
  };
  float* xa = (float*)carve((size_t)NH * 4);
  float* xb = (float*)carve((size_t)NH * 4);
  float* xc = (float*)carve((size_t)NH * 4);
  float* xd = (float*)carve((size_t)NH * 4);
  int* srcA = (int*)carve((size_t)NE * 4);
  int* dstA = (int*)carve((size_t)NE * 4);
  int* srcB = (int*)carve((size_t)NE * 4);
  int* dstB = (int*)carve((size_t)NE * 4);
  float* escore = (float*)carve((size_t)NE * 4);
  int* ebucket = (int*)carve((size_t)NE * 4);
  int* eids = (int*)carve((size_t)NE * 4);
  int* wl0 = (int*)carve((size_t)NE * 4);
  int* wl1 = (int*)carve((size_t)NE * 4);
  u64* ntop = (u64*)carve((size_t)NN * 8);
  float* npx1 = (float*)carve((size_t)NN * 4);
  float* npx2 = (float*)carve((size_t)NN * 4);
  int* ncluster = (int*)carve((size_t)NN * 4);
  int* nchosen = (int*)carve((size_t)NN * 4);
  int* nmatched = (int*)carve((size_t)NN * 4);
  int* nvb = (int*)carve((size_t)NN * 4);
  int* b3 = (int*)carve((size_t)3 * NN * 4);
  int* bcount = b3;
  int* bcursor = b3 + NN;
  int* bucount = b3 + 2 * NN;
  int* boffs = (int*)carve((size_t)(NN + 1) * 4);
  int* bnoffs = (int*)carve((size_t)(NN + 1) * 4);
  int* csroff = (int*)carve((size_t)(NN + 1) * 4);
  double* bnsum = (double*)carve((size_t)2 * HID * 8);
  float* gbuf = (float*)carve((size_t)(NG * HID + NG) * 4);
  float* gsum = gbuf;
  float* gcnt = gbuf + NG * HID;
  float* ghfc = (float*)carve((size_t)NG * HID * 4);
  int* scal = (int*)carve(64 * 4);
  (void)ws_size; (void)n_in; (void)in_sizes; (void)out_size;

  int* pE = scal;        // E_cur
  int* pcnt = scal + 1;  // valid node count
  int* wcount = scal + 2;  // worklist counts [2]

  hipMemcpyAsync(xa, x0, (size_t)NH * 4, hipMemcpyDeviceToDevice, stream);
  k_init<<<1875, 256, 0, stream>>>(ei, srcA, dstA, nvb, scal, b3);

  int* srcC = srcA; int* dstC = dstA; int* srcN = srcB; int* dstN = dstB;
  float* xcur = xa;
  float* xtmp = xd;

  auto sage = [&](const float* xin, float* xout, int L) {
    k_sage_gather<<<3750, 256, 0, stream>>>(csroff, eids, srcC, xin, xtmp);
    gemm_dual<<<469, 256, 0, stream>>>(xtmp, Wl + (size_t)L * HID * HID, xin,
                                       Wr + (size_t)L * HID * HID, bl + (size_t)L * HID,
                                       xout, NN, HID, 1, bnsum);
    k_bn_stats<<<235, 128, 0, stream>>>(xout, nvb, bnsum);
    k_bn_apply<<<15000, 256, 0, stream>>>(xout, bnsum, pcnt, gamma + (size_t)L * HID,
                                          beta + (size_t)L * HID);
  };

  for (int b = 0; b < 3; b++) {
    // CSR by dst (shared by both SAGE layers and edge softmax) + valid count
    k_csr_count<<<1875, 256, 0, stream>>>(pE, dstC, bcount, nvb, pcnt);
    k_scan<<<1, 1024, 0, stream>>>(bcount, csroff, NN, (int*)nullptr);
    k_csr_scatter<<<1875, 256, 0, stream>>>(pE, dstC, csroff, bcursor, eids);

    sage(xcur, xb, 2 * b);
    sage(xb, xc, 2 * b + 1);
    gemm_dual<<<469, 256, 0, stream>>>(xc, Wlin + (size_t)b * HID * 2 * HID, xb,
                                       Wlin + (size_t)b * HID * 2 * HID + HID,
                                       blin + (size_t)b * HID, xcur, NN, 2 * HID, 0, bnsum);

    // ----- edge pooling -----
    k_node_proj<<<118, 256, 0, stream>>>(xcur, Wp + (size_t)b * 2 * HID, npx1, npx2, wcount);
    k_edge_softmax_seed<<<118, 256, 0, stream>>>(csroff, eids, srcC, npx1, npx2, bp + b,
                                                 escore, nvb, nmatched, ncluster, nchosen,
                                                 ntop, wl0, wcount);
    for (int r = 0; r < 8; r++) {
      int p = r & 1;
      int* wlIn = p ? wl1 : wl0;
      int* wlOut = p ? wl0 : wl1;
      k_match_a<<<512, 256, 0, stream>>>(r, srcC, dstC, escore, nmatched, ntop,
                                         wcount + p, wlIn, wcount + (p ^ 1), wlOut);
      k_match_b<<<512, 256, 0, stream>>>(r, srcC, dstC, escore, nmatched, ncluster, nchosen,
                                         ntop, wcount + (p ^ 1), wlOut, wcount + p);
    }
    k_match_finish<<<1, 1024, 0, stream>>>(srcC, dstC, escore, nmatched, ncluster, nchosen,
                                           ntop, wl0, wl1, wcount, 8);
    k_new_x<<<3750, 256, 0, stream>>>(ncluster, nchosen, srcC, dstC, escore, xcur, xtmp,
                                      nvb, b3);

    k_bucket_count<<<1875, 256, 0, stream>>>(pE, srcC, ncluster, bcount);
    k_scan<<<1, 1024, 0, stream>>>(bcount, boffs, NN, (int*)nullptr);
    k_bucket_scatter<<<1875, 256, 0, stream>>>(pE, srcC, dstC, ncluster, boffs, bcursor, ebucket);
    k_sort_dedup<<<118, 256, 0, stream>>>(boffs, ebucket, bucount);
    k_scan<<<1, 1024, 0, stream>>>(bucount, bnoffs, NN, pE);
    k_emit<<<235, 256, 0, stream>>>(boffs, ebucket, bucount, bnoffs, srcN, dstN,
                                    b3, pcnt, gbuf);

    { int* t = srcC; srcC = srcN; srcN = t; t = dstC; dstC = dstN; dstN = t; }
    { float* t = xcur; xcur = xtmp; xtmp = t; }
  }

  k_graph_pool<<<469, 256, 0, stream>>>(nvb, batch, xcur, gsum, gcnt);
  k_head1<<<NG, 128, 0, stream>>>(gsum, gcnt, Wf1, bf1, ghfc);
  k_head2<<<NG, 32, 0, stream>>>(ghfc, Wf2, bf2, out);
}

// Round 5
// 18044.823 us; speedup vs baseline: 2.7379x; 2.7379x over previous
//
#include <hip/hip_runtime.h>
#include <stdint.h>

#define NN 30000
#define NE 480000
#define HID 128
#define NG 128
#define NC 6
#define BN_EPS 1e-5f
#define MBLK 256   // persistent matcher blocks: 1/CU, co-residency guaranteed

typedef unsigned int u32;
typedef unsigned long long u64;

// ---------------- init ----------------
__global__ void k_init(const int* __restrict__ ei, int* srcA, int* dstA, int* nvb,
                       int* scal, int* b3) {
  int t = blockIdx.x * 256 + threadIdx.x;
  if (t < NE) { srcA[t] = ei[t]; dstA[t] = ei[NE + t]; }
  if (t < NN) nvb[t] = 1;
  if (t < 2 * NN) b3[t] = 0;            // bcount, bcursor
  if (t == 0) { scal[0] = NE; scal[1] = 0; }
}

// ---------------- CSR build (by dst) + valid-node count ----------------
__global__ void k_csr_count(const int* __restrict__ pE, const int* __restrict__ dst,
                            int* __restrict__ cnt, const int* __restrict__ nvb,
                            int* __restrict__ pcnt) {
  int t = blockIdx.x * 256 + threadIdx.x;
  if (t < NN && nvb[t]) atomicAdd(pcnt, 1);
  if (t < *pE) atomicAdd(&cnt[dst[t]], 1);
}

__global__ void k_csr_scatter(const int* __restrict__ pE, const int* __restrict__ dst,
                              const int* __restrict__ coff, int* __restrict__ cursor,
                              int* __restrict__ eids) {
  int e = blockIdx.x * 256 + threadIdx.x;
  if (e >= *pE) return;
  int d = dst[e];
  int pos = coff[d] + atomicAdd(&cursor[d], 1);
  eids[pos] = e;
}

// ---------------- SAGE mean aggregation: CSR gather, 32 lanes/node ----------------
__global__ __launch_bounds__(256) void k_sage_gather(
    const int* __restrict__ coff, const int* __restrict__ eids,
    const int* __restrict__ src, const float* __restrict__ x,
    float* __restrict__ mean) {
  int grp = threadIdx.x >> 5;           // 8 nodes per block
  int lane = threadIdx.x & 31;
  int n = blockIdx.x * 8 + grp;
  if (n >= NN) return;
  int b = coff[n], e2 = coff[n + 1];
  float4 acc = make_float4(0.f, 0.f, 0.f, 0.f);
  for (int i = b; i < e2; i++) {
    int s = src[eids[i]];
    float4 v = *(const float4*)(x + (size_t)s * HID + lane * 4);
    acc.x += v.x; acc.y += v.y; acc.z += v.z; acc.w += v.w;
  }
  float inv = 1.0f / fmaxf((float)(e2 - b), 1.0f);
  acc.x *= inv; acc.y *= inv; acc.z *= inv; acc.w *= inv;
  *(float4*)(mean + (size_t)n * HID + lane * 4) = acc;
}

// out[n][j] = A1@W1^T + A2@W2^T + bias; optional relu. Also zeroes bnsum (block 0).
__global__ __launch_bounds__(256) void gemm_dual(
    const float* __restrict__ A1, const float* __restrict__ W1,
    const float* __restrict__ A2, const float* __restrict__ W2,
    const float* __restrict__ bias, float* __restrict__ out,
    int M, int ldw, int relu, double* __restrict__ bnsum) {
  if (blockIdx.x == 0 && threadIdx.x < 2 * HID) bnsum[threadIdx.x] = 0.0;
  __shared__ float As[64][33];
  __shared__ float Ws[32][132];  // transposed: Ws[kk][j]
  int row0 = blockIdx.x * 64;
  int tid = threadIdx.x;
  int cid = tid & 31;
  int rid = tid >> 5;
  float acc[8][4];
#pragma unroll
  for (int r = 0; r < 8; r++)
#pragma unroll
    for (int c = 0; c < 4; c++) acc[r][c] = 0.f;

  for (int srcI = 0; srcI < 2; ++srcI) {
    const float* A = srcI ? A2 : A1;
    const float* W = srcI ? W2 : W1;
    for (int kc = 0; kc < 128; kc += 32) {
#pragma unroll
      for (int i = 0; i < 2; ++i) {
        int idx = tid + i * 256;
        int r = idx >> 3;
        int c4 = (idx & 7) << 2;
        int gr = row0 + r;
        float4 v = make_float4(0.f, 0.f, 0.f, 0.f);
        if (gr < M) v = *(const float4*)(A + (size_t)gr * 128 + kc + c4);
        As[r][c4 + 0] = v.x; As[r][c4 + 1] = v.y; As[r][c4 + 2] = v.z; As[r][c4 + 3] = v.w;
      }
#pragma unroll
      for (int i = 0; i < 4; ++i) {
        int idx = tid + i * 256;
        int j = idx >> 3;
        int c4 = (idx & 7) << 2;
        float4 v = *(const float4*)(W + (size_t)j * ldw + kc + c4);
        Ws[c4 + 0][j] = v.x; Ws[c4 + 1][j] = v.y; Ws[c4 + 2][j] = v.z; Ws[c4 + 3][j] = v.w;
      }
      __syncthreads();
#pragma unroll
      for (int kk = 0; kk < 32; ++kk) {
        float4 w = *(const float4*)(&Ws[kk][cid * 4]);
#pragma unroll
        for (int r = 0; r < 8; ++r) {
          float a = As[rid * 8 + r][kk];
          acc[r][0] += a * w.x; acc[r][1] += a * w.y; acc[r][2] += a * w.z; acc[r][3] += a * w.w;
        }
      }
      __syncthreads();
    }
  }
#pragma unroll
  for (int r = 0; r < 8; ++r) {
    int gr = row0 + rid * 8 + r;
    if (gr >= M) continue;
#pragma unroll
    for (int c = 0; c < 4; ++c) {
      float v = acc[r][c] + bias[cid * 4 + c];
      if (relu) v = fmaxf(v, 0.f);
      out[(size_t)gr * 128 + cid * 4 + c] = v;
    }
  }
}

__global__ __launch_bounds__(128) void k_bn_stats(const float* __restrict__ x,
                                                  const int* __restrict__ nvb,
                                                  double* __restrict__ sums) {
  int k = threadIdx.x;
  int n0 = blockIdx.x * 64;
  float s = 0.f, q = 0.f;
  for (int r = 0; r < 64; r++) {
    int n = n0 + r;
    if (n >= NN) break;
    if (!nvb[n]) continue;
    float v = x[(size_t)n * HID + k];
    s += v; q += v * v;
  }
  atomicAdd(&sums[k], (double)s);
  atomicAdd(&sums[HID + k], (double)q);
}

__global__ void k_bn_apply(float* __restrict__ x, const double* __restrict__ sums,
                           const int* __restrict__ cnt, const float* __restrict__ gamma,
                           const float* __restrict__ beta) {
  int t = blockIdx.x * 256 + threadIdx.x;
  if (t >= NN * HID) return;
  int k = t & 127;
  double c = (double)((*cnt > 1) ? *cnt : 1);
  double mu = sums[k] / c;
  double var = sums[HID + k] / c - mu * mu;
  if (var < 0.0) var = 0.0;
  float inv = (float)(1.0 / sqrt(var + (double)BN_EPS));
  x[t] = gamma[k] * (x[t] - (float)mu) * inv + beta[k];
}

// ---------------- edge pool ----------------
// also zeroes wcount[0..1] and barrier state bar[0..1] (scal+2..5)
__global__ void k_node_proj(const float* __restrict__ x, const float* __restrict__ Wp,
                            float* __restrict__ px1, float* __restrict__ px2,
                            int* __restrict__ wcb) {
  int n = blockIdx.x * 256 + threadIdx.x;
  if (blockIdx.x == 0 && threadIdx.x < 4) wcb[threadIdx.x] = 0;
  if (n >= NN) return;
  const float* xr = x + (size_t)n * HID;
  float s1 = 0.f, s2 = 0.f;
#pragma unroll 8
  for (int k = 0; k < HID; k += 4) {
    float4 v = *(const float4*)(xr + k);
    float4 w1 = *(const float4*)(Wp + k);
    float4 w2 = *(const float4*)(Wp + HID + k);
    s1 += v.x * w1.x + v.y * w1.y + v.z * w1.z + v.w * w1.w;
    s2 += v.x * w2.x + v.y * w2.y + v.z * w2.z + v.w * w2.w;
  }
  px1[n] = s1; px2[n] = s2;
}

// fused: pool state init + per-dst softmax + worklist seed
__global__ void k_edge_softmax_seed(
    const int* __restrict__ coff, const int* __restrict__ eids,
    const int* __restrict__ src, const float* __restrict__ px1,
    const float* __restrict__ px2, const float* __restrict__ bp,
    float* __restrict__ score, const int* __restrict__ nvb,
    int* __restrict__ matched, int* __restrict__ cluster, int* __restrict__ chosen,
    u64* __restrict__ top, int* __restrict__ wl0, int* __restrict__ wcount) {
  int n = blockIdx.x * 256 + threadIdx.x;
  if (n >= NN) return;
  matched[n] = nvb[n] ? 0 : 1;
  cluster[n] = n;
  chosen[n] = -1;
  top[n] = 0ull;
  int b = coff[n], e2 = coff[n + 1];
  if (b == e2) return;
  float p2 = px2[n] + *bp;
  float mx = -3.4e38f;
  for (int i = b; i < e2; i++) {
    float r = px1[src[eids[i]]] + p2;
    mx = fmaxf(mx, r);
  }
  double den = 0.0;
  for (int i = b; i < e2; i++) {
    int eid = eids[i];
    float z = expf(px1[src[eid]] + p2 - mx);
    score[eid] = z;
    den += (double)z;
  }
  if (den < 1e-16) den = 1e-16;
  double invd = 1.0 / den;
  for (int i = b; i < e2; i++) {
    int eid = eids[i];
    score[eid] = (float)((double)score[eid] * invd) + 0.5f;
    if (src[eid] != n) {
      int idx = atomicAdd(&wcount[0], 1);
      wl0[idx] = eid;
    }
  }
}

__device__ __forceinline__ u64 make_key(int r, float sc, int e) {
  return ((u64)(r + 1) << 51) | ((u64)__float_as_uint(sc) << 19) | (u64)(0x7FFFFu - (u32)e);
}

// Persistent full-machine matcher. 256 blocks (1/CU) x 256 threads, all rounds
// inside one kernel with a sense-reversing device-scope barrier.
// Semantics identical to round-2's per-round kernels: phase A proposes
// (atomicMax round-tagged keys over alive worklist, compact survivors),
// phase B resolves locally-dominant winners. Exits when worklist empty.
__global__ __launch_bounds__(256) void k_match_persist(
    const int* __restrict__ src, const int* __restrict__ dst,
    const float* __restrict__ score, int* __restrict__ matched,
    int* __restrict__ cluster, int* __restrict__ chosen, u64* __restrict__ top,
    int* __restrict__ wl0, int* __restrict__ wl1, int* __restrict__ wcount,
    int* __restrict__ bar) {
  int gen = 0;
  auto gbar = [&]() {
    __syncthreads();
    if (threadIdx.x == 0) {
      __threadfence();  // release: flush our L2 writes to coherent point
      gen++;
      int arrived = __hip_atomic_fetch_add(&bar[0], 1, __ATOMIC_ACQ_REL,
                                           __HIP_MEMORY_SCOPE_AGENT);
      if (arrived == (int)gridDim.x - 1) {
        __hip_atomic_store(&bar[0], 0, __ATOMIC_RELAXED, __HIP_MEMORY_SCOPE_AGENT);
        __hip_atomic_store(&bar[1], gen, __ATOMIC_RELEASE, __HIP_MEMORY_SCOPE_AGENT);
      } else {
        while (__hip_atomic_load(&bar[1], __ATOMIC_ACQUIRE,
                                 __HIP_MEMORY_SCOPE_AGENT) < gen)
          __builtin_amdgcn_s_sleep(1);
      }
      __threadfence();  // acquire: invalidate stale local cache lines
    }
    __syncthreads();
  };

  for (int r = 0; r < 96; r++) {
    int p = r & 1;
    int cnt = __hip_atomic_load(&wcount[p], __ATOMIC_RELAXED, __HIP_MEMORY_SCOPE_AGENT);
    if (cnt == 0) break;  // uniform across blocks (read after common barrier)
    const int* wlIn = p ? wl1 : wl0;
    int* wlOut = p ? wl0 : wl1;
    // phase A: drop dead edges, propose survivors
    for (int i = blockIdx.x * 256 + threadIdx.x; i < cnt; i += gridDim.x * 256) {
      int e = wlIn[i];
      int s = src[e], d = dst[e];
      if (matched[s] | matched[d]) continue;
      u64 key = make_key(r, score[e], e);
      atomicMax(&top[s], key);
      atomicMax(&top[d], key);
      int idx = atomicAdd(&wcount[p ^ 1], 1);
      wlOut[idx] = e;
    }
    gbar();
    // phase B: resolve locally-dominant winners
    int ncnt = __hip_atomic_load(&wcount[p ^ 1], __ATOMIC_RELAXED, __HIP_MEMORY_SCOPE_AGENT);
    for (int i = blockIdx.x * 256 + threadIdx.x; i < ncnt; i += gridDim.x * 256) {
      int e = wlOut[i];
      int s = src[e], d = dst[e];
      u64 key = make_key(r, score[e], e);
      if (top[s] == key && top[d] == key) {
        matched[s] = 1; matched[d] = 1;
        int rep = s < d ? s : d;
        int oth = s < d ? d : s;
        cluster[oth] = rep;
        chosen[rep] = e;
      }
    }
    if (blockIdx.x == 0 && threadIdx.x == 0)
      __hip_atomic_store(&wcount[p], 0, __ATOMIC_RELAXED, __HIP_MEMORY_SCOPE_AGENT);
    gbar();
  }
}

// new_x gather (clusters have <=2 members) + nvb update + zero bcount/bcursor
__global__ __launch_bounds__(256) void k_new_x(
    const int* __restrict__ cluster, const int* __restrict__ chosen,
    const int* __restrict__ src, const int* __restrict__ dst,
    const float* __restrict__ score, const float* __restrict__ x,
    float* __restrict__ out, int* __restrict__ nvb, int* __restrict__ b3zero) {
  int gt = blockIdx.x * 256 + threadIdx.x;
  if (gt < 2 * NN) b3zero[gt] = 0;
  int grp = threadIdx.x >> 5;
  int lane = threadIdx.x & 31;
  int n = blockIdx.x * 8 + grp;
  if (n >= NN) return;
  float4 v = make_float4(0.f, 0.f, 0.f, 0.f);
  bool rep = (cluster[n] == n);
  if (rep) {
    v = *(const float4*)(x + (size_t)n * HID + lane * 4);
    int ch = chosen[n];
    if (ch >= 0) {
      int s = src[ch], d = dst[ch];
      int partner = (s == n) ? d : s;
      float4 w = *(const float4*)(x + (size_t)partner * HID + lane * 4);
      float sc = score[ch];
      v.x = (v.x + w.x) * sc; v.y = (v.y + w.y) * sc;
      v.z = (v.z + w.z) * sc; v.w = (v.w + w.w) * sc;
    }
  }
  *(float4*)(out + (size_t)n * HID + lane * 4) = v;
  if (lane == 0) nvb[n] = (nvb[n] && rep) ? 1 : 0;
}

// ---------------- dedup (sorted unique of (cs,cd)) ----------------
__global__ void k_bucket_count(const int* __restrict__ pE, const int* __restrict__ src,
                               const int* __restrict__ cluster, int* __restrict__ bcount) {
  int e = blockIdx.x * 256 + threadIdx.x;
  if (e >= *pE) return;
  atomicAdd(&bcount[cluster[src[e]]], 1);
}

__global__ __launch_bounds__(1024) void k_scan(const int* __restrict__ in, int* __restrict__ out,
                                               int n, int* totalDst) {
  __shared__ int part[1024];
  int t = threadIdx.x;
  int chunk = (n + 1023) / 1024;
  int b = t * chunk, e = b + chunk;
  if (b > n) b = n;
  if (e > n) e = n;
  int s = 0;
  for (int i = b; i < e; i++) s += in[i];
  part[t] = s;
  __syncthreads();
  for (int off = 1; off < 1024; off <<= 1) {
    int v = (t >= off) ? part[t - off] : 0;
    __syncthreads();
    part[t] += v;
    __syncthreads();
  }
  int excl = (t == 0) ? 0 : part[t - 1];
  int total = part[1023];
  for (int i = b; i < e; i++) { out[i] = excl; excl += in[i]; }
  if (t == 0) {
    out[n] = total;
    if (totalDst) *totalDst = total;
  }
}

__global__ void k_bucket_scatter(const int* __restrict__ pE, const int* __restrict__ src,
                                 const int* __restrict__ dst, const int* __restrict__ cluster,
                                 const int* __restrict__ boffs, int* __restrict__ bcursor,
                                 int* __restrict__ bucket) {
  int e = blockIdx.x * 256 + threadIdx.x;
  if (e >= *pE) return;
  int cs = cluster[src[e]], cd = cluster[dst[e]];
  int pos = boffs[cs] + atomicAdd(&bcursor[cs], 1);
  bucket[pos] = cd;
}

__global__ void k_sort_dedup(const int* __restrict__ boffs, int* __restrict__ bucket,
                             int* __restrict__ ucount) {
  int v = blockIdx.x * 256 + threadIdx.x;
  if (v >= NN) return;
  int b = boffs[v], e = boffs[v + 1];
  for (int i = b + 1; i < e; i++) {
    int key = bucket[i];
    int j = i - 1;
    while (j >= b && bucket[j] > key) { bucket[j + 1] = bucket[j]; j--; }
    bucket[j + 1] = key;
  }
  int u = 0, prev = -2147483648;
  for (int i = b; i < e; i++) {
    int x = bucket[i];
    if (x != prev) { bucket[b + u] = x; u++; prev = x; }
  }
  ucount[v] = u;
}

// emit compacted edges + zero bcount/bcursor/pcnt/gbuf for next phase
// (grid-stride zeroing so coverage never depends on grid size)
__global__ void k_emit(const int* __restrict__ boffs, const int* __restrict__ bucket,
                       const int* __restrict__ bucount, const int* __restrict__ bnoffs,
                       int* __restrict__ srcO, int* __restrict__ dstO,
                       int* __restrict__ b3zero, int* __restrict__ pcnt,
                       float* __restrict__ gbuf) {
  int t = blockIdx.x * 256 + threadIdx.x;
  int stride = gridDim.x * 256;
  for (int z = t; z < 2 * NN; z += stride) b3zero[z] = 0;
  for (int z = t; z < NG * HID + NG; z += stride) gbuf[z] = 0.f;
  if (t == 0) *pcnt = 0;
  if (t >= NN) return;
  int u = bucount[t], b = boffs[t], o = bnoffs[t];
  for (int i = 0; i < u; i++) { srcO[o + i] = t; dstO[o + i] = bucket[b + i]; }
}

// ---------------- readout ----------------
__global__ void k_graph_pool(const int* __restrict__ nvb, const int* __restrict__ batch,
                             const float* __restrict__ x, float* __restrict__ gsum,
                             float* __restrict__ gcnt) {
  int t = blockIdx.x * 256 + threadIdx.x;
  int n = t >> 2;
  if (n >= NN) return;
  if (!nvb[n]) return;
  int sub = t & 3;
  int g = batch[n];
  const float* xr = x + (size_t)n * HID + sub * 32;
  float* o = gsum + (size_t)g * HID + sub * 32;
#pragma unroll
  for (int i = 0; i < 8; i++) {
    float4 v = *(const float4*)(xr + i * 4);
    atomicAdd(o + i * 4 + 0, v.x); atomicAdd(o + i * 4 + 1, v.y);
    atomicAdd(o + i * 4 + 2, v.z); atomicAdd(o + i * 4 + 3, v.w);
  }
  if (sub == 0) atomicAdd(&gcnt[g], 1.0f);
}

__global__ __launch_bounds__(128) void k_head1(const float* __restrict__ gsum,
                                               const float* __restrict__ gcnt,
                                               const float* __restrict__ Wf1,
                                               const float* __restrict__ bf1,
                                               float* __restrict__ hfc) {
  int g = blockIdx.x;
  int j = threadIdx.x;
  __shared__ float p[HID];
  float c = fmaxf(gcnt[g], 1.f);
  p[j] = gsum[g * HID + j] / c;
  __syncthreads();
  float s = bf1[j];
  const float* w = Wf1 + (size_t)j * HID;
  for (int k = 0; k < HID; k++) s += p[k] * w[k];
  hfc[g * HID + j] = fmaxf(s, 0.f);
}

__global__ void k_head2(const float* __restrict__ hfc, const float* __restrict__ Wf2,
                        const float* __restrict__ bf2, float* __restrict__ out) {
  int g = blockIdx.x;
  int t = threadIdx.x;
  __shared__ float lg[NC];
  if (t < NC) {
    float s = bf2[t];
    const float* w = Wf2 + (size_t)t * HID;
    const float* h = hfc + (size_t)g * HID;
    for (int k = 0; k < HID; k++) s += h[k] * w[k];
    lg[t] = s;
  }
  __syncthreads();
  if (t == 0) {
    float m = lg[0];
    for (int c = 1; c < NC; c++) m = fmaxf(m, lg[c]);
    float se = 0.f;
    for (int c = 0; c < NC; c++) se += expf(lg[c] - m);
    float lse = m + logf(se);
    for (int c = 0; c < NC; c++) out[g * NC + c] = lg[c] - lse;
  }
}

extern "C" void kernel_launch(void* const* d_in, const int* in_sizes, int n_in,
                              void* d_out, int out_size, void* d_ws, size_t ws_size,
                              hipStream_t stream) {
  const float* x0 = (const float*)d_in[0];
  const int* ei = (const int*)d_in[1];
  const int* batch = (const int*)d_in[2];
  const float* Wl = (const float*)d_in[3];
  const float* bl = (const float*)d_in[4];
  const float* Wr = (const float*)d_in[5];
  const float* gamma = (const float*)d_in[6];
  const float* beta = (const float*)d_in[7];
  const float* Wlin = (const float*)d_in[8];
  const float* blin = (const float*)d_in[9];
  const float* Wp = (const float*)d_in[10];
  const float* bp = (const float*)d_in[11];
  const float* Wf1 = (const float*)d_in[12];
  const float* bf1 = (const float*)d_in[13];
  const float* Wf2 = (const float*)d_in[14];
  const float* bf2 = (const float*)d_in[15];
  float* out = (float*)d_out;

  const int NH = NN * HID;
  size_t off = 0;
  char* base = (char*)d_ws;
  auto carve = [&](size_t bytes) -> char* {
    char* p = base + off;
    off += (bytes + 255) & ~(size_t)255;
    return p;
  };
  float* xa = (float*)carve((size_t)NH * 4);
  float* xb = (float*)carve((size_t)NH * 4);
  float* xc = (float*)carve((size_t)NH * 4);
  float* xd = (float*)carve((size_t)NH * 4);
  int* srcA = (int*)carve((size_t)NE * 4);
  int* dstA = (int*)carve((size_t)NE * 4);
  int* srcB = (int*)carve((size_t)NE * 4);
  int* dstB = (int*)carve((size_t)NE * 4);
  float* escore = (float*)carve((size_t)NE * 4);
  int* ebucket = (int*)carve((size_t)NE * 4);
  int* eids = (int*)carve((size_t)NE * 4);
  int* wl0 = (int*)carve((size_t)NE * 4);
  int* wl1 = (int*)carve((size_t)NE * 4);
  u64* ntop = (u64*)carve((size_t)NN * 8);
  float* npx1 = (float*)carve((size_t)NN * 4);
  float* npx2 = (float*)carve((size_t)NN * 4);
  int* ncluster = (int*)carve((size_t)NN * 4);
  int* nchosen = (int*)carve((size_t)NN * 4);
  int* nmatched = (int*)carve((size_t)NN * 4);
  int* nvb = (int*)carve((size_t)NN * 4);
  int* b3 = (int*)carve((size_t)3 * NN * 4);
  int* bcount = b3;
  int* bcursor = b3 + NN;
  int* bucount = b3 + 2 * NN;
  int* boffs = (int*)carve((size_t)(NN + 1) * 4);
  int* bnoffs = (int*)carve((size_t)(NN + 1) * 4);
  int* csroff = (int*)carve((size_t)(NN + 1) * 4);
  double* bnsum = (double*)carve((size_t)2 * HID * 8);
  float* gbuf = (float*)carve((size_t)(NG * HID + NG) * 4);
  float* gsum = gbuf;
  float* gcnt = gbuf + NG * HID;
  float* ghfc = (float*)carve((size_t)NG * HID * 4);
  int* scal = (int*)carve(64 * 4);
  (void)ws_size; (void)n_in; (void)in_sizes; (void)out_size;

  int* pE = scal;          // E_cur
  int* pcnt = scal + 1;    // valid node count
  int* wcount = scal + 2;  // worklist counts [2]
  int* bar = scal + 4;     // barrier state: [arrive, gen]

  hipMemcpyAsync(xa, x0, (size_t)NH * 4, hipMemcpyDeviceToDevice, stream);
  k_init<<<1875, 256, 0, stream>>>(ei, srcA, dstA, nvb, scal, b3);

  int* srcC = srcA; int* dstC = dstA; int* srcN = srcB; int* dstN = dstB;
  float* xcur = xa;
  float* xtmp = xd;

  auto sage = [&](const float* xin, float* xout, int L) {
    k_sage_gather<<<3750, 256, 0, stream>>>(csroff, eids, srcC, xin, xtmp);
    gemm_dual<<<469, 256, 0, stream>>>(xtmp, Wl + (size_t)L * HID * HID, xin,
                                       Wr + (size_t)L * HID * HID, bl + (size_t)L * HID,
                                       xout, NN, HID, 1, bnsum);
    k_bn_stats<<<469, 128, 0, stream>>>(xout, nvb, bnsum);
    k_bn_apply<<<15000, 256, 0, stream>>>(xout, bnsum, pcnt, gamma + (size_t)L * HID,
                                          beta + (size_t)L * HID);
  };

  for (int b = 0; b < 3; b++) {
    // CSR by dst (shared by both SAGE layers and edge softmax) + valid count
    k_csr_count<<<1875, 256, 0, stream>>>(pE, dstC, bcount, nvb, pcnt);
    k_scan<<<1, 1024, 0, stream>>>(bcount, csroff, NN, (int*)nullptr);
    k_csr_scatter<<<1875, 256, 0, stream>>>(pE, dstC, csroff, bcursor, eids);

    sage(xcur, xb, 2 * b);
    sage(xb, xc, 2 * b + 1);
    gemm_dual<<<469, 256, 0, stream>>>(xc, Wlin + (size_t)b * HID * 2 * HID, xb,
                                       Wlin + (size_t)b * HID * 2 * HID + HID,
                                       blin + (size_t)b * HID, xcur, NN, 2 * HID, 0, bnsum);

    // ----- edge pooling -----
    k_node_proj<<<118, 256, 0, stream>>>(xcur, Wp + (size_t)b * 2 * HID, npx1, npx2, wcount);
    k_edge_softmax_seed<<<118, 256, 0, stream>>>(csroff, eids, srcC, npx1, npx2, bp + b,
                                                 escore, nvb, nmatched, ncluster, nchosen,
                                                 ntop, wl0, wcount);
    k_match_persist<<<MBLK, 256, 0, stream>>>(srcC, dstC, escore, nmatched, ncluster,
                                              nchosen, ntop, wl0, wl1, wcount, bar);
    k_new_x<<<3750, 256, 0, stream>>>(ncluster, nchosen, srcC, dstC, escore, xcur, xtmp,
                                      nvb, b3);

    k_bucket_count<<<1875, 256, 0, stream>>>(pE, srcC, ncluster, bcount);
    k_scan<<<1, 1024, 0, stream>>>(bcount, boffs, NN, (int*)nullptr);
    k_bucket_scatter<<<1875, 256, 0, stream>>>(pE, srcC, dstC, ncluster, boffs, bcursor, ebucket);
    k_sort_dedup<<<118, 256, 0, stream>>>(boffs, ebucket, bucount);
    k_scan<<<1, 1024, 0, stream>>>(bucount, bnoffs, NN, pE);
    k_emit<<<235, 256, 0, stream>>>(boffs, ebucket, bucount, bnoffs, srcN, dstN,
                                    b3, pcnt, gbuf);

    { int* t = srcC; srcC = srcN; srcN = t; t = dstC; dstC = dstN; dstN = t; }
    { float* t = xcur; xcur = xtmp; xtmp = t; }
  }

  k_graph_pool<<<469, 256, 0, stream>>>(nvb, batch, xcur, gsum, gcnt);
  k_head1<<<NG, 128, 0, stream>>>(gsum, gcnt, Wf1, bf1, ghfc);
  k_head2<<<NG, 32, 0, stream>>>(ghfc, Wf2, bf2, out);
}

// Round 6
// 7548.016 us; speedup vs baseline: 6.5454x; 2.3907x over previous
//
#include <hip/hip_runtime.h>
#include <stdint.h>

#define NN 30000
#define NE 480000
#define HID 128
#define NG 128
#define NC 6
#define BN_EPS 1e-5f
#define WPB 938   // ceil(NN/32) bitmap words

typedef unsigned int u32;
typedef unsigned long long u64;

// ---------------- init (also zeroes all per-call state) ----------------
__global__ void k_init(const int* __restrict__ ei, int* srcA, int* dstA, int* nvb,
                       int* scal, int* b3, int* i2, float* gbuf) {
  int t = blockIdx.x * 256 + threadIdx.x;
  if (t < NE) { srcA[t] = ei[t]; dstA[t] = ei[NE + t]; }
  if (t < NN) nvb[t] = 1;
  if (t < 2 * NN) { b3[t] = 0; i2[t] = 0; }   // bcount,bcursor + icnt,icursor
  if (t < NG * HID + NG) gbuf[t] = 0.f;
  if (t == 0) { scal[0] = NE; scal[1] = 0; }
}

// ---------------- CSR build (dst CSR + incidence CSR) + valid-node count ----------------
__global__ void k_csr_count(const int* __restrict__ pE, const int* __restrict__ src,
                            const int* __restrict__ dst, int* __restrict__ cnt,
                            int* __restrict__ icnt, const int* __restrict__ nvb,
                            int* __restrict__ pcnt) {
  int t = blockIdx.x * 256 + threadIdx.x;
  if (t < NN && nvb[t]) atomicAdd(pcnt, 1);
  if (t < *pE) {
    int s = src[t], d = dst[t];
    atomicAdd(&cnt[d], 1);
    if (s != d) { atomicAdd(&icnt[s], 1); atomicAdd(&icnt[d], 1); }
  }
}

// two independent single-block scans (block 0: dst-CSR, block 1: incidence)
__global__ __launch_bounds__(1024) void k_scan2(const int* __restrict__ in0, int* __restrict__ out0,
                                                const int* __restrict__ in1, int* __restrict__ out1) {
  const int* in = blockIdx.x ? in1 : in0;
  int* out = blockIdx.x ? out1 : out0;
  __shared__ int part[1024];
  int t = threadIdx.x;
  int chunk = (NN + 1023) / 1024;
  int b = t * chunk, e = b + chunk;
  if (b > NN) b = NN;
  if (e > NN) e = NN;
  int s = 0;
  for (int i = b; i < e; i++) s += in[i];
  part[t] = s;
  __syncthreads();
  for (int off = 1; off < 1024; off <<= 1) {
    int v = (t >= off) ? part[t - off] : 0;
    __syncthreads();
    part[t] += v;
    __syncthreads();
  }
  int excl = (t == 0) ? 0 : part[t - 1];
  for (int i = b; i < e; i++) { out[i] = excl; excl += in[i]; }
  if (t == 0) out[NN] = part[1023];
}

__global__ void k_csr_scatter(const int* __restrict__ pE, const int* __restrict__ src,
                              const int* __restrict__ dst, const int* __restrict__ coff,
                              int* __restrict__ cursor, int* __restrict__ eids,
                              const int* __restrict__ ioff, int* __restrict__ icur,
                              int* __restrict__ ieids) {
  int e = blockIdx.x * 256 + threadIdx.x;
  if (e >= *pE) return;
  int s = src[e], d = dst[e];
  int pos = coff[d] + atomicAdd(&cursor[d], 1);
  eids[pos] = e;
  if (s != d) {
    int p1 = ioff[s] + atomicAdd(&icur[s], 1); ieids[p1] = e;
    int p2 = ioff[d] + atomicAdd(&icur[d], 1); ieids[p2] = e;
  }
}

// ---------------- SAGE mean aggregation: CSR gather, 32 lanes/node ----------------
__global__ __launch_bounds__(256) void k_sage_gather(
    const int* __restrict__ coff, const int* __restrict__ eids,
    const int* __restrict__ src, const float* __restrict__ x,
    float* __restrict__ mean) {
  int grp = threadIdx.x >> 5;           // 8 nodes per block
  int lane = threadIdx.x & 31;
  int n = blockIdx.x * 8 + grp;
  if (n >= NN) return;
  int b = coff[n], e2 = coff[n + 1];
  float4 acc = make_float4(0.f, 0.f, 0.f, 0.f);
  for (int i = b; i < e2; i++) {
    int s = src[eids[i]];
    float4 v = *(const float4*)(x + (size_t)s * HID + lane * 4);
    acc.x += v.x; acc.y += v.y; acc.z += v.z; acc.w += v.w;
  }
  float inv = 1.0f / fmaxf((float)(e2 - b), 1.0f);
  acc.x *= inv; acc.y *= inv; acc.z *= inv; acc.w *= inv;
  *(float4*)(mean + (size_t)n * HID + lane * 4) = acc;
}

// out[n][j] = A1@W1^T + A2@W2^T + bias; optional relu. Also zeroes bnsum (block 0).
__global__ __launch_bounds__(256) void gemm_dual(
    const float* __restrict__ A1, const float* __restrict__ W1,
    const float* __restrict__ A2, const float* __restrict__ W2,
    const float* __restrict__ bias, float* __restrict__ out,
    int M, int ldw, int relu, double* __restrict__ bnsum) {
  if (blockIdx.x == 0 && threadIdx.x < 2 * HID) bnsum[threadIdx.x] = 0.0;
  __shared__ float As[64][33];
  __shared__ float Ws[32][132];  // transposed: Ws[kk][j]
  int row0 = blockIdx.x * 64;
  int tid = threadIdx.x;
  int cid = tid & 31;
  int rid = tid >> 5;
  float acc[8][4];
#pragma unroll
  for (int r = 0; r < 8; r++)
#pragma unroll
    for (int c = 0; c < 4; c++) acc[r][c] = 0.f;

  for (int srcI = 0; srcI < 2; ++srcI) {
    const float* A = srcI ? A2 : A1;
    const float* W = srcI ? W2 : W1;
    for (int kc = 0; kc < 128; kc += 32) {
#pragma unroll
      for (int i = 0; i < 2; ++i) {
        int idx = tid + i * 256;
        int r = idx >> 3;
        int c4 = (idx & 7) << 2;
        int gr = row0 + r;
        float4 v = make_float4(0.f, 0.f, 0.f, 0.f);
        if (gr < M) v = *(const float4*)(A + (size_t)gr * 128 + kc + c4);
        As[r][c4 + 0] = v.x; As[r][c4 + 1] = v.y; As[r][c4 + 2] = v.z; As[r][c4 + 3] = v.w;
      }
#pragma unroll
      for (int i = 0; i < 4; ++i) {
        int idx = tid + i * 256;
        int j = idx >> 3;
        int c4 = (idx & 7) << 2;
        float4 v = *(const float4*)(W + (size_t)j * ldw + kc + c4);
        Ws[c4 + 0][j] = v.x; Ws[c4 + 1][j] = v.y; Ws[c4 + 2][j] = v.z; Ws[c4 + 3][j] = v.w;
      }
      __syncthreads();
#pragma unroll
      for (int kk = 0; kk < 32; ++kk) {
        float4 w = *(const float4*)(&Ws[kk][cid * 4]);
#pragma unroll
        for (int r = 0; r < 8; ++r) {
          float a = As[rid * 8 + r][kk];
          acc[r][0] += a * w.x; acc[r][1] += a * w.y; acc[r][2] += a * w.z; acc[r][3] += a * w.w;
        }
      }
      __syncthreads();
    }
  }
#pragma unroll
  for (int r = 0; r < 8; ++r) {
    int gr = row0 + rid * 8 + r;
    if (gr >= M) continue;
#pragma unroll
    for (int c = 0; c < 4; ++c) {
      float v = acc[r][c] + bias[cid * 4 + c];
      if (relu) v = fmaxf(v, 0.f);
      out[(size_t)gr * 128 + cid * 4 + c] = v;
    }
  }
}

__global__ __launch_bounds__(128) void k_bn_stats(const float* __restrict__ x,
                                                  const int* __restrict__ nvb,
                                                  double* __restrict__ sums) {
  int k = threadIdx.x;
  int n0 = blockIdx.x * 64;
  float s = 0.f, q = 0.f;
  for (int r = 0; r < 64; r++) {
    int n = n0 + r;
    if (n >= NN) break;
    if (!nvb[n]) continue;
    float v = x[(size_t)n * HID + k];
    s += v; q += v * v;
  }
  atomicAdd(&sums[k], (double)s);
  atomicAdd(&sums[HID + k], (double)q);
}

__global__ void k_bn_apply(float* __restrict__ x, const double* __restrict__ sums,
                           const int* __restrict__ cnt, const float* __restrict__ gamma,
                           const float* __restrict__ beta) {
  int t = blockIdx.x * 256 + threadIdx.x;
  if (t >= NN * HID) return;
  int k = t & 127;
  double c = (double)((*cnt > 1) ? *cnt : 1);
  double mu = sums[k] / c;
  double var = sums[HID + k] / c - mu * mu;
  if (var < 0.0) var = 0.0;
  float inv = (float)(1.0 / sqrt(var + (double)BN_EPS));
  x[t] = gamma[k] * (x[t] - (float)mu) * inv + beta[k];
}

// ---------------- edge pool ----------------
__global__ void k_node_proj(const float* __restrict__ x, const float* __restrict__ Wp,
                            float* __restrict__ px1, float* __restrict__ px2) {
  int n = blockIdx.x * 256 + threadIdx.x;
  if (n >= NN) return;
  const float* xr = x + (size_t)n * HID;
  float s1 = 0.f, s2 = 0.f;
#pragma unroll 8
  for (int k = 0; k < HID; k += 4) {
    float4 v = *(const float4*)(xr + k);
    float4 w1 = *(const float4*)(Wp + k);
    float4 w2 = *(const float4*)(Wp + HID + k);
    s1 += v.x * w1.x + v.y * w1.y + v.z * w1.z + v.w * w1.w;
    s2 += v.x * w2.x + v.y * w2.y + v.z * w2.z + v.w * w2.w;
  }
  px1[n] = s1; px2[n] = s2;
}

// fused: pool state init (cluster/chosen/S) + per-dst softmax + suitor keys
__global__ void k_edge_softmax_seed(
    const int* __restrict__ coff, const int* __restrict__ eids,
    const int* __restrict__ src, const float* __restrict__ px1,
    const float* __restrict__ px2, const float* __restrict__ bp,
    float* __restrict__ score, u64* __restrict__ ekey,
    int* __restrict__ cluster, int* __restrict__ chosen, u64* __restrict__ S) {
  int n = blockIdx.x * 256 + threadIdx.x;
  if (n >= NN) return;
  cluster[n] = n;
  chosen[n] = -1;
  S[n] = 0ull;
  int b = coff[n], e2 = coff[n + 1];
  if (b == e2) return;
  float p2 = px2[n] + *bp;
  float mx = -3.4e38f;
  for (int i = b; i < e2; i++) {
    float r = px1[src[eids[i]]] + p2;
    mx = fmaxf(mx, r);
  }
  double den = 0.0;
  for (int i = b; i < e2; i++) {
    int eid = eids[i];
    float z = expf(px1[src[eid]] + p2 - mx);
    score[eid] = z;
    den += (double)z;
  }
  if (den < 1e-16) den = 1e-16;
  double invd = 1.0 / den;
  for (int i = b; i < e2; i++) {
    int eid = eids[i];
    float sc = (float)((double)score[eid] * invd) + 0.5f;
    score[eid] = sc;
    // key: score desc, then lower edge index wins (matches stable argsort(-score))
    ekey[eid] = ((u64)__float_as_uint(sc) << 32) | (u64)(0xFFFFFFFFu - (u32)eid);
  }
}

// ---------------- Suitor matching (Manne-Halappanavar): lock-free, exact greedy ----------------
// S[v] = best proposal key to v (monotone under atomicMax). Displaced proposer is
// re-seeked by the displacing thread. No barriers; result = unique greedy matching.
__global__ __launch_bounds__(256) void k_suitor(
    const int* __restrict__ ioff, const int* __restrict__ ieids,
    const int* __restrict__ src, const int* __restrict__ dst,
    const u64* __restrict__ ekey, u64* __restrict__ S) {
  int u0 = blockIdx.x * 256 + threadIdx.x;
  if (u0 >= NN) return;
  int cur = u0;
  while (cur >= 0) {
    int b = ioff[cur], e2 = ioff[cur + 1];
    u64 bestKey = 0; int bestV = -1;
    for (int i = b; i < e2; i++) {
      int e = ieids[i];
      u64 k = ekey[e];
      if (k <= bestKey) continue;
      int s = src[e], d = dst[e];
      int v = (s == cur) ? d : s;
      u64 sv = __hip_atomic_load(&S[v], __ATOMIC_RELAXED, __HIP_MEMORY_SCOPE_AGENT);
      if (k > sv) { bestKey = k; bestV = v; }
    }
    if (bestV < 0) break;                    // no available partner
    u64 old = atomicMax(&S[bestV], bestKey);
    if (old >= bestKey) continue;            // lost race; re-seek cur with fresh S
    if (old == 0) break;                     // accepted, nobody displaced
    int eo = (int)(0xFFFFFFFFu - (u32)(old & 0xFFFFFFFFull));
    int s = src[eo], d = dst[eo];
    cur = (s == bestV) ? d : s;              // displaced proposer re-seeks
  }
}

// mutual proposals -> matched pair; rep-side thread writes cluster/chosen
__global__ void k_resolve(const int* __restrict__ src, const int* __restrict__ dst,
                          const u64* __restrict__ S, int* __restrict__ cluster,
                          int* __restrict__ chosen) {
  int n = blockIdx.x * 256 + threadIdx.x;
  if (n >= NN) return;
  u64 k = S[n];
  if (!k) return;
  int e = (int)(0xFFFFFFFFu - (u32)(k & 0xFFFFFFFFull));
  int s = src[e], d = dst[e];
  int rep = s < d ? s : d;
  if (n != rep) return;
  if (S[s] == k && S[d] == k) {
    int oth = s < d ? d : s;
    cluster[oth] = rep;
    chosen[rep] = e;
  }
}

// new_x gather (clusters have <=2 members) + nvb update + zero bcount/bcursor
__global__ __launch_bounds__(256) void k_new_x(
    const int* __restrict__ cluster, const int* __restrict__ chosen,
    const int* __restrict__ src, const int* __restrict__ dst,
    const float* __restrict__ score, const float* __restrict__ x,
    float* __restrict__ out, int* __restrict__ nvb, int* __restrict__ b3zero) {
  int gt = blockIdx.x * 256 + threadIdx.x;
  if (gt < 2 * NN) b3zero[gt] = 0;
  int grp = threadIdx.x >> 5;
  int lane = threadIdx.x & 31;
  int n = blockIdx.x * 8 + grp;
  if (n >= NN) return;
  float4 v = make_float4(0.f, 0.f, 0.f, 0.f);
  bool rep = (cluster[n] == n);
  if (rep) {
    v = *(const float4*)(x + (size_t)n * HID + lane * 4);
    int ch = chosen[n];
    if (ch >= 0) {
      int s = src[ch], d = dst[ch];
      int partner = (s == n) ? d : s;
      float4 w = *(const float4*)(x + (size_t)partner * HID + lane * 4);
      float sc = score[ch];
      v.x = (v.x + w.x) * sc; v.y = (v.y + w.y) * sc;
      v.z = (v.z + w.z) * sc; v.w = (v.w + w.w) * sc;
    }
  }
  *(float4*)(out + (size_t)n * HID + lane * 4) = v;
  if (lane == 0) nvb[n] = (nvb[n] && rep) ? 1 : 0;
}

// ---------------- dedup (sorted unique of (cs,cd)) ----------------
__global__ void k_bucket_count(const int* __restrict__ pE, const int* __restrict__ src,
                               const int* __restrict__ cluster, int* __restrict__ bcount) {
  int e = blockIdx.x * 256 + threadIdx.x;
  if (e >= *pE) return;
  atomicAdd(&bcount[cluster[src[e]]], 1);
}

__global__ __launch_bounds__(1024) void k_scan(const int* __restrict__ in, int* __restrict__ out,
                                               int n, int* totalDst) {
  __shared__ int part[1024];
  int t = threadIdx.x;
  int chunk = (n + 1023) / 1024;
  int b = t * chunk, e = b + chunk;
  if (b > n) b = n;
  if (e > n) e = n;
  int s = 0;
  for (int i = b; i < e; i++) s += in[i];
  part[t] = s;
  __syncthreads();
  for (int off = 1; off < 1024; off <<= 1) {
    int v = (t >= off) ? part[t - off] : 0;
    __syncthreads();
    part[t] += v;
    __syncthreads();
  }
  int excl = (t == 0) ? 0 : part[t - 1];
  int total = part[1023];
  for (int i = b; i < e; i++) { out[i] = excl; excl += in[i]; }
  if (t == 0) {
    out[n] = total;
    if (totalDst) *totalDst = total;
  }
}

__global__ void k_bucket_scatter(const int* __restrict__ pE, const int* __restrict__ src,
                                 const int* __restrict__ dst, const int* __restrict__ cluster,
                                 const int* __restrict__ boffs, int* __restrict__ bcursor,
                                 int* __restrict__ bucket) {
  int e = blockIdx.x * 256 + threadIdx.x;
  if (e >= *pE) return;
  int cs = cluster[src[e]], cd = cluster[dst[e]];
  int pos = boffs[cs] + atomicAdd(&bcursor[cs], 1);
  bucket[pos] = cd;
}

// sorted-unique per bucket via per-wave LDS bitmap (no comparison sort, no O(d^2)).
// one wave per node; grid 7500x256 = exactly 30000 waves, no ragged barriers.
__global__ __launch_bounds__(256) void k_dedup_bitmap(
    const int* __restrict__ boffs, int* __restrict__ bucket,
    int* __restrict__ ucount) {
  __shared__ u32 bm[4][960];
  int wid = threadIdx.x >> 6;
  int lane = threadIdx.x & 63;
  int n = blockIdx.x * 4 + wid;
  int b = boffs[n], e = boffs[n + 1];
  for (int w = lane; w < 960; w += 64) bm[wid][w] = 0;
  __syncthreads();
  for (int i = b + lane; i < e; i += 64)
    atomicOr(&bm[wid][bucket[i] >> 5], 1u << (bucket[i] & 31));
  __syncthreads();
  int w0 = lane * 15;
  int w1 = w0 + 15; if (w1 > WPB) w1 = WPB;
  int cnt = 0;
  for (int w = w0; w < w1; w++) cnt += __popc(bm[wid][w]);
  int inc = cnt;
  for (int o = 1; o < 64; o <<= 1) { int v = __shfl_up(inc, o); if (lane >= o) inc += v; }
  int excl = inc - cnt;
  int total = __shfl(inc, 63);
  int pos = b + excl;
  for (int w = w0; w < w1; w++) {
    u32 v = bm[wid][w];
    while (v) { int bit = __ffs(v) - 1; bucket[pos++] = (w << 5) | bit; v &= v - 1; }
  }
  if (lane == 0) ucount[n] = total;
}

// emit compacted edges + zero bcount/bcursor/icnt/icursor/pcnt for next level
__global__ void k_emit(const int* __restrict__ boffs, const int* __restrict__ bucket,
                       const int* __restrict__ bucount, const int* __restrict__ bnoffs,
                       int* __restrict__ srcO, int* __restrict__ dstO,
                       int* __restrict__ b3zero, int* __restrict__ i2zero,
                       int* __restrict__ pcnt) {
  int t = blockIdx.x * 256 + threadIdx.x;
  int stride = gridDim.x * 256;
  for (int z = t; z < 2 * NN; z += stride) { b3zero[z] = 0; i2zero[z] = 0; }
  if (t == 0) *pcnt = 0;
  if (t >= NN) return;
  int u = bucount[t], b = boffs[t], o = bnoffs[t];
  for (int i = 0; i < u; i++) { srcO[o + i] = t; dstO[o + i] = bucket[b + i]; }
}

// ---------------- readout ----------------
__global__ void k_graph_pool(const int* __restrict__ nvb, const int* __restrict__ batch,
                             const float* __restrict__ x, float* __restrict__ gsum,
                             float* __restrict__ gcnt) {
  int t = blockIdx.x * 256 + threadIdx.x;
  int n = t >> 2;
  if (n >= NN) return;
  if (!nvb[n]) return;
  int sub = t & 3;
  int g = batch[n];
  const float* xr = x + (size_t)n * HID + sub * 32;
  float* o = gsum + (size_t)g * HID + sub * 32;
#pragma unroll
  for (int i = 0; i < 8; i++) {
    float4 v = *(const float4*)(xr + i * 4);
    atomicAdd(o + i * 4 + 0, v.x); atomicAdd(o + i * 4 + 1, v.y);
    atomicAdd(o + i * 4 + 2, v.z); atomicAdd(o + i * 4 + 3, v.w);
  }
  if (sub == 0) atomicAdd(&gcnt[g], 1.0f);
}

__global__ __launch_bounds__(128) void k_head1(const float* __restrict__ gsum,
                                               const float* __restrict__ gcnt,
                                               const float* __restrict__ Wf1,
                                               const float* __restrict__ bf1,
                                               float* __restrict__ hfc) {
  int g = blockIdx.x;
  int j = threadIdx.x;
  __shared__ float p[HID];
  float c = fmaxf(gcnt[g], 1.f);
  p[j] = gsum[g * HID + j] / c;
  __syncthreads();
  float s = bf1[j];
  const float* w = Wf1 + (size_t)j * HID;
  for (int k = 0; k < HID; k++) s += p[k] * w[k];
  hfc[g * HID + j] = fmaxf(s, 0.f);
}

__global__ void k_head2(const float* __restrict__ hfc, const float* __restrict__ Wf2,
                        const float* __restrict__ bf2, float* __restrict__ out) {
  int g = blockIdx.x;
  int t = threadIdx.x;
  __shared__ float lg[NC];
  if (t < NC) {
    float s = bf2[t];
    const float* w = Wf2 + (size_t)t * HID;
    const float* h = hfc + (size_t)g * HID;
    for (int k = 0; k < HID; k++) s += h[k] * w[k];
    lg[t] = s;
  }
  __syncthreads();
  if (t == 0) {
    float m = lg[0];
    for (int c = 1; c < NC; c++) m = fmaxf(m, lg[c]);
    float se = 0.f;
    for (int c = 0; c < NC; c++) se += expf(lg[c] - m);
    float lse = m + logf(se);
    for (int c = 0; c < NC; c++) out[g * NC + c] = lg[c] - lse;
  }
}

extern "C" void kernel_launch(void* const* d_in, const int* in_sizes, int n_in,
                              void* d_out, int out_size, void* d_ws, size_t ws_size,
                              hipStream_t stream) {
  const float* x0 = (const float*)d_in[0];
  const int* ei = (const int*)d_in[1];
  const int* batch = (const int*)d_in[2];
  const float* Wl = (const float*)d_in[3];
  const float* bl = (const float*)d_in[4];
  const float* Wr = (const float*)d_in[5];
  const float* gamma = (const float*)d_in[6];
  const float* beta = (const float*)d_in[7];
  const float* Wlin = (const float*)d_in[8];
  const float* blin = (const float*)d_in[9];
  const float* Wp = (const float*)d_in[10];
  const float* bp = (const float*)d_in[11];
  const float* Wf1 = (const float*)d_in[12];
  const float* bf1 = (const float*)d_in[13];
  const float* Wf2 = (const float*)d_in[14];
  const float* bf2 = (const float*)d_in[15];
  float* out = (float*)d_out;

  const int NH = NN * HID;
  size_t off = 0;
  char* base = (char*)d_ws;
  auto carve = [&](size_t bytes) -> char* {
    char* p = base + off;
    off += (bytes + 255) & ~(size_t)255;
    return p;
  };
  float* xa = (float*)carve((size_t)NH * 4);
  float* xb = (float*)carve((size_t)NH * 4);
  float* xc = (float*)carve((size_t)NH * 4);
  float* xd = (float*)carve((size_t)NH * 4);
  int* srcA = (int*)carve((size_t)NE * 4);
  int* dstA = (int*)carve((size_t)NE * 4);
  int* srcB = (int*)carve((size_t)NE * 4);
  int* dstB = (int*)carve((size_t)NE * 4);
  float* escore = (float*)carve((size_t)NE * 4);
  int* ebucket = (int*)carve((size_t)NE * 4);
  int* eids = (int*)carve((size_t)NE * 4);
  u64* ekey = (u64*)carve((size_t)NE * 8);
  int* ieids = (int*)carve((size_t)2 * NE * 4);
  u64* S = (u64*)carve((size_t)NN * 8);
  float* npx1 = (float*)carve((size_t)NN * 4);
  float* npx2 = (float*)carve((size_t)NN * 4);
  int* ncluster = (int*)carve((size_t)NN * 4);
  int* nchosen = (int*)carve((size_t)NN * 4);
  int* nvb = (int*)carve((size_t)NN * 4);
  int* b3 = (int*)carve((size_t)3 * NN * 4);
  int* bcount = b3;
  int* bcursor = b3 + NN;
  int* bucount = b3 + 2 * NN;
  int* i2 = (int*)carve((size_t)2 * NN * 4);
  int* icnt = i2;
  int* icursor = i2 + NN;
  int* boffs = (int*)carve((size_t)(NN + 1) * 4);
  int* bnoffs = (int*)carve((size_t)(NN + 1) * 4);
  int* csroff = (int*)carve((size_t)(NN + 1) * 4);
  int* ioff = (int*)carve((size_t)(NN + 1) * 4);
  double* bnsum = (double*)carve((size_t)2 * HID * 8);
  float* gbuf = (float*)carve((size_t)(NG * HID + NG) * 4);
  float* gsum = gbuf;
  float* gcnt = gbuf + NG * HID;
  float* ghfc = (float*)carve((size_t)NG * HID * 4);
  int* scal = (int*)carve(64 * 4);
  (void)ws_size; (void)n_in; (void)in_sizes; (void)out_size;

  int* pE = scal;        // E_cur
  int* pcnt = scal + 1;  // valid node count

  hipMemcpyAsync(xa, x0, (size_t)NH * 4, hipMemcpyDeviceToDevice, stream);
  k_init<<<1875, 256, 0, stream>>>(ei, srcA, dstA, nvb, scal, b3, i2, gbuf);

  int* srcC = srcA; int* dstC = dstA; int* srcN = srcB; int* dstN = dstB;
  float* xcur = xa;
  float* xtmp = xd;

  auto sage = [&](const float* xin, float* xout, int L) {
    k_sage_gather<<<3750, 256, 0, stream>>>(csroff, eids, srcC, xin, xtmp);
    gemm_dual<<<469, 256, 0, stream>>>(xtmp, Wl + (size_t)L * HID * HID, xin,
                                       Wr + (size_t)L * HID * HID, bl + (size_t)L * HID,
                                       xout, NN, HID, 1, bnsum);
    k_bn_stats<<<469, 128, 0, stream>>>(xout, nvb, bnsum);
    k_bn_apply<<<15000, 256, 0, stream>>>(xout, bnsum, pcnt, gamma + (size_t)L * HID,
                                          beta + (size_t)L * HID);
  };

  for (int b = 0; b < 3; b++) {
    // dst-CSR (sage + softmax) and incidence-CSR (suitor), one count/scan/scatter chain
    k_csr_count<<<1875, 256, 0, stream>>>(pE, srcC, dstC, bcount, icnt, nvb, pcnt);
    k_scan2<<<2, 1024, 0, stream>>>(bcount, csroff, icnt, ioff);
    k_csr_scatter<<<1875, 256, 0, stream>>>(pE, srcC, dstC, csroff, bcursor, eids,
                                            ioff, icursor, ieids);

    sage(xcur, xb, 2 * b);
    sage(xb, xc, 2 * b + 1);
    gemm_dual<<<469, 256, 0, stream>>>(xc, Wlin + (size_t)b * HID * 2 * HID, xb,
                                       Wlin + (size_t)b * HID * 2 * HID + HID,
                                       blin + (size_t)b * HID, xcur, NN, 2 * HID, 0, bnsum);

    // ----- edge pooling: softmax scores -> suitor matching -> resolve -----
    k_node_proj<<<118, 256, 0, stream>>>(xcur, Wp + (size_t)b * 2 * HID, npx1, npx2);
    k_edge_softmax_seed<<<118, 256, 0, stream>>>(csroff, eids, srcC, npx1, npx2, bp + b,
                                                 escore, ekey, ncluster, nchosen, S);
    k_suitor<<<118, 256, 0, stream>>>(ioff, ieids, srcC, dstC, ekey, S);
    k_resolve<<<118, 256, 0, stream>>>(srcC, dstC, S, ncluster, nchosen);
    k_new_x<<<3750, 256, 0, stream>>>(ncluster, nchosen, srcC, dstC, escore, xcur, xtmp,
                                      nvb, b3);

    if (b < 2) {  // level-2 coarse edges are never consumed
      k_bucket_count<<<1875, 256, 0, stream>>>(pE, srcC, ncluster, bcount);
      k_scan<<<1, 1024, 0, stream>>>(bcount, boffs, NN, (int*)nullptr);
      k_bucket_scatter<<<1875, 256, 0, stream>>>(pE, srcC, dstC, ncluster, boffs, bcursor,
                                                 ebucket);
      k_dedup_bitmap<<<7500, 256, 0, stream>>>(boffs, ebucket, bucount);
      k_scan<<<1, 1024, 0, stream>>>(bucount, bnoffs, NN, pE);
      k_emit<<<235, 256, 0, stream>>>(boffs, ebucket, bucount, bnoffs, srcN, dstN,
                                      b3, i2, pcnt);
      { int* t = srcC; srcC = srcN; srcN = t; t = dstC; dstC = dstN; dstN = t; }
    }
    { float* t = xcur; xcur = xtmp; xtmp = t; }
  }

  k_graph_pool<<<469, 256, 0, stream>>>(nvb, batch, xcur, gsum, gcnt);
  k_head1<<<NG, 128, 0, stream>>>(gsum, gcnt, Wf1, bf1, ghfc);
  k_head2<<<NG, 32, 0, stream>>>(ghfc, Wf2, bf2, out);
}

// Round 7
// 3107.504 us; speedup vs baseline: 15.8985x; 2.4290x over previous
//
#include <hip/hip_runtime.h>
#include <stdint.h>

#define NN 30000
#define NE 480000
#define HID 128
#define NG 128
#define NC 6
#define BN_EPS 1e-5f
#define WPB 938   // ceil(NN/32) bitmap words

typedef unsigned int u32;
typedef unsigned long long u64;

// ---------------- init (also zeroes all per-call state) ----------------
__global__ void k_init(const int* __restrict__ ei, int* srcA, int* dstA, int* nvb,
                       int* scal, int* b3, int* i2, float* gbuf) {
  int t = blockIdx.x * 256 + threadIdx.x;
  if (t < NE) { srcA[t] = ei[t]; dstA[t] = ei[NE + t]; }
  if (t < NN) nvb[t] = 1;
  if (t < 2 * NN) { b3[t] = 0; i2[t] = 0; }   // bcount,bcursor + icnt,icursor
  if (t < NG * HID + NG) gbuf[t] = 0.f;
  if (t == 0) { scal[0] = NE; scal[1] = 0; }
}

// ---------------- CSR build (dst CSR + incidence CSR) + valid-node count ----------------
__global__ void k_csr_count(const int* __restrict__ pE, const int* __restrict__ src,
                            const int* __restrict__ dst, int* __restrict__ cnt,
                            int* __restrict__ icnt, const int* __restrict__ nvb,
                            int* __restrict__ pcnt) {
  int t = blockIdx.x * 256 + threadIdx.x;
  if (t < NN && nvb[t]) atomicAdd(pcnt, 1);
  if (t < *pE) {
    int s = src[t], d = dst[t];
    atomicAdd(&cnt[d], 1);
    if (s != d) { atomicAdd(&icnt[s], 1); atomicAdd(&icnt[d], 1); }
  }
}

// two independent single-block scans (block 0: dst-CSR, block 1: incidence)
__global__ __launch_bounds__(1024) void k_scan2(const int* __restrict__ in0, int* __restrict__ out0,
                                                const int* __restrict__ in1, int* __restrict__ out1) {
  const int* in = blockIdx.x ? in1 : in0;
  int* out = blockIdx.x ? out1 : out0;
  __shared__ int part[1024];
  int t = threadIdx.x;
  int chunk = (NN + 1023) / 1024;
  int b = t * chunk, e = b + chunk;
  if (b > NN) b = NN;
  if (e > NN) e = NN;
  int s = 0;
  for (int i = b; i < e; i++) s += in[i];
  part[t] = s;
  __syncthreads();
  for (int off = 1; off < 1024; off <<= 1) {
    int v = (t >= off) ? part[t - off] : 0;
    __syncthreads();
    part[t] += v;
    __syncthreads();
  }
  int excl = (t == 0) ? 0 : part[t - 1];
  for (int i = b; i < e; i++) { out[i] = excl; excl += in[i]; }
  if (t == 0) out[NN] = part[1023];
}

__global__ void k_csr_scatter(const int* __restrict__ pE, const int* __restrict__ src,
                              const int* __restrict__ dst, const int* __restrict__ coff,
                              int* __restrict__ cursor, int* __restrict__ eids,
                              const int* __restrict__ ioff, int* __restrict__ icur,
                              int* __restrict__ ieids) {
  int e = blockIdx.x * 256 + threadIdx.x;
  if (e >= *pE) return;
  int s = src[e], d = dst[e];
  int pos = coff[d] + atomicAdd(&cursor[d], 1);
  eids[pos] = e;
  if (s != d) {
    int p1 = ioff[s] + atomicAdd(&icur[s], 1); ieids[p1] = e;
    int p2 = ioff[d] + atomicAdd(&icur[d], 1); ieids[p2] = e;
  }
}

// ---------------- SAGE mean aggregation: CSR gather, 32 lanes/node ----------------
__global__ __launch_bounds__(256) void k_sage_gather(
    const int* __restrict__ coff, const int* __restrict__ eids,
    const int* __restrict__ src, const float* __restrict__ x,
    float* __restrict__ mean) {
  int grp = threadIdx.x >> 5;           // 8 nodes per block
  int lane = threadIdx.x & 31;
  int n = blockIdx.x * 8 + grp;
  if (n >= NN) return;
  int b = coff[n], e2 = coff[n + 1];
  float4 acc = make_float4(0.f, 0.f, 0.f, 0.f);
  for (int i = b; i < e2; i++) {
    int s = src[eids[i]];
    float4 v = *(const float4*)(x + (size_t)s * HID + lane * 4);
    acc.x += v.x; acc.y += v.y; acc.z += v.z; acc.w += v.w;
  }
  float inv = 1.0f / fmaxf((float)(e2 - b), 1.0f);
  acc.x *= inv; acc.y *= inv; acc.z *= inv; acc.w *= inv;
  *(float4*)(mean + (size_t)n * HID + lane * 4) = acc;
}

// out[n][j] = A1@W1^T + A2@W2^T + bias; optional relu. Also zeroes bnsum (block 0).
__global__ __launch_bounds__(256) void gemm_dual(
    const float* __restrict__ A1, const float* __restrict__ W1,
    const float* __restrict__ A2, const float* __restrict__ W2,
    const float* __restrict__ bias, float* __restrict__ out,
    int M, int ldw, int relu, double* __restrict__ bnsum) {
  if (blockIdx.x == 0 && threadIdx.x < 2 * HID) bnsum[threadIdx.x] = 0.0;
  __shared__ float As[64][33];
  __shared__ float Ws[32][132];  // transposed: Ws[kk][j]
  int row0 = blockIdx.x * 64;
  int tid = threadIdx.x;
  int cid = tid & 31;
  int rid = tid >> 5;
  float acc[8][4];
#pragma unroll
  for (int r = 0; r < 8; r++)
#pragma unroll
    for (int c = 0; c < 4; c++) acc[r][c] = 0.f;

  for (int srcI = 0; srcI < 2; ++srcI) {
    const float* A = srcI ? A2 : A1;
    const float* W = srcI ? W2 : W1;
    for (int kc = 0; kc < 128; kc += 32) {
#pragma unroll
      for (int i = 0; i < 2; ++i) {
        int idx = tid + i * 256;
        int r = idx >> 3;
        int c4 = (idx & 7) << 2;
        int gr = row0 + r;
        float4 v = make_float4(0.f, 0.f, 0.f, 0.f);
        if (gr < M) v = *(const float4*)(A + (size_t)gr * 128 + kc + c4);
        As[r][c4 + 0] = v.x; As[r][c4 + 1] = v.y; As[r][c4 + 2] = v.z; As[r][c4 + 3] = v.w;
      }
#pragma unroll
      for (int i = 0; i < 4; ++i) {
        int idx = tid + i * 256;
        int j = idx >> 3;
        int c4 = (idx & 7) << 2;
        float4 v = *(const float4*)(W + (size_t)j * ldw + kc + c4);
        Ws[c4 + 0][j] = v.x; Ws[c4 + 1][j] = v.y; Ws[c4 + 2][j] = v.z; Ws[c4 + 3][j] = v.w;
      }
      __syncthreads();
#pragma unroll
      for (int kk = 0; kk < 32; ++kk) {
        float4 w = *(const float4*)(&Ws[kk][cid * 4]);
#pragma unroll
        for (int r = 0; r < 8; ++r) {
          float a = As[rid * 8 + r][kk];
          acc[r][0] += a * w.x; acc[r][1] += a * w.y; acc[r][2] += a * w.z; acc[r][3] += a * w.w;
        }
      }
      __syncthreads();
    }
  }
#pragma unroll
  for (int r = 0; r < 8; ++r) {
    int gr = row0 + rid * 8 + r;
    if (gr >= M) continue;
#pragma unroll
    for (int c = 0; c < 4; ++c) {
      float v = acc[r][c] + bias[cid * 4 + c];
      if (relu) v = fmaxf(v, 0.f);
      out[(size_t)gr * 128 + cid * 4 + c] = v;
    }
  }
}

__global__ __launch_bounds__(128) void k_bn_stats(const float* __restrict__ x,
                                                  const int* __restrict__ nvb,
                                                  double* __restrict__ sums) {
  int k = threadIdx.x;
  int n0 = blockIdx.x * 64;
  float s = 0.f, q = 0.f;
  for (int r = 0; r < 64; r++) {
    int n = n0 + r;
    if (n >= NN) break;
    if (!nvb[n]) continue;
    float v = x[(size_t)n * HID + k];
    s += v; q += v * v;
  }
  atomicAdd(&sums[k], (double)s);
  atomicAdd(&sums[HID + k], (double)q);
}

__global__ void k_bn_apply(float* __restrict__ x, const double* __restrict__ sums,
                           const int* __restrict__ cnt, const float* __restrict__ gamma,
                           const float* __restrict__ beta) {
  int t = blockIdx.x * 256 + threadIdx.x;
  if (t >= NN * HID) return;
  int k = t & 127;
  double c = (double)((*cnt > 1) ? *cnt : 1);
  double mu = sums[k] / c;
  double var = sums[HID + k] / c - mu * mu;
  if (var < 0.0) var = 0.0;
  float inv = (float)(1.0 / sqrt(var + (double)BN_EPS));
  x[t] = gamma[k] * (x[t] - (float)mu) * inv + beta[k];
}

// ---------------- edge pool ----------------
__global__ void k_node_proj(const float* __restrict__ x, const float* __restrict__ Wp,
                            float* __restrict__ px1, float* __restrict__ px2) {
  int n = blockIdx.x * 256 + threadIdx.x;
  if (n >= NN) return;
  const float* xr = x + (size_t)n * HID;
  float s1 = 0.f, s2 = 0.f;
#pragma unroll 8
  for (int k = 0; k < HID; k += 4) {
    float4 v = *(const float4*)(xr + k);
    float4 w1 = *(const float4*)(Wp + k);
    float4 w2 = *(const float4*)(Wp + HID + k);
    s1 += v.x * w1.x + v.y * w1.y + v.z * w1.z + v.w * w1.w;
    s2 += v.x * w2.x + v.y * w2.y + v.z * w2.z + v.w * w2.w;
  }
  px1[n] = s1; px2[n] = s2;
}

// fused: pool state init (cluster/chosen/S) + per-dst softmax + suitor keys
__global__ void k_edge_softmax_seed(
    const int* __restrict__ coff, const int* __restrict__ eids,
    const int* __restrict__ src, const float* __restrict__ px1,
    const float* __restrict__ px2, const float* __restrict__ bp,
    float* __restrict__ score, u64* __restrict__ ekey,
    int* __restrict__ cluster, int* __restrict__ chosen, u64* __restrict__ S) {
  int n = blockIdx.x * 256 + threadIdx.x;
  if (n >= NN) return;
  cluster[n] = n;
  chosen[n] = -1;
  S[n] = 0ull;
  int b = coff[n], e2 = coff[n + 1];
  if (b == e2) return;
  float p2 = px2[n] + *bp;
  float mx = -3.4e38f;
  for (int i = b; i < e2; i++) {
    float r = px1[src[eids[i]]] + p2;
    mx = fmaxf(mx, r);
  }
  double den = 0.0;
  for (int i = b; i < e2; i++) {
    int eid = eids[i];
    float z = expf(px1[src[eid]] + p2 - mx);
    score[eid] = z;
    den += (double)z;
  }
  if (den < 1e-16) den = 1e-16;
  double invd = 1.0 / den;
  for (int i = b; i < e2; i++) {
    int eid = eids[i];
    float sc = (float)((double)score[eid] * invd) + 0.5f;
    score[eid] = sc;
    // key: score desc, then lower edge index wins (matches stable argsort(-score))
    ekey[eid] = ((u64)__float_as_uint(sc) << 32) | (u64)(0xFFFFFFFFu - (u32)eid);
  }
}

// ---------------- Suitor matching, wave-per-node ----------------
// Same lattice-monotone algorithm as round 6 (exact greedy matching), but the
// incidence-list seek is 64-lane parallel and 30000 waves run concurrently
// (round-6 version: 30208 *threads* total, 0.46 blocks/CU, serial seeks ->
// latency-bound at 40 GB/s). Lane 0 owns the atomicMax + displacement chase.
__global__ __launch_bounds__(256) void k_suitor(
    const int* __restrict__ ioff, const int* __restrict__ ieids,
    const int* __restrict__ src, const int* __restrict__ dst,
    const u64* __restrict__ ekey, u64* __restrict__ S) {
  int wid = threadIdx.x >> 6;
  int lane = threadIdx.x & 63;
  int n = blockIdx.x * 4 + wid;
  if (n >= NN) return;
  int cur = n;
  while (cur >= 0) {
    int b = ioff[cur], e2 = ioff[cur + 1];
    u64 bestKey = 0;
    for (int i = b + lane; i < e2; i += 64) {
      int e = ieids[i];
      u64 k = ekey[e];
      if (k <= bestKey) continue;
      int s = src[e], d = dst[e];
      int v = (s == cur) ? d : s;
      u64 sv = __hip_atomic_load(&S[v], __ATOMIC_RELAXED, __HIP_MEMORY_SCOPE_AGENT);
      if (k > sv) bestKey = k;
    }
#pragma unroll
    for (int o = 32; o > 0; o >>= 1) {
      u64 other = __shfl_xor(bestKey, o, 64);
      if (other > bestKey) bestKey = other;
    }
    int next = -1;
    if (bestKey != 0) {
      if (lane == 0) {
        int e = (int)(0xFFFFFFFFu - (u32)(bestKey & 0xFFFFFFFFull));
        int s = src[e], d = dst[e];
        int bestV = (s == cur) ? d : s;
        u64 old = atomicMax(&S[bestV], bestKey);
        if (old >= bestKey) {
          next = cur;                        // lost race; re-seek same node
        } else if (old != 0) {
          int eo = (int)(0xFFFFFFFFu - (u32)(old & 0xFFFFFFFFull));
          int so = src[eo], do_ = dst[eo];
          next = (so == bestV) ? do_ : so;   // displaced proposer re-seeks
        }                                    // old==0: accepted, next=-1
      }
      next = __shfl(next, 0, 64);
    }
    cur = next;
  }
}

// mutual proposals -> matched pair; rep-side thread writes cluster/chosen
__global__ void k_resolve(const int* __restrict__ src, const int* __restrict__ dst,
                          const u64* __restrict__ S, int* __restrict__ cluster,
                          int* __restrict__ chosen) {
  int n = blockIdx.x * 256 + threadIdx.x;
  if (n >= NN) return;
  u64 k = S[n];
  if (!k) return;
  int e = (int)(0xFFFFFFFFu - (u32)(k & 0xFFFFFFFFull));
  int s = src[e], d = dst[e];
  int rep = s < d ? s : d;
  if (n != rep) return;
  if (S[s] == k && S[d] == k) {
    int oth = s < d ? d : s;
    cluster[oth] = rep;
    chosen[rep] = e;
  }
}

// new_x gather (clusters have <=2 members) + nvb update + zero bcount/bcursor
__global__ __launch_bounds__(256) void k_new_x(
    const int* __restrict__ cluster, const int* __restrict__ chosen,
    const int* __restrict__ src, const int* __restrict__ dst,
    const float* __restrict__ score, const float* __restrict__ x,
    float* __restrict__ out, int* __restrict__ nvb, int* __restrict__ b3zero) {
  int gt = blockIdx.x * 256 + threadIdx.x;
  if (gt < 2 * NN) b3zero[gt] = 0;
  int grp = threadIdx.x >> 5;
  int lane = threadIdx.x & 31;
  int n = blockIdx.x * 8 + grp;
  if (n >= NN) return;
  float4 v = make_float4(0.f, 0.f, 0.f, 0.f);
  bool rep = (cluster[n] == n);
  if (rep) {
    v = *(const float4*)(x + (size_t)n * HID + lane * 4);
    int ch = chosen[n];
    if (ch >= 0) {
      int s = src[ch], d = dst[ch];
      int partner = (s == n) ? d : s;
      float4 w = *(const float4*)(x + (size_t)partner * HID + lane * 4);
      float sc = score[ch];
      v.x = (v.x + w.x) * sc; v.y = (v.y + w.y) * sc;
      v.z = (v.z + w.z) * sc; v.w = (v.w + w.w) * sc;
    }
  }
  *(float4*)(out + (size_t)n * HID + lane * 4) = v;
  if (lane == 0) nvb[n] = (nvb[n] && rep) ? 1 : 0;
}

// ---------------- dedup (sorted unique of (cs,cd)) ----------------
__global__ void k_bucket_count(const int* __restrict__ pE, const int* __restrict__ src,
                               const int* __restrict__ cluster, int* __restrict__ bcount) {
  int e = blockIdx.x * 256 + threadIdx.x;
  if (e >= *pE) return;
  atomicAdd(&bcount[cluster[src[e]]], 1);
}

__global__ __launch_bounds__(1024) void k_scan(const int* __restrict__ in, int* __restrict__ out,
                                               int n, int* totalDst) {
  __shared__ int part[1024];
  int t = threadIdx.x;
  int chunk = (n + 1023) / 1024;
  int b = t * chunk, e = b + chunk;
  if (b > n) b = n;
  if (e > n) e = n;
  int s = 0;
  for (int i = b; i < e; i++) s += in[i];
  part[t] = s;
  __syncthreads();
  for (int off = 1; off < 1024; off <<= 1) {
    int v = (t >= off) ? part[t - off] : 0;
    __syncthreads();
    part[t] += v;
    __syncthreads();
  }
  int excl = (t == 0) ? 0 : part[t - 1];
  int total = part[1023];
  for (int i = b; i < e; i++) { out[i] = excl; excl += in[i]; }
  if (t == 0) {
    out[n] = total;
    if (totalDst) *totalDst = total;
  }
}

__global__ void k_bucket_scatter(const int* __restrict__ pE, const int* __restrict__ src,
                                 const int* __restrict__ dst, const int* __restrict__ cluster,
                                 const int* __restrict__ boffs, int* __restrict__ bcursor,
                                 int* __restrict__ bucket) {
  int e = blockIdx.x * 256 + threadIdx.x;
  if (e >= *pE) return;
  int cs = cluster[src[e]], cd = cluster[dst[e]];
  int pos = boffs[cs] + atomicAdd(&bcursor[cs], 1);
  bucket[pos] = cd;
}

// sorted-unique per bucket via per-wave LDS bitmap (no comparison sort, no O(d^2)).
__global__ __launch_bounds__(256) void k_dedup_bitmap(
    const int* __restrict__ boffs, int* __restrict__ bucket,
    int* __restrict__ ucount) {
  __shared__ u32 bm[4][960];
  int wid = threadIdx.x >> 6;
  int lane = threadIdx.x & 63;
  int n = blockIdx.x * 4 + wid;
  int b = boffs[n], e = boffs[n + 1];
  for (int w = lane; w < 960; w += 64) bm[wid][w] = 0;
  __syncthreads();
  for (int i = b + lane; i < e; i += 64)
    atomicOr(&bm[wid][bucket[i] >> 5], 1u << (bucket[i] & 31));
  __syncthreads();
  int w0 = lane * 15;
  int w1 = w0 + 15; if (w1 > WPB) w1 = WPB;
  int cnt = 0;
  for (int w = w0; w < w1; w++) cnt += __popc(bm[wid][w]);
  int inc = cnt;
  for (int o = 1; o < 64; o <<= 1) { int v = __shfl_up(inc, o); if (lane >= o) inc += v; }
  int excl = inc - cnt;
  int total = __shfl(inc, 63);
  int pos = b + excl;
  for (int w = w0; w < w1; w++) {
    u32 v = bm[wid][w];
    while (v) { int bit = __ffs(v) - 1; bucket[pos++] = (w << 5) | bit; v &= v - 1; }
  }
  if (lane == 0) ucount[n] = total;
}

// emit compacted edges + zero bcount/bcursor/icnt/icursor/pcnt for next level
__global__ void k_emit(const int* __restrict__ boffs, const int* __restrict__ bucket,
                       const int* __restrict__ bucount, const int* __restrict__ bnoffs,
                       int* __restrict__ srcO, int* __restrict__ dstO,
                       int* __restrict__ b3zero, int* __restrict__ i2zero,
                       int* __restrict__ pcnt) {
  int t = blockIdx.x * 256 + threadIdx.x;
  int stride = gridDim.x * 256;
  for (int z = t; z < 2 * NN; z += stride) { b3zero[z] = 0; i2zero[z] = 0; }
  if (t == 0) *pcnt = 0;
  if (t >= NN) return;
  int u = bucount[t], b = boffs[t], o = bnoffs[t];
  for (int i = 0; i < u; i++) { srcO[o + i] = t; dstO[o + i] = bucket[b + i]; }
}

// ---------------- readout ----------------
__global__ void k_graph_pool(const int* __restrict__ nvb, const int* __restrict__ batch,
                             const float* __restrict__ x, float* __restrict__ gsum,
                             float* __restrict__ gcnt) {
  int t = blockIdx.x * 256 + threadIdx.x;
  int n = t >> 2;
  if (n >= NN) return;
  if (!nvb[n]) return;
  int sub = t & 3;
  int g = batch[n];
  const float* xr = x + (size_t)n * HID + sub * 32;
  float* o = gsum + (size_t)g * HID + sub * 32;
#pragma unroll
  for (int i = 0; i < 8; i++) {
    float4 v = *(const float4*)(xr + i * 4);
    atomicAdd(o + i * 4 + 0, v.x); atomicAdd(o + i * 4 + 1, v.y);
    atomicAdd(o + i * 4 + 2, v.z); atomicAdd(o + i * 4 + 3, v.w);
  }
  if (sub == 0) atomicAdd(&gcnt[g], 1.0f);
}

__global__ __launch_bounds__(128) void k_head1(const float* __restrict__ gsum,
                                               const float* __restrict__ gcnt,
                                               const float* __restrict__ Wf1,
                                               const float* __restrict__ bf1,
                                               float* __restrict__ hfc) {
  int g = blockIdx.x;
  int j = threadIdx.x;
  __shared__ float p[HID];
  float c = fmaxf(gcnt[g], 1.f);
  p[j] = gsum[g * HID + j] / c;
  __syncthreads();
  float s = bf1[j];
  const float* w = Wf1 + (size_t)j * HID;
  for (int k = 0; k < HID; k++) s += p[k] * w[k];
  hfc[g * HID + j] = fmaxf(s, 0.f);
}

__global__ void k_head2(const float* __restrict__ hfc, const float* __restrict__ Wf2,
                        const float* __restrict__ bf2, float* __restrict__ out) {
  int g = blockIdx.x;
  int t = threadIdx.x;
  __shared__ float lg[NC];
  if (t < NC) {
    float s = bf2[t];
    const float* w = Wf2 + (size_t)t * HID;
    const float* h = hfc + (size_t)g * HID;
    for (int k = 0; k < HID; k++) s += h[k] * w[k];
    lg[t] = s;
  }
  __syncthreads();
  if (t == 0) {
    float m = lg[0];
    for (int c = 1; c < NC; c++) m = fmaxf(m, lg[c]);
    float se = 0.f;
    for (int c = 0; c < NC; c++) se += expf(lg[c] - m);
    float lse = m + logf(se);
    for (int c = 0; c < NC; c++) out[g * NC + c] = lg[c] - lse;
  }
}

extern "C" void kernel_launch(void* const* d_in, const int* in_sizes, int n_in,
                              void* d_out, int out_size, void* d_ws, size_t ws_size,
                              hipStream_t stream) {
  const float* x0 = (const float*)d_in[0];
  const int* ei = (const int*)d_in[1];
  const int* batch = (const int*)d_in[2];
  const float* Wl = (const float*)d_in[3];
  const float* bl = (const float*)d_in[4];
  const float* Wr = (const float*)d_in[5];
  const float* gamma = (const float*)d_in[6];
  const float* beta = (const float*)d_in[7];
  const float* Wlin = (const float*)d_in[8];
  const float* blin = (const float*)d_in[9];
  const float* Wp = (const float*)d_in[10];
  const float* bp = (const float*)d_in[11];
  const float* Wf1 = (const float*)d_in[12];
  const float* bf1 = (const float*)d_in[13];
  const float* Wf2 = (const float*)d_in[14];
  const float* bf2 = (const float*)d_in[15];
  float* out = (float*)d_out;

  const int NH = NN * HID;
  size_t off = 0;
  char* base = (char*)d_ws;
  auto carve = [&](size_t bytes) -> char* {
    char* p = base + off;
    off += (bytes + 255) & ~(size_t)255;
    return p;
  };
  float* xa = (float*)carve((size_t)NH * 4);
  float* xb = (float*)carve((size_t)NH * 4);
  float* xc = (float*)carve((size_t)NH * 4);
  float* xd = (float*)carve((size_t)NH * 4);
  int* srcA = (int*)carve((size_t)NE * 4);
  int* dstA = (int*)carve((size_t)NE * 4);
  int* srcB = (int*)carve((size_t)NE * 4);
  int* dstB = (int*)carve((size_t)NE * 4);
  float* escore = (float*)carve((size_t)NE * 4);
  int* ebucket = (int*)carve((size_t)NE * 4);
  int* eids = (int*)carve((size_t)NE * 4);
  u64* ekey = (u64*)carve((size_t)NE * 8);
  int* ieids = (int*)carve((size_t)2 * NE * 4);
  u64* S = (u64*)carve((size_t)NN * 8);
  float* npx1 = (float*)carve((size_t)NN * 4);
  float* npx2 = (float*)carve((size_t)NN * 4);
  int* ncluster = (int*)carve((size_t)NN * 4);
  int* nchosen = (int*)carve((size_t)NN * 4);
  int* nvb = (int*)carve((size_t)NN * 4);
  int* b3 = (int*)carve((size_t)3 * NN * 4);
  int* bcount = b3;
  int* bcursor = b3 + NN;
  int* bucount = b3 + 2 * NN;
  int* i2 = (int*)carve((size_t)2 * NN * 4);
  int* icnt = i2;
  int* icursor = i2 + NN;
  int* boffs = (int*)carve((size_t)(NN + 1) * 4);
  int* bnoffs = (int*)carve((size_t)(NN + 1) * 4);
  int* csroff = (int*)carve((size_t)(NN + 1) * 4);
  int* ioff = (int*)carve((size_t)(NN + 1) * 4);
  double* bnsum = (double*)carve((size_t)2 * HID * 8);
  float* gbuf = (float*)carve((size_t)(NG * HID + NG) * 4);
  float* gsum = gbuf;
  float* gcnt = gbuf + NG * HID;
  float* ghfc = (float*)carve((size_t)NG * HID * 4);
  int* scal = (int*)carve(64 * 4);
  (void)ws_size; (void)n_in; (void)in_sizes; (void)out_size;

  int* pE = scal;        // E_cur
  int* pcnt = scal + 1;  // valid node count

  hipMemcpyAsync(xa, x0, (size_t)NH * 4, hipMemcpyDeviceToDevice, stream);
  k_init<<<1875, 256, 0, stream>>>(ei, srcA, dstA, nvb, scal, b3, i2, gbuf);

  int* srcC = srcA; int* dstC = dstA; int* srcN = srcB; int* dstN = dstB;
  float* xcur = xa;
  float* xtmp = xd;

  auto sage = [&](const float* xin, float* xout, int L) {
    k_sage_gather<<<3750, 256, 0, stream>>>(csroff, eids, srcC, xin, xtmp);
    gemm_dual<<<469, 256, 0, stream>>>(xtmp, Wl + (size_t)L * HID * HID, xin,
                                       Wr + (size_t)L * HID * HID, bl + (size_t)L * HID,
                                       xout, NN, HID, 1, bnsum);
    k_bn_stats<<<469, 128, 0, stream>>>(xout, nvb, bnsum);
    k_bn_apply<<<15000, 256, 0, stream>>>(xout, bnsum, pcnt, gamma + (size_t)L * HID,
                                          beta + (size_t)L * HID);
  };

  for (int b = 0; b < 3; b++) {
    // dst-CSR (sage + softmax) and incidence-CSR (suitor), one count/scan/scatter chain
    k_csr_count<<<1875, 256, 0, stream>>>(pE, srcC, dstC, bcount, icnt, nvb, pcnt);
    k_scan2<<<2, 1024, 0, stream>>>(bcount, csroff, icnt, ioff);
    k_csr_scatter<<<1875, 256, 0, stream>>>(pE, srcC, dstC, csroff, bcursor, eids,
                                            ioff, icursor, ieids);

    sage(xcur, xb, 2 * b);
    sage(xb, xc, 2 * b + 1);
    gemm_dual<<<469, 256, 0, stream>>>(xc, Wlin + (size_t)b * HID * 2 * HID, xb,
                                       Wlin + (size_t)b * HID * 2 * HID + HID,
                                       blin + (size_t)b * HID, xcur, NN, 2 * HID, 0, bnsum);

    // ----- edge pooling: softmax scores -> suitor matching -> resolve -----
    k_node_proj<<<118, 256, 0, stream>>>(xcur, Wp + (size_t)b * 2 * HID, npx1, npx2);
    k_edge_softmax_seed<<<118, 256, 0, stream>>>(csroff, eids, srcC, npx1, npx2, bp + b,
                                                 escore, ekey, ncluster, nchosen, S);
    k_suitor<<<7500, 256, 0, stream>>>(ioff, ieids, srcC, dstC, ekey, S);
    k_resolve<<<118, 256, 0, stream>>>(srcC, dstC, S, ncluster, nchosen);
    k_new_x<<<3750, 256, 0, stream>>>(ncluster, nchosen, srcC, dstC, escore, xcur, xtmp,
                                      nvb, b3);

    if (b < 2) {  // level-2 coarse edges are never consumed
      k_bucket_count<<<1875, 256, 0, stream>>>(pE, srcC, ncluster, bcount);
      k_scan<<<1, 1024, 0, stream>>>(bcount, boffs, NN, (int*)nullptr);
      k_bucket_scatter<<<1875, 256, 0, stream>>>(pE, srcC, dstC, ncluster, boffs, bcursor,
                                                 ebucket);
      k_dedup_bitmap<<<7500, 256, 0, stream>>>(boffs, ebucket, bucount);
      k_scan<<<1, 1024, 0, stream>>>(bucount, bnoffs, NN, pE);
      k_emit<<<235, 256, 0, stream>>>(boffs, ebucket, bucount, bnoffs, srcN, dstN,
                                      b3, i2, pcnt);
      { int* t = srcC; srcC = srcN; srcN = t; t = dstC; dstC = dstN; dstN = t; }
    }
    { float* t = xcur; xcur = xtmp; xtmp = t; }
  }

  k_graph_pool<<<469, 256, 0, stream>>>(nvb, batch, xcur, gsum, gcnt);
  k_head1<<<NG, 128, 0, stream>>>(gsum, gcnt, Wf1, bf1, ghfc);
  k_head2<<<NG, 32, 0, stream>>>(ghfc, Wf2, bf2, out);
}

// Round 8
// 3008.446 us; speedup vs baseline: 16.4220x; 1.0329x over previous
//
#include <hip/hip_runtime.h>
#include <stdint.h>

#define NN 30000
#define NE 480000
#define HID 128
#define NG 128
#define NC 6
#define BN_EPS 1e-5f
#define WPB 938   // ceil(NN/32) bitmap words
#define SLOTS 4   // reg-resident suitor entries per lane (deg <= 256)

typedef unsigned int u32;
typedef unsigned long long u64;

// ---------------- init (also zeroes all per-call state) ----------------
__global__ void k_init(const int* __restrict__ ei, int* srcA, int* dstA, int* nvb,
                       int* scal, int* b3, int* i2, float* gbuf) {
  int t = blockIdx.x * 256 + threadIdx.x;
  if (t < NE) { srcA[t] = ei[t]; dstA[t] = ei[NE + t]; }
  if (t < NN) nvb[t] = 1;
  if (t < 2 * NN) { b3[t] = 0; i2[t] = 0; }   // bcount,bcursor + icnt,icursor
  if (t < NG * HID + NG) gbuf[t] = 0.f;
  if (t == 0) { scal[0] = NE; scal[1] = 0; }
}

// ---------------- CSR build (dst CSR + incidence CSR) + valid-node count ----------------
__global__ void k_csr_count(const int* __restrict__ pE, const int* __restrict__ src,
                            const int* __restrict__ dst, int* __restrict__ cnt,
                            int* __restrict__ icnt, const int* __restrict__ nvb,
                            int* __restrict__ pcnt) {
  int t = blockIdx.x * 256 + threadIdx.x;
  if (t < NN && nvb[t]) atomicAdd(pcnt, 1);
  if (t < *pE) {
    int s = src[t], d = dst[t];
    atomicAdd(&cnt[d], 1);
    if (s != d) { atomicAdd(&icnt[s], 1); atomicAdd(&icnt[d], 1); }
  }
}

// two independent single-block scans (block 0: dst-CSR, block 1: incidence)
__global__ __launch_bounds__(1024) void k_scan2(const int* __restrict__ in0, int* __restrict__ out0,
                                                const int* __restrict__ in1, int* __restrict__ out1) {
  const int* in = blockIdx.x ? in1 : in0;
  int* out = blockIdx.x ? out1 : out0;
  __shared__ int part[1024];
  int t = threadIdx.x;
  int chunk = (NN + 1023) / 1024;
  int b = t * chunk, e = b + chunk;
  if (b > NN) b = NN;
  if (e > NN) e = NN;
  int s = 0;
  for (int i = b; i < e; i++) s += in[i];
  part[t] = s;
  __syncthreads();
  for (int off = 1; off < 1024; off <<= 1) {
    int v = (t >= off) ? part[t - off] : 0;
    __syncthreads();
    part[t] += v;
    __syncthreads();
  }
  int excl = (t == 0) ? 0 : part[t - 1];
  for (int i = b; i < e; i++) { out[i] = excl; excl += in[i]; }
  if (t == 0) out[NN] = part[1023];
}

__global__ void k_csr_scatter(const int* __restrict__ pE, const int* __restrict__ src,
                              const int* __restrict__ dst, const int* __restrict__ coff,
                              int* __restrict__ cursor, int* __restrict__ eids,
                              const int* __restrict__ ioff, int* __restrict__ icur,
                              int* __restrict__ ieids) {
  int e = blockIdx.x * 256 + threadIdx.x;
  if (e >= *pE) return;
  int s = src[e], d = dst[e];
  int pos = coff[d] + atomicAdd(&cursor[d], 1);
  eids[pos] = e;
  if (s != d) {
    int p1 = ioff[s] + atomicAdd(&icur[s], 1); ieids[p1] = e;
    int p2 = ioff[d] + atomicAdd(&icur[d], 1); ieids[p2] = e;
  }
}

// ---------------- SAGE mean aggregation: CSR gather, 32 lanes/node ----------------
__global__ __launch_bounds__(256) void k_sage_gather(
    const int* __restrict__ coff, const int* __restrict__ eids,
    const int* __restrict__ src, const float* __restrict__ x,
    float* __restrict__ mean) {
  int grp = threadIdx.x >> 5;           // 8 nodes per block
  int lane = threadIdx.x & 31;
  int n = blockIdx.x * 8 + grp;
  if (n >= NN) return;
  int b = coff[n], e2 = coff[n + 1];
  float4 acc = make_float4(0.f, 0.f, 0.f, 0.f);
  for (int i = b; i < e2; i++) {
    int s = src[eids[i]];
    float4 v = *(const float4*)(x + (size_t)s * HID + lane * 4);
    acc.x += v.x; acc.y += v.y; acc.z += v.z; acc.w += v.w;
  }
  float inv = 1.0f / fmaxf((float)(e2 - b), 1.0f);
  acc.x *= inv; acc.y *= inv; acc.z *= inv; acc.w *= inv;
  *(float4*)(mean + (size_t)n * HID + lane * 4) = acc;
}

// out[n][j] = A1@W1^T + A2@W2^T + bias; optional relu. Also zeroes bnsum (block 0).
__global__ __launch_bounds__(256) void gemm_dual(
    const float* __restrict__ A1, const float* __restrict__ W1,
    const float* __restrict__ A2, const float* __restrict__ W2,
    const float* __restrict__ bias, float* __restrict__ out,
    int M, int ldw, int relu, double* __restrict__ bnsum) {
  if (blockIdx.x == 0 && threadIdx.x < 2 * HID) bnsum[threadIdx.x] = 0.0;
  __shared__ float As[64][33];
  __shared__ float Ws[32][132];  // transposed: Ws[kk][j]
  int row0 = blockIdx.x * 64;
  int tid = threadIdx.x;
  int cid = tid & 31;
  int rid = tid >> 5;
  float acc[8][4];
#pragma unroll
  for (int r = 0; r < 8; r++)
#pragma unroll
    for (int c = 0; c < 4; c++) acc[r][c] = 0.f;

  for (int srcI = 0; srcI < 2; ++srcI) {
    const float* A = srcI ? A2 : A1;
    const float* W = srcI ? W2 : W1;
    for (int kc = 0; kc < 128; kc += 32) {
#pragma unroll
      for (int i = 0; i < 2; ++i) {
        int idx = tid + i * 256;
        int r = idx >> 3;
        int c4 = (idx & 7) << 2;
        int gr = row0 + r;
        float4 v = make_float4(0.f, 0.f, 0.f, 0.f);
        if (gr < M) v = *(const float4*)(A + (size_t)gr * 128 + kc + c4);
        As[r][c4 + 0] = v.x; As[r][c4 + 1] = v.y; As[r][c4 + 2] = v.z; As[r][c4 + 3] = v.w;
      }
#pragma unroll
      for (int i = 0; i < 4; ++i) {
        int idx = tid + i * 256;
        int j = idx >> 3;
        int c4 = (idx & 7) << 2;
        float4 v = *(const float4*)(W + (size_t)j * ldw + kc + c4);
        Ws[c4 + 0][j] = v.x; Ws[c4 + 1][j] = v.y; Ws[c4 + 2][j] = v.z; Ws[c4 + 3][j] = v.w;
      }
      __syncthreads();
#pragma unroll
      for (int kk = 0; kk < 32; ++kk) {
        float4 w = *(const float4*)(&Ws[kk][cid * 4]);
#pragma unroll
        for (int r = 0; r < 8; ++r) {
          float a = As[rid * 8 + r][kk];
          acc[r][0] += a * w.x; acc[r][1] += a * w.y; acc[r][2] += a * w.z; acc[r][3] += a * w.w;
        }
      }
      __syncthreads();
    }
  }
#pragma unroll
  for (int r = 0; r < 8; ++r) {
    int gr = row0 + rid * 8 + r;
    if (gr >= M) continue;
#pragma unroll
    for (int c = 0; c < 4; ++c) {
      float v = acc[r][c] + bias[cid * 4 + c];
      if (relu) v = fmaxf(v, 0.f);
      out[(size_t)gr * 128 + cid * 4 + c] = v;
    }
  }
}

__global__ __launch_bounds__(128) void k_bn_stats(const float* __restrict__ x,
                                                  const int* __restrict__ nvb,
                                                  double* __restrict__ sums) {
  int k = threadIdx.x;
  int n0 = blockIdx.x * 64;
  float s = 0.f, q = 0.f;
  for (int r = 0; r < 64; r++) {
    int n = n0 + r;
    if (n >= NN) break;
    if (!nvb[n]) continue;
    float v = x[(size_t)n * HID + k];
    s += v; q += v * v;
  }
  atomicAdd(&sums[k], (double)s);
  atomicAdd(&sums[HID + k], (double)q);
}

__global__ void k_bn_apply(float* __restrict__ x, const double* __restrict__ sums,
                           const int* __restrict__ cnt, const float* __restrict__ gamma,
                           const float* __restrict__ beta) {
  int t = blockIdx.x * 256 + threadIdx.x;
  if (t >= NN * HID) return;
  int k = t & 127;
  double c = (double)((*cnt > 1) ? *cnt : 1);
  double mu = sums[k] / c;
  double var = sums[HID + k] / c - mu * mu;
  if (var < 0.0) var = 0.0;
  float inv = (float)(1.0 / sqrt(var + (double)BN_EPS));
  x[t] = gamma[k] * (x[t] - (float)mu) * inv + beta[k];
}

// ---------------- edge pool ----------------
__global__ void k_node_proj(const float* __restrict__ x, const float* __restrict__ Wp,
                            float* __restrict__ px1, float* __restrict__ px2) {
  int n = blockIdx.x * 256 + threadIdx.x;
  if (n >= NN) return;
  const float* xr = x + (size_t)n * HID;
  float s1 = 0.f, s2 = 0.f;
#pragma unroll 8
  for (int k = 0; k < HID; k += 4) {
    float4 v = *(const float4*)(xr + k);
    float4 w1 = *(const float4*)(Wp + k);
    float4 w2 = *(const float4*)(Wp + HID + k);
    s1 += v.x * w1.x + v.y * w1.y + v.z * w1.z + v.w * w1.w;
    s2 += v.x * w2.x + v.y * w2.y + v.z * w2.z + v.w * w2.w;
  }
  px1[n] = s1; px2[n] = s2;
}

// fused: S init + per-dst softmax + suitor keys
__global__ void k_edge_softmax_seed(
    const int* __restrict__ coff, const int* __restrict__ eids,
    const int* __restrict__ src, const float* __restrict__ px1,
    const float* __restrict__ px2, const float* __restrict__ bp,
    float* __restrict__ score, u64* __restrict__ ekey, u64* __restrict__ S) {
  int n = blockIdx.x * 256 + threadIdx.x;
  if (n >= NN) return;
  S[n] = 0ull;
  int b = coff[n], e2 = coff[n + 1];
  if (b == e2) return;
  float p2 = px2[n] + *bp;
  float mx = -3.4e38f;
  for (int i = b; i < e2; i++) {
    float r = px1[src[eids[i]]] + p2;
    mx = fmaxf(mx, r);
  }
  double den = 0.0;
  for (int i = b; i < e2; i++) {
    int eid = eids[i];
    float z = expf(px1[src[eid]] + p2 - mx);
    score[eid] = z;
    den += (double)z;
  }
  if (den < 1e-16) den = 1e-16;
  double invd = 1.0 / den;
  for (int i = b; i < e2; i++) {
    int eid = eids[i];
    float sc = (float)((double)score[eid] * invd) + 0.5f;
    score[eid] = sc;
    // key: score desc, then lower edge index wins (matches stable argsort(-score))
    ekey[eid] = ((u64)__float_as_uint(sc) << 32) | (u64)(0xFFFFFFFFu - (u32)eid);
  }
}

// ---------------- Suitor matching, wave-per-node, register-resident ----------------
// v3: candidate list (key, partner) loaded ONCE into registers per node-visit
// (<= SLOTS*64 entries); re-passes after lost races touch only alive slots with
// a single atomic S-load each. Slot killing is permanent (S monotone): observe
// S[v] >= key(e) -> e can never be matched -> drop. Lost race's atomicMax return
// value kills its own slot authoritatively -> guaranteed progress, no streaming
// re-reads (round-7: 260 MB HBM fetch/level from per-pass re-scans).
__global__ __launch_bounds__(256) void k_suitor(
    const int* __restrict__ ioff, const int* __restrict__ ieids,
    const int* __restrict__ src, const int* __restrict__ dst,
    const u64* __restrict__ ekey, u64* __restrict__ S) {
  int wid = threadIdx.x >> 6;
  int lane = threadIdx.x & 63;
  int n = blockIdx.x * 4 + wid;
  if (n >= NN) return;
  int cur = n;
  while (cur >= 0) {
    int b = ioff[cur], e2 = ioff[cur + 1];
    int deg = e2 - b;
    if (deg == 0) break;
    if (deg <= 64 * SLOTS) {
      // ---- register-resident path ----
      u64 key[SLOTS]; int pv[SLOTS];
#pragma unroll
      for (int s = 0; s < SLOTS; s++) {
        key[s] = 0; pv[s] = 0;
        int i = b + s * 64 + lane;
        if (i < e2) {
          int e = ieids[i];
          key[s] = ekey[e];
          int es = src[e], ed = dst[e];
          pv[s] = (es == cur) ? ed : es;
        }
      }
      long long res;
      for (;;) {
        u64 localBest = 0;
#pragma unroll
        for (int s = 0; s < SLOTS; s++) {
          if (!key[s]) continue;
          u64 sv = __hip_atomic_load(&S[pv[s]], __ATOMIC_RELAXED, __HIP_MEMORY_SCOPE_AGENT);
          if (sv >= key[s]) key[s] = 0;              // permanently dead
          else if (key[s] > localBest) localBest = key[s];
        }
        u64 bestKey = localBest;
#pragma unroll
        for (int o = 32; o > 0; o >>= 1) {
          u64 other = __shfl_xor(bestKey, o, 64);
          if (other > bestKey) bestKey = other;
        }
        if (bestKey == 0) { res = -1; break; }       // nothing proposable
        int ms = -1;
#pragma unroll
        for (int s = 0; s < SLOTS; s++)
          if (ms < 0 && key[s] == bestKey) ms = s;
        u64 ball = __ballot(ms >= 0);
        int owner = (int)(__ffsll((long long)ball) - 1);
        long long r0 = -3;
        if (lane == owner) {
          int bv = pv[ms];
          u64 old = atomicMax(&S[bv], bestKey);
          if (old >= bestKey) { key[ms] = 0; r0 = -2; }          // lost race; retry cur
          else if (old == 0) r0 = -1;                            // accepted, chain ends
          else {
            int eo = (int)(0xFFFFFFFFu - (u32)(old & 0xFFFFFFFFull));
            int so = src[eo], do_ = dst[eo];
            r0 = (so == bv) ? do_ : so;                          // displaced re-seeks
          }
        }
        res = __shfl(r0, owner, 64);
        if (res != -2) break;
      }
      if (res < 0) break;
      cur = (int)res;
    } else {
      // ---- fallback memory path (rare high-degree nodes) ----
      u64 bestKey = 0;
      for (int i = b + lane; i < e2; i += 64) {
        int e = ieids[i];
        u64 k = ekey[e];
        if (k <= bestKey) continue;
        int es = src[e], ed = dst[e];
        int v = (es == cur) ? ed : es;
        u64 sv = __hip_atomic_load(&S[v], __ATOMIC_RELAXED, __HIP_MEMORY_SCOPE_AGENT);
        if (k > sv) bestKey = k;
      }
#pragma unroll
      for (int o = 32; o > 0; o >>= 1) {
        u64 other = __shfl_xor(bestKey, o, 64);
        if (other > bestKey) bestKey = other;
      }
      long long r0 = -1;
      if (bestKey != 0 && lane == 0) {
        int e = (int)(0xFFFFFFFFu - (u32)(bestKey & 0xFFFFFFFFull));
        int es = src[e], ed = dst[e];
        int bv = (es == cur) ? ed : es;
        u64 old = atomicMax(&S[bv], bestKey);
        if (old >= bestKey) r0 = cur;                            // rescan
        else if (old != 0) {
          int eo = (int)(0xFFFFFFFFu - (u32)(old & 0xFFFFFFFFull));
          int so = src[eo], do_ = dst[eo];
          r0 = (so == bv) ? do_ : so;
        }
      }
      long long res = (bestKey != 0) ? __shfl(r0, 0, 64) : -1;
      cur = (int)res;
    }
  }
}

// new_x gather + cluster derivation from S (resolve fused in) + nvb update + zero b3
__global__ __launch_bounds__(256) void k_new_x(
    const u64* __restrict__ S, const int* __restrict__ src, const int* __restrict__ dst,
    const float* __restrict__ score, const float* __restrict__ x,
    float* __restrict__ out, int* __restrict__ cluster,
    int* __restrict__ nvb, int* __restrict__ b3zero) {
  int gt = blockIdx.x * 256 + threadIdx.x;
  if (gt < 2 * NN) b3zero[gt] = 0;
  int grp = threadIdx.x >> 5;
  int lane = threadIdx.x & 31;
  int n = blockIdx.x * 8 + grp;
  if (n >= NN) return;
  // derive match state from S (uniform within the 32-lane group)
  u64 k = S[n];
  int partner = -1;
  bool isOth = false;
  float sc = 1.f;
  if (k) {
    int e = (int)(0xFFFFFFFFu - (u32)(k & 0xFFFFFFFFull));
    int s = src[e], d = dst[e];
    int other = (s == n) ? d : s;
    if (S[other] == k) {                 // mutual -> matched pair
      if (n > other) isOth = true;       // n is the non-representative
      else { partner = other; sc = score[e]; }
    }
  }
  float4 v = make_float4(0.f, 0.f, 0.f, 0.f);
  if (!isOth) {
    v = *(const float4*)(x + (size_t)n * HID + lane * 4);
    if (partner >= 0) {
      float4 w = *(const float4*)(x + (size_t)partner * HID + lane * 4);
      v.x = (v.x + w.x) * sc; v.y = (v.y + w.y) * sc;
      v.z = (v.z + w.z) * sc; v.w = (v.w + w.w) * sc;
    }
  }
  *(float4*)(out + (size_t)n * HID + lane * 4) = v;
  if (lane == 0) {
    int e2 = (int)(0xFFFFFFFFu - (u32)(k & 0xFFFFFFFFull));
    int s2 = isOth ? src[e2] : n;
    int d2 = isOth ? dst[e2] : n;
    cluster[n] = isOth ? (s2 < d2 ? s2 : d2) : n;
    nvb[n] = (nvb[n] && !isOth) ? 1 : 0;
  }
}

// ---------------- dedup (sorted unique of (cs,cd)) ----------------
__global__ void k_bucket_count(const int* __restrict__ pE, const int* __restrict__ src,
                               const int* __restrict__ cluster, int* __restrict__ bcount) {
  int e = blockIdx.x * 256 + threadIdx.x;
  if (e >= *pE) return;
  atomicAdd(&bcount[cluster[src[e]]], 1);
}

__global__ __launch_bounds__(1024) void k_scan(const int* __restrict__ in, int* __restrict__ out,
                                               int n, int* totalDst) {
  __shared__ int part[1024];
  int t = threadIdx.x;
  int chunk = (n + 1023) / 1024;
  int b = t * chunk, e = b + chunk;
  if (b > n) b = n;
  if (e > n) e = n;
  int s = 0;
  for (int i = b; i < e; i++) s += in[i];
  part[t] = s;
  __syncthreads();
  for (int off = 1; off < 1024; off <<= 1) {
    int v = (t >= off) ? part[t - off] : 0;
    __syncthreads();
    part[t] += v;
    __syncthreads();
  }
  int excl = (t == 0) ? 0 : part[t - 1];
  int total = part[1023];
  for (int i = b; i < e; i++) { out[i] = excl; excl += in[i]; }
  if (t == 0) {
    out[n] = total;
    if (totalDst) *totalDst = total;
  }
}

__global__ void k_bucket_scatter(const int* __restrict__ pE, const int* __restrict__ src,
                                 const int* __restrict__ dst, const int* __restrict__ cluster,
                                 const int* __restrict__ boffs, int* __restrict__ bcursor,
                                 int* __restrict__ bucket) {
  int e = blockIdx.x * 256 + threadIdx.x;
  if (e >= *pE) return;
  int cs = cluster[src[e]], cd = cluster[dst[e]];
  int pos = boffs[cs] + atomicAdd(&bcursor[cs], 1);
  bucket[pos] = cd;
}

// sorted-unique per bucket via per-wave LDS bitmap (no comparison sort, no O(d^2)).
__global__ __launch_bounds__(256) void k_dedup_bitmap(
    const int* __restrict__ boffs, int* __restrict__ bucket,
    int* __restrict__ ucount) {
  __shared__ u32 bm[4][960];
  int wid = threadIdx.x >> 6;
  int lane = threadIdx.x & 63;
  int n = blockIdx.x * 4 + wid;
  int b = boffs[n], e = boffs[n + 1];
  for (int w = lane; w < 960; w += 64) bm[wid][w] = 0;
  __syncthreads();
  for (int i = b + lane; i < e; i += 64)
    atomicOr(&bm[wid][bucket[i] >> 5], 1u << (bucket[i] & 31));
  __syncthreads();
  int w0 = lane * 15;
  int w1 = w0 + 15; if (w1 > WPB) w1 = WPB;
  int cnt = 0;
  for (int w = w0; w < w1; w++) cnt += __popc(bm[wid][w]);
  int inc = cnt;
  for (int o = 1; o < 64; o <<= 1) { int v = __shfl_up(inc, o); if (lane >= o) inc += v; }
  int excl = inc - cnt;
  int total = __shfl(inc, 63);
  int pos = b + excl;
  for (int w = w0; w < w1; w++) {
    u32 v = bm[wid][w];
    while (v) { int bit = __ffs(v) - 1; bucket[pos++] = (w << 5) | bit; v &= v - 1; }
  }
  if (lane == 0) ucount[n] = total;
}

// emit compacted edges + zero bcount/bcursor/icnt/icursor/pcnt for next level
__global__ void k_emit(const int* __restrict__ boffs, const int* __restrict__ bucket,
                       const int* __restrict__ bucount, const int* __restrict__ bnoffs,
                       int* __restrict__ srcO, int* __restrict__ dstO,
                       int* __restrict__ b3zero, int* __restrict__ i2zero,
                       int* __restrict__ pcnt) {
  int t = blockIdx.x * 256 + threadIdx.x;
  int stride = gridDim.x * 256;
  for (int z = t; z < 2 * NN; z += stride) { b3zero[z] = 0; i2zero[z] = 0; }
  if (t == 0) *pcnt = 0;
  if (t >= NN) return;
  int u = bucount[t], b = boffs[t], o = bnoffs[t];
  for (int i = 0; i < u; i++) { srcO[o + i] = t; dstO[o + i] = bucket[b + i]; }
}

// ---------------- readout ----------------
__global__ void k_graph_pool(const int* __restrict__ nvb, const int* __restrict__ batch,
                             const float* __restrict__ x, float* __restrict__ gsum,
                             float* __restrict__ gcnt) {
  int t = blockIdx.x * 256 + threadIdx.x;
  int n = t >> 2;
  if (n >= NN) return;
  if (!nvb[n]) return;
  int sub = t & 3;
  int g = batch[n];
  const float* xr = x + (size_t)n * HID + sub * 32;
  float* o = gsum + (size_t)g * HID + sub * 32;
#pragma unroll
  for (int i = 0; i < 8; i++) {
    float4 v = *(const float4*)(xr + i * 4);
    atomicAdd(o + i * 4 + 0, v.x); atomicAdd(o + i * 4 + 1, v.y);
    atomicAdd(o + i * 4 + 2, v.z); atomicAdd(o + i * 4 + 3, v.w);
  }
  if (sub == 0) atomicAdd(&gcnt[g], 1.0f);
}

__global__ __launch_bounds__(128) void k_head1(const float* __restrict__ gsum,
                                               const float* __restrict__ gcnt,
                                               const float* __restrict__ Wf1,
                                               const float* __restrict__ bf1,
                                               float* __restrict__ hfc) {
  int g = blockIdx.x;
  int j = threadIdx.x;
  __shared__ float p[HID];
  float c = fmaxf(gcnt[g], 1.f);
  p[j] = gsum[g * HID + j] / c;
  __syncthreads();
  float s = bf1[j];
  const float* w = Wf1 + (size_t)j * HID;
  for (int k = 0; k < HID; k++) s += p[k] * w[k];
  hfc[g * HID + j] = fmaxf(s, 0.f);
}

__global__ void k_head2(const float* __restrict__ hfc, const float* __restrict__ Wf2,
                        const float* __restrict__ bf2, float* __restrict__ out) {
  int g = blockIdx.x;
  int t = threadIdx.x;
  __shared__ float lg[NC];
  if (t < NC) {
    float s = bf2[t];
    const float* w = Wf2 + (size_t)t * HID;
    const float* h = hfc + (size_t)g * HID;
    for (int k = 0; k < HID; k++) s += h[k] * w[k];
    lg[t] = s;
  }
  __syncthreads();
  if (t == 0) {
    float m = lg[0];
    for (int c = 1; c < NC; c++) m = fmaxf(m, lg[c]);
    float se = 0.f;
    for (int c = 0; c < NC; c++) se += expf(lg[c] - m);
    float lse = m + logf(se);
    for (int c = 0; c < NC; c++) out[g * NC + c] = lg[c] - lse;
  }
}

extern "C" void kernel_launch(void* const* d_in, const int* in_sizes, int n_in,
                              void* d_out, int out_size, void* d_ws, size_t ws_size,
                              hipStream_t stream) {
  const float* x0 = (const float*)d_in[0];
  const int* ei = (const int*)d_in[1];
  const int* batch = (const int*)d_in[2];
  const float* Wl = (const float*)d_in[3];
  const float* bl = (const float*)d_in[4];
  const float* Wr = (const float*)d_in[5];
  const float* gamma = (const float*)d_in[6];
  const float* beta = (const float*)d_in[7];
  const float* Wlin = (const float*)d_in[8];
  const float* blin = (const float*)d_in[9];
  const float* Wp = (const float*)d_in[10];
  const float* bp = (const float*)d_in[11];
  const float* Wf1 = (const float*)d_in[12];
  const float* bf1 = (const float*)d_in[13];
  const float* Wf2 = (const float*)d_in[14];
  const float* bf2 = (const float*)d_in[15];
  float* out = (float*)d_out;

  const int NH = NN * HID;
  size_t off = 0;
  char* base = (char*)d_ws;
  auto carve = [&](size_t bytes) -> char* {
    char* p = base + off;
    off += (bytes + 255) & ~(size_t)255;
    return p;
  };
  float* xa = (float*)carve((size_t)NH * 4);
  float* xb = (float*)carve((size_t)NH * 4);
  float* xc = (float*)carve((size_t)NH * 4);
  float* xd = (float*)carve((size_t)NH * 4);
  int* srcA = (int*)carve((size_t)NE * 4);
  int* dstA = (int*)carve((size_t)NE * 4);
  int* srcB = (int*)carve((size_t)NE * 4);
  int* dstB = (int*)carve((size_t)NE * 4);
  float* escore = (float*)carve((size_t)NE * 4);
  int* ebucket = (int*)carve((size_t)NE * 4);
  int* eids = (int*)carve((size_t)NE * 4);
  u64* ekey = (u64*)carve((size_t)NE * 8);
  int* ieids = (int*)carve((size_t)2 * NE * 4);
  u64* S = (u64*)carve((size_t)NN * 8);
  float* npx1 = (float*)carve((size_t)NN * 4);
  float* npx2 = (float*)carve((size_t)NN * 4);
  int* ncluster = (int*)carve((size_t)NN * 4);
  int* nvb = (int*)carve((size_t)NN * 4);
  int* b3 = (int*)carve((size_t)3 * NN * 4);
  int* bcount = b3;
  int* bcursor = b3 + NN;
  int* bucount = b3 + 2 * NN;
  int* i2 = (int*)carve((size_t)2 * NN * 4);
  int* icnt = i2;
  int* icursor = i2 + NN;
  int* boffs = (int*)carve((size_t)(NN + 1) * 4);
  int* bnoffs = (int*)carve((size_t)(NN + 1) * 4);
  int* csroff = (int*)carve((size_t)(NN + 1) * 4);
  int* ioff = (int*)carve((size_t)(NN + 1) * 4);
  double* bnsum = (double*)carve((size_t)2 * HID * 8);
  float* gbuf = (float*)carve((size_t)(NG * HID + NG) * 4);
  float* gsum = gbuf;
  float* gcnt = gbuf + NG * HID;
  float* ghfc = (float*)carve((size_t)NG * HID * 4);
  int* scal = (int*)carve(64 * 4);
  (void)ws_size; (void)n_in; (void)in_sizes; (void)out_size;

  int* pE = scal;        // E_cur
  int* pcnt = scal + 1;  // valid node count

  hipMemcpyAsync(xa, x0, (size_t)NH * 4, hipMemcpyDeviceToDevice, stream);
  k_init<<<1875, 256, 0, stream>>>(ei, srcA, dstA, nvb, scal, b3, i2, gbuf);

  int* srcC = srcA; int* dstC = dstA; int* srcN = srcB; int* dstN = dstB;
  float* xcur = xa;
  float* xtmp = xd;

  auto sage = [&](const float* xin, float* xout, int L) {
    k_sage_gather<<<3750, 256, 0, stream>>>(csroff, eids, srcC, xin, xtmp);
    gemm_dual<<<469, 256, 0, stream>>>(xtmp, Wl + (size_t)L * HID * HID, xin,
                                       Wr + (size_t)L * HID * HID, bl + (size_t)L * HID,
                                       xout, NN, HID, 1, bnsum);
    k_bn_stats<<<469, 128, 0, stream>>>(xout, nvb, bnsum);
    k_bn_apply<<<15000, 256, 0, stream>>>(xout, bnsum, pcnt, gamma + (size_t)L * HID,
                                          beta + (size_t)L * HID);
  };

  for (int b = 0; b < 3; b++) {
    // dst-CSR (sage + softmax) and incidence-CSR (suitor), one count/scan/scatter chain
    k_csr_count<<<1875, 256, 0, stream>>>(pE, srcC, dstC, bcount, icnt, nvb, pcnt);
    k_scan2<<<2, 1024, 0, stream>>>(bcount, csroff, icnt, ioff);
    k_csr_scatter<<<1875, 256, 0, stream>>>(pE, srcC, dstC, csroff, bcursor, eids,
                                            ioff, icursor, ieids);

    sage(xcur, xb, 2 * b);
    sage(xb, xc, 2 * b + 1);
    gemm_dual<<<469, 256, 0, stream>>>(xc, Wlin + (size_t)b * HID * 2 * HID, xb,
                                       Wlin + (size_t)b * HID * 2 * HID + HID,
                                       blin + (size_t)b * HID, xcur, NN, 2 * HID, 0, bnsum);

    // ----- edge pooling: softmax scores -> suitor matching -> new_x (resolve fused) -----
    k_node_proj<<<118, 256, 0, stream>>>(xcur, Wp + (size_t)b * 2 * HID, npx1, npx2);
    k_edge_softmax_seed<<<118, 256, 0, stream>>>(csroff, eids, srcC, npx1, npx2, bp + b,
                                                 escore, ekey, S);
    k_suitor<<<7500, 256, 0, stream>>>(ioff, ieids, srcC, dstC, ekey, S);
    k_new_x<<<3750, 256, 0, stream>>>(S, srcC, dstC, escore, xcur, xtmp,
                                      ncluster, nvb, b3);

    if (b < 2) {  // level-2 coarse edges are never consumed
      k_bucket_count<<<1875, 256, 0, stream>>>(pE, srcC, ncluster, bcount);
      k_scan<<<1, 1024, 0, stream>>>(bcount, boffs, NN, (int*)nullptr);
      k_bucket_scatter<<<1875, 256, 0, stream>>>(pE, srcC, dstC, ncluster, boffs, bcursor,
                                                 ebucket);
      k_dedup_bitmap<<<7500, 256, 0, stream>>>(boffs, ebucket, bucount);
      k_scan<<<1, 1024, 0, stream>>>(bucount, bnoffs, NN, pE);
      k_emit<<<235, 256, 0, stream>>>(boffs, ebucket, bucount, bnoffs, srcN, dstN,
                                      b3, i2, pcnt);
      { int* t = srcC; srcC = srcN; srcN = t; t = dstC; dstC = dstN; dstN = t; }
    }
    { float* t = xcur; xcur = xtmp; xtmp = t; }
  }

  k_graph_pool<<<469, 256, 0, stream>>>(nvb, batch, xcur, gsum, gcnt);
  k_head1<<<NG, 128, 0, stream>>>(gsum, gcnt, Wf1, bf1, ghfc);
  k_head2<<<NG, 32, 0, stream>>>(ghfc, Wf2, bf2, out);
}

// Round 9
// 2842.515 us; speedup vs baseline: 17.3806x; 1.0584x over previous
//
#include <hip/hip_runtime.h>
#include <stdint.h>

#define NN 30000
#define NE 480000
#define HID 128
#define NG 128
#define NC 6
#define BN_EPS 1e-5f
#define WPB 938   // ceil(NN/32) bitmap words
#define SLOTS 4   // reg-resident suitor entries per lane (deg <= 256)

typedef unsigned int u32;
typedef unsigned long long u64;

__device__ __forceinline__ u64 ent_key(int4 ent) {
  return ((u64)(u32)ent.y << 32) | (u32)ent.x;
}

// ---------------- init (also zeroes all per-call state) ----------------
__global__ void k_init(const int* __restrict__ ei, int* srcA, int* dstA, int* nvb,
                       int* scal, int* b3, int* i2, float* gbuf) {
  int t = blockIdx.x * 256 + threadIdx.x;
  if (t < NE) { srcA[t] = ei[t]; dstA[t] = ei[NE + t]; }
  if (t < NN) nvb[t] = 1;
  if (t < 2 * NN) { b3[t] = 0; i2[t] = 0; }   // bcount,bcursor + icnt,icursor
  if (t < NG * HID + NG) gbuf[t] = 0.f;
  if (t == 0) { scal[0] = NE; scal[1] = 0; }
}

// ---------------- CSR build (dst CSR + incidence counts) + valid-node count ----------------
__global__ void k_csr_count(const int* __restrict__ pE, const int* __restrict__ src,
                            const int* __restrict__ dst, int* __restrict__ cnt,
                            int* __restrict__ icnt, const int* __restrict__ nvb,
                            int* __restrict__ pcnt) {
  int t = blockIdx.x * 256 + threadIdx.x;
  if (t < NN && nvb[t]) atomicAdd(pcnt, 1);
  if (t < *pE) {
    int s = src[t], d = dst[t];
    atomicAdd(&cnt[d], 1);
    if (s != d) { atomicAdd(&icnt[s], 1); atomicAdd(&icnt[d], 1); }
  }
}

// two independent single-block scans (block 0: dst-CSR, block 1: incidence)
__global__ __launch_bounds__(1024) void k_scan2(const int* __restrict__ in0, int* __restrict__ out0,
                                                const int* __restrict__ in1, int* __restrict__ out1) {
  const int* in = blockIdx.x ? in1 : in0;
  int* out = blockIdx.x ? out1 : out0;
  __shared__ int part[1024];
  int t = threadIdx.x;
  int chunk = (NN + 1023) / 1024;
  int b = t * chunk, e = b + chunk;
  if (b > NN) b = NN;
  if (e > NN) e = NN;
  int s = 0;
  for (int i = b; i < e; i++) s += in[i];
  part[t] = s;
  __syncthreads();
  for (int off = 1; off < 1024; off <<= 1) {
    int v = (t >= off) ? part[t - off] : 0;
    __syncthreads();
    part[t] += v;
    __syncthreads();
  }
  int excl = (t == 0) ? 0 : part[t - 1];
  for (int i = b; i < e; i++) { out[i] = excl; excl += in[i]; }
  if (t == 0) out[NN] = part[1023];
}

__global__ void k_csr_scatter(const int* __restrict__ pE, const int* __restrict__ dst,
                              const int* __restrict__ coff, int* __restrict__ cursor,
                              int* __restrict__ eids) {
  int e = blockIdx.x * 256 + threadIdx.x;
  if (e >= *pE) return;
  int d = dst[e];
  int pos = coff[d] + atomicAdd(&cursor[d], 1);
  eids[pos] = e;
}

// ---------------- SAGE mean aggregation: CSR gather, 32 lanes/node ----------------
__global__ __launch_bounds__(256) void k_sage_gather(
    const int* __restrict__ coff, const int* __restrict__ eids,
    const int* __restrict__ src, const float* __restrict__ x,
    float* __restrict__ mean) {
  int grp = threadIdx.x >> 5;           // 8 nodes per block
  int lane = threadIdx.x & 31;
  int n = blockIdx.x * 8 + grp;
  if (n >= NN) return;
  int b = coff[n], e2 = coff[n + 1];
  float4 acc = make_float4(0.f, 0.f, 0.f, 0.f);
  for (int i = b; i < e2; i++) {
    int s = src[eids[i]];
    float4 v = *(const float4*)(x + (size_t)s * HID + lane * 4);
    acc.x += v.x; acc.y += v.y; acc.z += v.z; acc.w += v.w;
  }
  float inv = 1.0f / fmaxf((float)(e2 - b), 1.0f);
  acc.x *= inv; acc.y *= inv; acc.z *= inv; acc.w *= inv;
  *(float4*)(mean + (size_t)n * HID + lane * 4) = acc;
}

// out[n][j] = A1@W1^T + A2@W2^T + bias; optional relu. Also zeroes bnsum (block 0).
__global__ __launch_bounds__(256) void gemm_dual(
    const float* __restrict__ A1, const float* __restrict__ W1,
    const float* __restrict__ A2, const float* __restrict__ W2,
    const float* __restrict__ bias, float* __restrict__ out,
    int M, int ldw, int relu, double* __restrict__ bnsum) {
  if (blockIdx.x == 0 && threadIdx.x < 2 * HID) bnsum[threadIdx.x] = 0.0;
  __shared__ float As[64][33];
  __shared__ float Ws[32][132];  // transposed: Ws[kk][j]
  int row0 = blockIdx.x * 64;
  int tid = threadIdx.x;
  int cid = tid & 31;
  int rid = tid >> 5;
  float acc[8][4];
#pragma unroll
  for (int r = 0; r < 8; r++)
#pragma unroll
    for (int c = 0; c < 4; c++) acc[r][c] = 0.f;

  for (int srcI = 0; srcI < 2; ++srcI) {
    const float* A = srcI ? A2 : A1;
    const float* W = srcI ? W2 : W1;
    for (int kc = 0; kc < 128; kc += 32) {
#pragma unroll
      for (int i = 0; i < 2; ++i) {
        int idx = tid + i * 256;
        int r = idx >> 3;
        int c4 = (idx & 7) << 2;
        int gr = row0 + r;
        float4 v = make_float4(0.f, 0.f, 0.f, 0.f);
        if (gr < M) v = *(const float4*)(A + (size_t)gr * 128 + kc + c4);
        As[r][c4 + 0] = v.x; As[r][c4 + 1] = v.y; As[r][c4 + 2] = v.z; As[r][c4 + 3] = v.w;
      }
#pragma unroll
      for (int i = 0; i < 4; ++i) {
        int idx = tid + i * 256;
        int j = idx >> 3;
        int c4 = (idx & 7) << 2;
        float4 v = *(const float4*)(W + (size_t)j * ldw + kc + c4);
        Ws[c4 + 0][j] = v.x; Ws[c4 + 1][j] = v.y; Ws[c4 + 2][j] = v.z; Ws[c4 + 3][j] = v.w;
      }
      __syncthreads();
#pragma unroll
      for (int kk = 0; kk < 32; ++kk) {
        float4 w = *(const float4*)(&Ws[kk][cid * 4]);
#pragma unroll
        for (int r = 0; r < 8; ++r) {
          float a = As[rid * 8 + r][kk];
          acc[r][0] += a * w.x; acc[r][1] += a * w.y; acc[r][2] += a * w.z; acc[r][3] += a * w.w;
        }
      }
      __syncthreads();
    }
  }
#pragma unroll
  for (int r = 0; r < 8; ++r) {
    int gr = row0 + rid * 8 + r;
    if (gr >= M) continue;
#pragma unroll
    for (int c = 0; c < 4; ++c) {
      float v = acc[r][c] + bias[cid * 4 + c];
      if (relu) v = fmaxf(v, 0.f);
      out[(size_t)gr * 128 + cid * 4 + c] = v;
    }
  }
}

__global__ __launch_bounds__(128) void k_bn_stats(const float* __restrict__ x,
                                                  const int* __restrict__ nvb,
                                                  double* __restrict__ sums) {
  int k = threadIdx.x;
  int n0 = blockIdx.x * 64;
  float s = 0.f, q = 0.f;
  for (int r = 0; r < 64; r++) {
    int n = n0 + r;
    if (n >= NN) break;
    if (!nvb[n]) continue;
    float v = x[(size_t)n * HID + k];
    s += v; q += v * v;
  }
  atomicAdd(&sums[k], (double)s);
  atomicAdd(&sums[HID + k], (double)q);
}

__global__ void k_bn_apply(float* __restrict__ x, const double* __restrict__ sums,
                           const int* __restrict__ cnt, const float* __restrict__ gamma,
                           const float* __restrict__ beta) {
  int t = blockIdx.x * 256 + threadIdx.x;
  if (t >= NN * HID) return;
  int k = t & 127;
  double c = (double)((*cnt > 1) ? *cnt : 1);
  double mu = sums[k] / c;
  double var = sums[HID + k] / c - mu * mu;
  if (var < 0.0) var = 0.0;
  float inv = (float)(1.0 / sqrt(var + (double)BN_EPS));
  x[t] = gamma[k] * (x[t] - (float)mu) * inv + beta[k];
}

// ---------------- edge pool ----------------
__global__ void k_node_proj(const float* __restrict__ x, const float* __restrict__ Wp,
                            float* __restrict__ px1, float* __restrict__ px2) {
  int n = blockIdx.x * 256 + threadIdx.x;
  if (n >= NN) return;
  const float* xr = x + (size_t)n * HID;
  float s1 = 0.f, s2 = 0.f;
#pragma unroll 8
  for (int k = 0; k < HID; k += 4) {
    float4 v = *(const float4*)(xr + k);
    float4 w1 = *(const float4*)(Wp + k);
    float4 w2 = *(const float4*)(Wp + HID + k);
    s1 += v.x * w1.x + v.y * w1.y + v.z * w1.z + v.w * w1.w;
    s2 += v.x * w2.x + v.y * w2.y + v.z * w2.z + v.w * w2.w;
  }
  px1[n] = s1; px2[n] = s2;
}

// fused: S init + per-dst softmax + suitor keys
__global__ void k_edge_softmax_seed(
    const int* __restrict__ coff, const int* __restrict__ eids,
    const int* __restrict__ src, const float* __restrict__ px1,
    const float* __restrict__ px2, const float* __restrict__ bp,
    float* __restrict__ score, u64* __restrict__ ekey, u64* __restrict__ S) {
  int n = blockIdx.x * 256 + threadIdx.x;
  if (n >= NN) return;
  S[n] = 0ull;
  int b = coff[n], e2 = coff[n + 1];
  if (b == e2) return;
  float p2 = px2[n] + *bp;
  float mx = -3.4e38f;
  for (int i = b; i < e2; i++) {
    float r = px1[src[eids[i]]] + p2;
    mx = fmaxf(mx, r);
  }
  double den = 0.0;
  for (int i = b; i < e2; i++) {
    int eid = eids[i];
    float z = expf(px1[src[eid]] + p2 - mx);
    score[eid] = z;
    den += (double)z;
  }
  if (den < 1e-16) den = 1e-16;
  double invd = 1.0 / den;
  for (int i = b; i < e2; i++) {
    int eid = eids[i];
    float sc = (float)((double)score[eid] * invd) + 0.5f;
    score[eid] = sc;
    // key: score desc, then lower edge index wins (matches stable argsort(-score))
    ekey[eid] = ((u64)__float_as_uint(sc) << 32) | (u64)(0xFFFFFFFFu - (u32)eid);
  }
}

// incidence scatter with INLINE payload {key, partner}: suitor then streams one
// contiguous 16B entry per candidate instead of 3 scattered line-fetches
// (round-8: 960k entries x {ekey,src,dst} x 64B lines ~ 184 MB -> measured 206 MB).
// Reads here are sequential in e (coalesced); writes are scattered 16B (fine).
__global__ void k_inc_scatter(const int* __restrict__ pE, const int* __restrict__ src,
                              const int* __restrict__ dst, const u64* __restrict__ ekey,
                              const int* __restrict__ ioff, int* __restrict__ icur,
                              int4* __restrict__ ielist) {
  int e = blockIdx.x * 256 + threadIdx.x;
  if (e >= *pE) return;
  int s = src[e], d = dst[e];
  if (s == d) return;
  u64 k = ekey[e];
  int4 ent;
  ent.x = (int)(u32)(k & 0xFFFFFFFFull);
  ent.y = (int)(u32)(k >> 32);
  ent.w = 0;
  ent.z = d;
  ielist[ioff[s] + atomicAdd(&icur[s], 1)] = ent;
  ent.z = s;
  ielist[ioff[d] + atomicAdd(&icur[d], 1)] = ent;
}

// ---------------- Suitor matching, wave-per-node, register-resident ----------------
// Candidate (key, partner) pairs stream from the inline-payload ielist; loaded ONCE
// per node-visit. Slot killing is permanent (S monotone). Lost race's atomicMax
// return kills its own slot -> guaranteed progress.
__global__ __launch_bounds__(256) void k_suitor(
    const int* __restrict__ ioff, const int4* __restrict__ ielist,
    const int* __restrict__ src, const int* __restrict__ dst,
    u64* __restrict__ S) {
  int wid = threadIdx.x >> 6;
  int lane = threadIdx.x & 63;
  int n = blockIdx.x * 4 + wid;
  if (n >= NN) return;
  int cur = n;
  while (cur >= 0) {
    int b = ioff[cur], e2 = ioff[cur + 1];
    int deg = e2 - b;
    if (deg == 0) break;
    if (deg <= 64 * SLOTS) {
      // ---- register-resident path ----
      u64 key[SLOTS]; int pv[SLOTS];
#pragma unroll
      for (int s = 0; s < SLOTS; s++) {
        key[s] = 0; pv[s] = 0;
        int i = b + s * 64 + lane;
        if (i < e2) {
          int4 ent = ielist[i];
          key[s] = ent_key(ent);
          pv[s] = ent.z;
        }
      }
      long long res;
      for (;;) {
        u64 localBest = 0;
#pragma unroll
        for (int s = 0; s < SLOTS; s++) {
          if (!key[s]) continue;
          u64 sv = __hip_atomic_load(&S[pv[s]], __ATOMIC_RELAXED, __HIP_MEMORY_SCOPE_AGENT);
          if (sv >= key[s]) key[s] = 0;              // permanently dead
          else if (key[s] > localBest) localBest = key[s];
        }
        u64 bestKey = localBest;
#pragma unroll
        for (int o = 32; o > 0; o >>= 1) {
          u64 other = __shfl_xor(bestKey, o, 64);
          if (other > bestKey) bestKey = other;
        }
        if (bestKey == 0) { res = -1; break; }       // nothing proposable
        int ms = -1;
#pragma unroll
        for (int s = 0; s < SLOTS; s++)
          if (ms < 0 && key[s] == bestKey) ms = s;
        u64 ball = __ballot(ms >= 0);
        int owner = (int)(__ffsll((long long)ball) - 1);
        long long r0 = -3;
        if (lane == owner) {
          int bv = pv[ms];
          u64 old = atomicMax(&S[bv], bestKey);
          if (old >= bestKey) { key[ms] = 0; r0 = -2; }          // lost race; retry cur
          else if (old == 0) r0 = -1;                            // accepted, chain ends
          else {
            int eo = (int)(0xFFFFFFFFu - (u32)(old & 0xFFFFFFFFull));
            int so = src[eo], do_ = dst[eo];
            r0 = (so == bv) ? do_ : so;                          // displaced re-seeks
          }
        }
        res = __shfl(r0, owner, 64);
        if (res != -2) break;
      }
      if (res < 0) break;
      cur = (int)res;
    } else {
      // ---- fallback streaming path (rare high-degree nodes) ----
      u64 bestKey = 0;
      for (int i = b + lane; i < e2; i += 64) {
        int4 ent = ielist[i];
        u64 k = ent_key(ent);
        if (k <= bestKey) continue;
        u64 sv = __hip_atomic_load(&S[ent.z], __ATOMIC_RELAXED, __HIP_MEMORY_SCOPE_AGENT);
        if (k > sv) bestKey = k;
      }
#pragma unroll
      for (int o = 32; o > 0; o >>= 1) {
        u64 other = __shfl_xor(bestKey, o, 64);
        if (other > bestKey) bestKey = other;
      }
      long long r0 = -1;
      if (bestKey != 0 && lane == 0) {
        int e = (int)(0xFFFFFFFFu - (u32)(bestKey & 0xFFFFFFFFull));
        int es = src[e], ed = dst[e];
        int bv = (es == cur) ? ed : es;
        u64 old = atomicMax(&S[bv], bestKey);
        if (old >= bestKey) r0 = cur;                            // rescan
        else if (old != 0) {
          int eo = (int)(0xFFFFFFFFu - (u32)(old & 0xFFFFFFFFull));
          int so = src[eo], do_ = dst[eo];
          r0 = (so == bv) ? do_ : so;
        }
      }
      long long res = (bestKey != 0) ? __shfl(r0, 0, 64) : -1;
      cur = (int)res;
    }
  }
}

// new_x gather + cluster derivation from S (resolve fused in) + nvb update + zero b3
__global__ __launch_bounds__(256) void k_new_x(
    const u64* __restrict__ S, const int* __restrict__ src, const int* __restrict__ dst,
    const float* __restrict__ score, const float* __restrict__ x,
    float* __restrict__ out, int* __restrict__ cluster,
    int* __restrict__ nvb, int* __restrict__ b3zero) {
  int gt = blockIdx.x * 256 + threadIdx.x;
  if (gt < 2 * NN) b3zero[gt] = 0;
  int grp = threadIdx.x >> 5;
  int lane = threadIdx.x & 31;
  int n = blockIdx.x * 8 + grp;
  if (n >= NN) return;
  // derive match state from S (uniform within the 32-lane group)
  u64 k = S[n];
  int partner = -1;
  int rep = n;
  bool isOth = false;
  float sc = 1.f;
  if (k) {
    int e = (int)(0xFFFFFFFFu - (u32)(k & 0xFFFFFFFFull));
    int s = src[e], d = dst[e];
    int other = (s == n) ? d : s;
    if (S[other] == k) {                 // mutual -> matched pair
      if (n > other) { isOth = true; rep = other; }
      else { partner = other; sc = score[e]; }
    }
  }
  float4 v = make_float4(0.f, 0.f, 0.f, 0.f);
  if (!isOth) {
    v = *(const float4*)(x + (size_t)n * HID + lane * 4);
    if (partner >= 0) {
      float4 w = *(const float4*)(x + (size_t)partner * HID + lane * 4);
      v.x = (v.x + w.x) * sc; v.y = (v.y + w.y) * sc;
      v.z = (v.z + w.z) * sc; v.w = (v.w + w.w) * sc;
    }
  }
  *(float4*)(out + (size_t)n * HID + lane * 4) = v;
  if (lane == 0) {
    cluster[n] = rep;
    nvb[n] = (nvb[n] && !isOth) ? 1 : 0;
  }
}

// ---------------- dedup (sorted unique of (cs,cd)) ----------------
__global__ void k_bucket_count(const int* __restrict__ pE, const int* __restrict__ src,
                               const int* __restrict__ cluster, int* __restrict__ bcount) {
  int e = blockIdx.x * 256 + threadIdx.x;
  if (e >= *pE) return;
  atomicAdd(&bcount[cluster[src[e]]], 1);
}

__global__ __launch_bounds__(1024) void k_scan(const int* __restrict__ in, int* __restrict__ out,
                                               int n, int* totalDst) {
  __shared__ int part[1024];
  int t = threadIdx.x;
  int chunk = (n + 1023) / 1024;
  int b = t * chunk, e = b + chunk;
  if (b > n) b = n;
  if (e > n) e = n;
  int s = 0;
  for (int i = b; i < e; i++) s += in[i];
  part[t] = s;
  __syncthreads();
  for (int off = 1; off < 1024; off <<= 1) {
    int v = (t >= off) ? part[t - off] : 0;
    __syncthreads();
    part[t] += v;
    __syncthreads();
  }
  int excl = (t == 0) ? 0 : part[t - 1];
  int total = part[1023];
  for (int i = b; i < e; i++) { out[i] = excl; excl += in[i]; }
  if (t == 0) {
    out[n] = total;
    if (totalDst) *totalDst = total;
  }
}

__global__ void k_bucket_scatter(const int* __restrict__ pE, const int* __restrict__ src,
                                 const int* __restrict__ dst, const int* __restrict__ cluster,
                                 const int* __restrict__ boffs, int* __restrict__ bcursor,
                                 int* __restrict__ bucket) {
  int e = blockIdx.x * 256 + threadIdx.x;
  if (e >= *pE) return;
  int cs = cluster[src[e]], cd = cluster[dst[e]];
  int pos = boffs[cs] + atomicAdd(&bcursor[cs], 1);
  bucket[pos] = cd;
}

// sorted-unique per bucket via per-wave LDS bitmap (no comparison sort, no O(d^2)).
__global__ __launch_bounds__(256) void k_dedup_bitmap(
    const int* __restrict__ boffs, int* __restrict__ bucket,
    int* __restrict__ ucount) {
  __shared__ u32 bm[4][960];
  int wid = threadIdx.x >> 6;
  int lane = threadIdx.x & 63;
  int n = blockIdx.x * 4 + wid;
  int b = boffs[n], e = boffs[n + 1];
  for (int w = lane; w < 960; w += 64) bm[wid][w] = 0;
  __syncthreads();
  for (int i = b + lane; i < e; i += 64)
    atomicOr(&bm[wid][bucket[i] >> 5], 1u << (bucket[i] & 31));
  __syncthreads();
  int w0 = lane * 15;
  int w1 = w0 + 15; if (w1 > WPB) w1 = WPB;
  int cnt = 0;
  for (int w = w0; w < w1; w++) cnt += __popc(bm[wid][w]);
  int inc = cnt;
  for (int o = 1; o < 64; o <<= 1) { int v = __shfl_up(inc, o); if (lane >= o) inc += v; }
  int excl = inc - cnt;
  int total = __shfl(inc, 63);
  int pos = b + excl;
  for (int w = w0; w < w1; w++) {
    u32 v = bm[wid][w];
    while (v) { int bit = __ffs(v) - 1; bucket[pos++] = (w << 5) | bit; v &= v - 1; }
  }
  if (lane == 0) ucount[n] = total;
}

// emit compacted edges + zero bcount/bcursor/icnt/icursor/pcnt for next level
__global__ void k_emit(const int* __restrict__ boffs, const int* __restrict__ bucket,
                       const int* __restrict__ bucount, const int* __restrict__ bnoffs,
                       int* __restrict__ srcO, int* __restrict__ dstO,
                       int* __restrict__ b3zero, int* __restrict__ i2zero,
                       int* __restrict__ pcnt) {
  int t = blockIdx.x * 256 + threadIdx.x;
  int stride = gridDim.x * 256;
  for (int z = t; z < 2 * NN; z += stride) { b3zero[z] = 0; i2zero[z] = 0; }
  if (t == 0) *pcnt = 0;
  if (t >= NN) return;
  int u = bucount[t], b = boffs[t], o = bnoffs[t];
  for (int i = 0; i < u; i++) { srcO[o + i] = t; dstO[o + i] = bucket[b + i]; }
}

// ---------------- readout ----------------
__global__ void k_graph_pool(const int* __restrict__ nvb, const int* __restrict__ batch,
                             const float* __restrict__ x, float* __restrict__ gsum,
                             float* __restrict__ gcnt) {
  int t = blockIdx.x * 256 + threadIdx.x;
  int n = t >> 2;
  if (n >= NN) return;
  if (!nvb[n]) return;
  int sub = t & 3;
  int g = batch[n];
  const float* xr = x + (size_t)n * HID + sub * 32;
  float* o = gsum + (size_t)g * HID + sub * 32;
#pragma unroll
  for (int i = 0; i < 8; i++) {
    float4 v = *(const float4*)(xr + i * 4);
    atomicAdd(o + i * 4 + 0, v.x); atomicAdd(o + i * 4 + 1, v.y);
    atomicAdd(o + i * 4 + 2, v.z); atomicAdd(o + i * 4 + 3, v.w);
  }
  if (sub == 0) atomicAdd(&gcnt[g], 1.0f);
}

__global__ __launch_bounds__(128) void k_head1(const float* __restrict__ gsum,
                                               const float* __restrict__ gcnt,
                                               const float* __restrict__ Wf1,
                                               const float* __restrict__ bf1,
                                               float* __restrict__ hfc) {
  int g = blockIdx.x;
  int j = threadIdx.x;
  __shared__ float p[HID];
  float c = fmaxf(gcnt[g], 1.f);
  p[j] = gsum[g * HID + j] / c;
  __syncthreads();
  float s = bf1[j];
  const float* w = Wf1 + (size_t)j * HID;
  for (int k = 0; k < HID; k++) s += p[k] * w[k];
  hfc[g * HID + j] = fmaxf(s, 0.f);
}

__global__ void k_head2(const float* __restrict__ hfc, const float* __restrict__ Wf2,
                        const float* __restrict__ bf2, float* __restrict__ out) {
  int g = blockIdx.x;
  int t = threadIdx.x;
  __shared__ float lg[NC];
  if (t < NC) {
    float s = bf2[t];
    const float* w = Wf2 + (size_t)t * HID;
    const float* h = hfc + (size_t)g * HID;
    for (int k = 0; k < HID; k++) s += h[k] * w[k];
    lg[t] = s;
  }
  __syncthreads();
  if (t == 0) {
    float m = lg[0];
    for (int c = 1; c < NC; c++) m = fmaxf(m, lg[c]);
    float se = 0.f;
    for (int c = 0; c < NC; c++) se += expf(lg[c] - m);
    float lse = m + logf(se);
    for (int c = 0; c < NC; c++) out[g * NC + c] = lg[c] - lse;
  }
}

extern "C" void kernel_launch(void* const* d_in, const int* in_sizes, int n_in,
                              void* d_out, int out_size, void* d_ws, size_t ws_size,
                              hipStream_t stream) {
  const float* x0 = (const float*)d_in[0];
  const int* ei = (const int*)d_in[1];
  const int* batch = (const int*)d_in[2];
  const float* Wl = (const float*)d_in[3];
  const float* bl = (const float*)d_in[4];
  const float* Wr = (const float*)d_in[5];
  const float* gamma = (const float*)d_in[6];
  const float* beta = (const float*)d_in[7];
  const float* Wlin = (const float*)d_in[8];
  const float* blin = (const float*)d_in[9];
  const float* Wp = (const float*)d_in[10];
  const float* bp = (const float*)d_in[11];
  const float* Wf1 = (const float*)d_in[12];
  const float* bf1 = (const float*)d_in[13];
  const float* Wf2 = (const float*)d_in[14];
  const float* bf2 = (const float*)d_in[15];
  float* out = (float*)d_out;

  const int NH = NN * HID;
  size_t off = 0;
  char* base = (char*)d_ws;
  auto carve = [&](size_t bytes) -> char* {
    char* p = base + off;
    off += (bytes + 255) & ~(size_t)255;
    return p;
  };
  float* xa = (float*)carve((size_t)NH * 4);
  float* xb = (float*)carve((size_t)NH * 4);
  float* xc = (float*)carve((size_t)NH * 4);   // ALSO aliased as ielist (same 15.36 MB)
  float* xd = (float*)carve((size_t)NH * 4);
  int* srcA = (int*)carve((size_t)NE * 4);
  int* dstA = (int*)carve((size_t)NE * 4);
  int* srcB = (int*)carve((size_t)NE * 4);
  int* dstB = (int*)carve((size_t)NE * 4);
  float* escore = (float*)carve((size_t)NE * 4);
  int* ebucket = (int*)carve((size_t)NE * 4);
  int* eids = (int*)carve((size_t)NE * 4);
  u64* ekey = (u64*)carve((size_t)NE * 8);
  u64* S = (u64*)carve((size_t)NN * 8);
  float* npx1 = (float*)carve((size_t)NN * 4);
  float* npx2 = (float*)carve((size_t)NN * 4);
  int* ncluster = (int*)carve((size_t)NN * 4);
  int* nvb = (int*)carve((size_t)NN * 4);
  int* b3 = (int*)carve((size_t)3 * NN * 4);
  int* bcount = b3;
  int* bcursor = b3 + NN;
  int* bucount = b3 + 2 * NN;
  int* i2 = (int*)carve((size_t)2 * NN * 4);
  int* icnt = i2;
  int* icursor = i2 + NN;
  int* boffs = (int*)carve((size_t)(NN + 1) * 4);
  int* bnoffs = (int*)carve((size_t)(NN + 1) * 4);
  int* csroff = (int*)carve((size_t)(NN + 1) * 4);
  int* ioff = (int*)carve((size_t)(NN + 1) * 4);
  double* bnsum = (double*)carve((size_t)2 * HID * 8);
  float* gbuf = (float*)carve((size_t)(NG * HID + NG) * 4);
  float* gsum = gbuf;
  float* gcnt = gbuf + NG * HID;
  float* ghfc = (float*)carve((size_t)NG * HID * 4);
  int* scal = (int*)carve(64 * 4);
  (void)ws_size; (void)n_in; (void)in_sizes; (void)out_size;

  // ielist aliases xc: 2*NE*16 B == NH*4 B == 15,360,000 B exactly.
  // xc is dead after the concat-linear gemm (stream order: ... gemm(xc,..) ->
  // node_proj -> softmax_seed -> inc_scatter(writes ielist) -> suitor), and is
  // rewritten next level by sage#2 only after suitor completes.
  int4* ielist = (int4*)xc;

  int* pE = scal;        // E_cur
  int* pcnt = scal + 1;  // valid node count

  hipMemcpyAsync(xa, x0, (size_t)NH * 4, hipMemcpyDeviceToDevice, stream);
  k_init<<<1875, 256, 0, stream>>>(ei, srcA, dstA, nvb, scal, b3, i2, gbuf);

  int* srcC = srcA; int* dstC = dstA; int* srcN = srcB; int* dstN = dstB;
  float* xcur = xa;
  float* xtmp = xd;

  auto sage = [&](const float* xin, float* xout, int L) {
    k_sage_gather<<<3750, 256, 0, stream>>>(csroff, eids, srcC, xin, xtmp);
    gemm_dual<<<469, 256, 0, stream>>>(xtmp, Wl + (size_t)L * HID * HID, xin,
                                       Wr + (size_t)L * HID * HID, bl + (size_t)L * HID,
                                       xout, NN, HID, 1, bnsum);
    k_bn_stats<<<469, 128, 0, stream>>>(xout, nvb, bnsum);
    k_bn_apply<<<15000, 256, 0, stream>>>(xout, bnsum, pcnt, gamma + (size_t)L * HID,
                                          beta + (size_t)L * HID);
  };

  for (int b = 0; b < 3; b++) {
    // dst-CSR (sage + softmax) + incidence counts, one count/scan chain
    k_csr_count<<<1875, 256, 0, stream>>>(pE, srcC, dstC, bcount, icnt, nvb, pcnt);
    k_scan2<<<2, 1024, 0, stream>>>(bcount, csroff, icnt, ioff);
    k_csr_scatter<<<1875, 256, 0, stream>>>(pE, dstC, csroff, bcursor, eids);

    sage(xcur, xb, 2 * b);
    sage(xb, xc, 2 * b + 1);
    gemm_dual<<<469, 256, 0, stream>>>(xc, Wlin + (size_t)b * HID * 2 * HID, xb,
                                       Wlin + (size_t)b * HID * 2 * HID + HID,
                                       blin + (size_t)b * HID, xcur, NN, 2 * HID, 0, bnsum);

    // ----- edge pooling: softmax scores -> inline-payload incidence -> suitor -----
    k_node_proj<<<118, 256, 0, stream>>>(xcur, Wp + (size_t)b * 2 * HID, npx1, npx2);
    k_edge_softmax_seed<<<118, 256, 0, stream>>>(csroff, eids, srcC, npx1, npx2, bp + b,
                                                 escore, ekey, S);
    k_inc_scatter<<<1875, 256, 0, stream>>>(pE, srcC, dstC, ekey, ioff, icursor, ielist);
    k_suitor<<<7500, 256, 0, stream>>>(ioff, ielist, srcC, dstC, S);
    k_new_x<<<3750, 256, 0, stream>>>(S, srcC, dstC, escore, xcur, xtmp,
                                      ncluster, nvb, b3);

    if (b < 2) {  // level-2 coarse edges are never consumed
      k_bucket_count<<<1875, 256, 0, stream>>>(pE, srcC, ncluster, bcount);
      k_scan<<<1, 1024, 0, stream>>>(bcount, boffs, NN, (int*)nullptr);
      k_bucket_scatter<<<1875, 256, 0, stream>>>(pE, srcC, dstC, ncluster, boffs, bcursor,
                                                 ebucket);
      k_dedup_bitmap<<<7500, 256, 0, stream>>>(boffs, ebucket, bucount);
      k_scan<<<1, 1024, 0, stream>>>(bucount, bnoffs, NN, pE);
      k_emit<<<235, 256, 0, stream>>>(boffs, ebucket, bucount, bnoffs, srcN, dstN,
                                      b3, i2, pcnt);
      { int* t = srcC; srcC = srcN; srcN = t; t = dstC; dstC = dstN; dstN = t; }
    }
    { float* t = xcur; xcur = xtmp; xtmp = t; }
  }

  k_graph_pool<<<469, 256, 0, stream>>>(nvb, batch, xcur, gsum, gcnt);
  k_head1<<<NG, 128, 0, stream>>>(gsum, gcnt, Wf1, bf1, ghfc);
  k_head2<<<NG, 32, 0, stream>>>(ghfc, Wf2, bf2, out);
}

// Round 10
// 2544.183 us; speedup vs baseline: 19.4187x; 1.1173x over previous
//
#include <hip/hip_runtime.h>
#include <stdint.h>

#define NN 30000
#define NE 480000
#define HID 128
#define NG 128
#define NC 6
#define BN_EPS 1e-5f
#define WPB 938   // ceil(NN/32) bitmap words
#define SLOTS 4   // reg-resident suitor entries per lane (deg <= 256)
#define GPAD 132

typedef unsigned int u32;
typedef unsigned long long u64;

__device__ __forceinline__ u64 ent_key(int4 ent) {
  return ((u64)(u32)ent.y << 32) | (u32)ent.x;
}

// ---------------- init (also zeroes all per-call state) ----------------
__global__ void k_init(const int* __restrict__ ei, int* srcA, int* dstA, int* nvb,
                       int* scal, int* b3, int* i2, float* gbuf) {
  int t = blockIdx.x * 256 + threadIdx.x;
  if (t < NE) { srcA[t] = ei[t]; dstA[t] = ei[NE + t]; }
  if (t < NN) nvb[t] = 1;
  if (t < 2 * NN) { b3[t] = 0; i2[t] = 0; }   // bcount,bcursor + icnt,icursor
  if (t < NG * HID + NG) gbuf[t] = 0.f;
  if (t == 0) { scal[0] = NE; scal[1] = 0; }
}

// ---------------- CSR build (dst CSR + incidence counts) + valid-node count ----------------
__global__ void k_csr_count(const int* __restrict__ pE, const int* __restrict__ src,
                            const int* __restrict__ dst, int* __restrict__ cnt,
                            int* __restrict__ icnt, const int* __restrict__ nvb,
                            int* __restrict__ pcnt) {
  int t = blockIdx.x * 256 + threadIdx.x;
  if (t < NN && nvb[t]) atomicAdd(pcnt, 1);
  if (t < *pE) {
    int s = src[t], d = dst[t];
    atomicAdd(&cnt[d], 1);
    if (s != d) { atomicAdd(&icnt[s], 1); atomicAdd(&icnt[d], 1); }
  }
}

// two independent single-block scans (block 0: dst-CSR, block 1: incidence)
__global__ __launch_bounds__(1024) void k_scan2(const int* __restrict__ in0, int* __restrict__ out0,
                                                const int* __restrict__ in1, int* __restrict__ out1) {
  const int* in = blockIdx.x ? in1 : in0;
  int* out = blockIdx.x ? out1 : out0;
  __shared__ int part[1024];
  int t = threadIdx.x;
  int chunk = (NN + 1023) / 1024;
  int b = t * chunk, e = b + chunk;
  if (b > NN) b = NN;
  if (e > NN) e = NN;
  int s = 0;
  for (int i = b; i < e; i++) s += in[i];
  part[t] = s;
  __syncthreads();
  for (int off = 1; off < 1024; off <<= 1) {
    int v = (t >= off) ? part[t - off] : 0;
    __syncthreads();
    part[t] += v;
    __syncthreads();
  }
  int excl = (t == 0) ? 0 : part[t - 1];
  for (int i = b; i < e; i++) { out[i] = excl; excl += in[i]; }
  if (t == 0) out[NN] = part[1023];
}

// writes eids (edge id, for score/ekey addressing) AND gsrc (resolved src node,
// so sage_gather/softmax avoid the dependent src[eids[i]] two-hop gather)
__global__ void k_csr_scatter(const int* __restrict__ pE, const int* __restrict__ src,
                              const int* __restrict__ dst, const int* __restrict__ coff,
                              int* __restrict__ cursor, int* __restrict__ eids,
                              int* __restrict__ gsrc) {
  int e = blockIdx.x * 256 + threadIdx.x;
  if (e >= *pE) return;
  int d = dst[e];
  int pos = coff[d] + atomicAdd(&cursor[d], 1);
  eids[pos] = e;
  gsrc[pos] = src[e];
}

// ---------------- SAGE mean aggregation: CSR gather, 32 lanes/node ----------------
// block 0 also zeroes bnsum for the following gemm's fused BN stats
__global__ __launch_bounds__(256) void k_sage_gather(
    const int* __restrict__ coff, const int* __restrict__ gsrc,
    const float* __restrict__ x, float* __restrict__ mean,
    double* __restrict__ bnsum) {
  if (blockIdx.x == 0 && threadIdx.x < 2 * HID) bnsum[threadIdx.x] = 0.0;
  int grp = threadIdx.x >> 5;           // 8 nodes per block
  int lane = threadIdx.x & 31;
  int n = blockIdx.x * 8 + grp;
  if (n >= NN) return;
  int b = coff[n], e2 = coff[n + 1];
  float4 acc = make_float4(0.f, 0.f, 0.f, 0.f);
  int i = b;
  for (; i + 1 < e2; i += 2) {
    int s0 = gsrc[i], s1 = gsrc[i + 1];
    float4 v0 = *(const float4*)(x + (size_t)s0 * HID + lane * 4);
    float4 v1 = *(const float4*)(x + (size_t)s1 * HID + lane * 4);
    acc.x += v0.x; acc.y += v0.y; acc.z += v0.z; acc.w += v0.w;
    acc.x += v1.x; acc.y += v1.y; acc.z += v1.z; acc.w += v1.w;
  }
  if (i < e2) {
    int s0 = gsrc[i];
    float4 v0 = *(const float4*)(x + (size_t)s0 * HID + lane * 4);
    acc.x += v0.x; acc.y += v0.y; acc.z += v0.z; acc.w += v0.w;
  }
  float inv = 1.0f / fmaxf((float)(e2 - b), 1.0f);
  acc.x *= inv; acc.y *= inv; acc.z *= inv; acc.w *= inv;
  *(float4*)(mean + (size_t)n * HID + lane * 4) = acc;
}

// out[n][0:128] = A1@W1^T + A2@W2^T + bias; optional relu; optional fused BN
// stats (masked column sum/sumsq -> bnsum, zeroed by preceding k_sage_gather).
// 128x128 tile, 8x8 per thread, Ast transposed so inner step = 4 ds_read_b128
// per 64 FMA (old gemm: 9 LDS insts per 32 FMA).
__global__ __launch_bounds__(256) void gemm_dual2(
    const float* __restrict__ A1, const float* __restrict__ W1,
    const float* __restrict__ A2, const float* __restrict__ W2,
    const float* __restrict__ bias, float* __restrict__ out,
    int M, int ldw, int relu, const int* __restrict__ nvb,
    double* __restrict__ bnsum, int dostats) {
  __shared__ float Ast[16][GPAD];   // [kk][row]
  __shared__ float Ws[16][GPAD];    // [kk][col]
  int tid = threadIdx.x;
  int rg = tid >> 4, cg = tid & 15;
  int r0 = rg * 8, c0 = cg * 8;
  int row0 = blockIdx.x * 128;
  float acc[8][8];
#pragma unroll
  for (int a = 0; a < 8; a++)
#pragma unroll
    for (int bq = 0; bq < 8; bq++) acc[a][bq] = 0.f;

  for (int srcI = 0; srcI < 2; srcI++) {
    const float* A = srcI ? A2 : A1;
    const float* W = srcI ? W2 : W1;
    for (int kc = 0; kc < 128; kc += 16) {
#pragma unroll
      for (int i = 0; i < 2; i++) {
        int k = tid + i * 256;
        int r = k >> 2, c4 = (k & 3) << 2;
        int gr = row0 + r;
        float4 v = make_float4(0.f, 0.f, 0.f, 0.f);
        if (gr < M) v = *(const float4*)(A + (size_t)gr * 128 + kc + c4);
        Ast[c4 + 0][r] = v.x; Ast[c4 + 1][r] = v.y;
        Ast[c4 + 2][r] = v.z; Ast[c4 + 3][r] = v.w;
        float4 w = *(const float4*)(W + (size_t)r * ldw + kc + c4);
        Ws[c4 + 0][r] = w.x; Ws[c4 + 1][r] = w.y;
        Ws[c4 + 2][r] = w.z; Ws[c4 + 3][r] = w.w;
      }
      __syncthreads();
#pragma unroll
      for (int kk = 0; kk < 16; kk++) {
        float4 a0 = *(const float4*)(&Ast[kk][r0]);
        float4 a1 = *(const float4*)(&Ast[kk][r0 + 4]);
        float4 b0 = *(const float4*)(&Ws[kk][c0]);
        float4 b1 = *(const float4*)(&Ws[kk][c0 + 4]);
        float av[8] = {a0.x, a0.y, a0.z, a0.w, a1.x, a1.y, a1.z, a1.w};
        float bv[8] = {b0.x, b0.y, b0.z, b0.w, b1.x, b1.y, b1.z, b1.w};
#pragma unroll
        for (int rr = 0; rr < 8; rr++)
#pragma unroll
          for (int cc = 0; cc < 8; cc++) acc[rr][cc] += av[rr] * bv[cc];
      }
      __syncthreads();
    }
  }

  float sCol[8], qCol[8];
#pragma unroll
  for (int cc = 0; cc < 8; cc++) { sCol[cc] = 0.f; qCol[cc] = 0.f; }
#pragma unroll
  for (int rr = 0; rr < 8; rr++) {
    int gr = row0 + r0 + rr;
    if (gr >= M) continue;
    int valid = dostats ? nvb[gr] : 0;
    float vv[8];
#pragma unroll
    for (int cc = 0; cc < 8; cc++) {
      float v = acc[rr][cc] + bias[c0 + cc];
      if (relu) v = fmaxf(v, 0.f);
      vv[cc] = v;
      if (valid) { sCol[cc] += v; qCol[cc] += v * v; }
    }
    *(float4*)(out + (size_t)gr * 128 + c0) = make_float4(vv[0], vv[1], vv[2], vv[3]);
    *(float4*)(out + (size_t)gr * 128 + c0 + 4) = make_float4(vv[4], vv[5], vv[6], vv[7]);
  }
  if (dostats) {
    // loop-end barrier already separates last LDS reads; reuse Ast/Ws as [16][128]
#pragma unroll
    for (int cc = 0; cc < 8; cc++) { Ast[rg][c0 + cc] = sCol[cc]; Ws[rg][c0 + cc] = qCol[cc]; }
    __syncthreads();
    if (tid < HID) {
      float s = 0.f, q = 0.f;
#pragma unroll
      for (int g = 0; g < 16; g++) { s += Ast[g][tid]; q += Ws[g][tid]; }
      atomicAdd(&bnsum[tid], (double)s);
      atomicAdd(&bnsum[HID + tid], (double)q);
    }
  }
}

__global__ void k_bn_apply(float* __restrict__ x, const double* __restrict__ sums,
                           const int* __restrict__ cnt, const float* __restrict__ gamma,
                           const float* __restrict__ beta) {
  int t = blockIdx.x * 256 + threadIdx.x;
  if (t >= NN * HID) return;
  int k = t & 127;
  double c = (double)((*cnt > 1) ? *cnt : 1);
  double mu = sums[k] / c;
  double var = sums[HID + k] / c - mu * mu;
  if (var < 0.0) var = 0.0;
  float inv = (float)(1.0 / sqrt(var + (double)BN_EPS));
  x[t] = gamma[k] * (x[t] - (float)mu) * inv + beta[k];
}

// ---------------- edge pool ----------------
__global__ void k_node_proj(const float* __restrict__ x, const float* __restrict__ Wp,
                            float* __restrict__ px1, float* __restrict__ px2) {
  int n = blockIdx.x * 256 + threadIdx.x;
  if (n >= NN) return;
  const float* xr = x + (size_t)n * HID;
  float s1 = 0.f, s2 = 0.f;
#pragma unroll 8
  for (int k = 0; k < HID; k += 4) {
    float4 v = *(const float4*)(xr + k);
    float4 w1 = *(const float4*)(Wp + k);
    float4 w2 = *(const float4*)(Wp + HID + k);
    s1 += v.x * w1.x + v.y * w1.y + v.z * w1.z + v.w * w1.w;
    s2 += v.x * w2.x + v.y * w2.y + v.z * w2.z + v.w * w2.w;
  }
  px1[n] = s1; px2[n] = s2;
}

// fused: S init + per-dst softmax + suitor keys
__global__ void k_edge_softmax_seed(
    const int* __restrict__ coff, const int* __restrict__ eids,
    const int* __restrict__ gsrc, const float* __restrict__ px1,
    const float* __restrict__ px2, const float* __restrict__ bp,
    float* __restrict__ score, u64* __restrict__ ekey, u64* __restrict__ S) {
  int n = blockIdx.x * 256 + threadIdx.x;
  if (n >= NN) return;
  S[n] = 0ull;
  int b = coff[n], e2 = coff[n + 1];
  if (b == e2) return;
  float p2 = px2[n] + *bp;
  float mx = -3.4e38f;
  for (int i = b; i < e2; i++) {
    float r = px1[gsrc[i]] + p2;
    mx = fmaxf(mx, r);
  }
  double den = 0.0;
  for (int i = b; i < e2; i++) {
    int eid = eids[i];
    float z = expf(px1[gsrc[i]] + p2 - mx);
    score[eid] = z;
    den += (double)z;
  }
  if (den < 1e-16) den = 1e-16;
  double invd = 1.0 / den;
  for (int i = b; i < e2; i++) {
    int eid = eids[i];
    float sc = (float)((double)score[eid] * invd) + 0.5f;
    score[eid] = sc;
    // key: score desc, then lower edge index wins (matches stable argsort(-score))
    ekey[eid] = ((u64)__float_as_uint(sc) << 32) | (u64)(0xFFFFFFFFu - (u32)eid);
  }
}

// incidence scatter with INLINE payload {key, partner}
__global__ void k_inc_scatter(const int* __restrict__ pE, const int* __restrict__ src,
                              const int* __restrict__ dst, const u64* __restrict__ ekey,
                              const int* __restrict__ ioff, int* __restrict__ icur,
                              int4* __restrict__ ielist) {
  int e = blockIdx.x * 256 + threadIdx.x;
  if (e >= *pE) return;
  int s = src[e], d = dst[e];
  if (s == d) return;
  u64 k = ekey[e];
  int4 ent;
  ent.x = (int)(u32)(k & 0xFFFFFFFFull);
  ent.y = (int)(u32)(k >> 32);
  ent.w = 0;
  ent.z = d;
  ielist[ioff[s] + atomicAdd(&icur[s], 1)] = ent;
  ent.z = s;
  ielist[ioff[d] + atomicAdd(&icur[d], 1)] = ent;
}

// ---------------- Suitor matching, wave-per-node, register-resident ----------------
__global__ __launch_bounds__(256) void k_suitor(
    const int* __restrict__ ioff, const int4* __restrict__ ielist,
    const int* __restrict__ src, const int* __restrict__ dst,
    u64* __restrict__ S) {
  int wid = threadIdx.x >> 6;
  int lane = threadIdx.x & 63;
  int n = blockIdx.x * 4 + wid;
  if (n >= NN) return;
  int cur = n;
  while (cur >= 0) {
    int b = ioff[cur], e2 = ioff[cur + 1];
    int deg = e2 - b;
    if (deg == 0) break;
    if (deg <= 64 * SLOTS) {
      u64 key[SLOTS]; int pv[SLOTS];
#pragma unroll
      for (int s = 0; s < SLOTS; s++) {
        key[s] = 0; pv[s] = 0;
        int i = b + s * 64 + lane;
        if (i < e2) {
          int4 ent = ielist[i];
          key[s] = ent_key(ent);
          pv[s] = ent.z;
        }
      }
      long long res;
      for (;;) {
        u64 localBest = 0;
#pragma unroll
        for (int s = 0; s < SLOTS; s++) {
          if (!key[s]) continue;
          u64 sv = __hip_atomic_load(&S[pv[s]], __ATOMIC_RELAXED, __HIP_MEMORY_SCOPE_AGENT);
          if (sv >= key[s]) key[s] = 0;              // permanently dead
          else if (key[s] > localBest) localBest = key[s];
        }
        u64 bestKey = localBest;
#pragma unroll
        for (int o = 32; o > 0; o >>= 1) {
          u64 other = __shfl_xor(bestKey, o, 64);
          if (other > bestKey) bestKey = other;
        }
        if (bestKey == 0) { res = -1; break; }
        int ms = -1;
#pragma unroll
        for (int s = 0; s < SLOTS; s++)
          if (ms < 0 && key[s] == bestKey) ms = s;
        u64 ball = __ballot(ms >= 0);
        int owner = (int)(__ffsll((long long)ball) - 1);
        long long r0 = -3;
        if (lane == owner) {
          int bv = pv[ms];
          u64 old = atomicMax(&S[bv], bestKey);
          if (old >= bestKey) { key[ms] = 0; r0 = -2; }
          else if (old == 0) r0 = -1;
          else {
            int eo = (int)(0xFFFFFFFFu - (u32)(old & 0xFFFFFFFFull));
            int so = src[eo], do_ = dst[eo];
            r0 = (so == bv) ? do_ : so;
          }
        }
        res = __shfl(r0, owner, 64);
        if (res != -2) break;
      }
      if (res < 0) break;
      cur = (int)res;
    } else {
      u64 bestKey = 0;
      for (int i = b + lane; i < e2; i += 64) {
        int4 ent = ielist[i];
        u64 k = ent_key(ent);
        if (k <= bestKey) continue;
        u64 sv = __hip_atomic_load(&S[ent.z], __ATOMIC_RELAXED, __HIP_MEMORY_SCOPE_AGENT);
        if (k > sv) bestKey = k;
      }
#pragma unroll
      for (int o = 32; o > 0; o >>= 1) {
        u64 other = __shfl_xor(bestKey, o, 64);
        if (other > bestKey) bestKey = other;
      }
      long long r0 = -1;
      if (bestKey != 0 && lane == 0) {
        int e = (int)(0xFFFFFFFFu - (u32)(bestKey & 0xFFFFFFFFull));
        int es = src[e], ed = dst[e];
        int bv = (es == cur) ? ed : es;
        u64 old = atomicMax(&S[bv], bestKey);
        if (old >= bestKey) r0 = cur;
        else if (old != 0) {
          int eo = (int)(0xFFFFFFFFu - (u32)(old & 0xFFFFFFFFull));
          int so = src[eo], do_ = dst[eo];
          r0 = (so == bv) ? do_ : so;
        }
      }
      long long res = (bestKey != 0) ? __shfl(r0, 0, 64) : -1;
      cur = (int)res;
    }
  }
}

// new_x gather + cluster derivation from S + nvb update + zero b3
__global__ __launch_bounds__(256) void k_new_x(
    const u64* __restrict__ S, const int* __restrict__ src, const int* __restrict__ dst,
    const float* __restrict__ score, const float* __restrict__ x,
    float* __restrict__ out, int* __restrict__ cluster,
    int* __restrict__ nvb, int* __restrict__ b3zero) {
  int gt = blockIdx.x * 256 + threadIdx.x;
  if (gt < 2 * NN) b3zero[gt] = 0;
  int grp = threadIdx.x >> 5;
  int lane = threadIdx.x & 31;
  int n = blockIdx.x * 8 + grp;
  if (n >= NN) return;
  u64 k = S[n];
  int partner = -1;
  int rep = n;
  bool isOth = false;
  float sc = 1.f;
  if (k) {
    int e = (int)(0xFFFFFFFFu - (u32)(k & 0xFFFFFFFFull));
    int s = src[e], d = dst[e];
    int other = (s == n) ? d : s;
    if (S[other] == k) {
      if (n > other) { isOth = true; rep = other; }
      else { partner = other; sc = score[e]; }
    }
  }
  float4 v = make_float4(0.f, 0.f, 0.f, 0.f);
  if (!isOth) {
    v = *(const float4*)(x + (size_t)n * HID + lane * 4);
    if (partner >= 0) {
      float4 w = *(const float4*)(x + (size_t)partner * HID + lane * 4);
      v.x = (v.x + w.x) * sc; v.y = (v.y + w.y) * sc;
      v.z = (v.z + w.z) * sc; v.w = (v.w + w.w) * sc;
    }
  }
  *(float4*)(out + (size_t)n * HID + lane * 4) = v;
  if (lane == 0) {
    cluster[n] = rep;
    nvb[n] = (nvb[n] && !isOth) ? 1 : 0;
  }
}

// ---------------- dedup (sorted unique of (cs,cd)) ----------------
__global__ void k_bucket_count(const int* __restrict__ pE, const int* __restrict__ src,
                               const int* __restrict__ cluster, int* __restrict__ bcount) {
  int e = blockIdx.x * 256 + threadIdx.x;
  if (e >= *pE) return;
  atomicAdd(&bcount[cluster[src[e]]], 1);
}

__global__ __launch_bounds__(1024) void k_scan(const int* __restrict__ in, int* __restrict__ out,
                                               int n, int* totalDst) {
  __shared__ int part[1024];
  int t = threadIdx.x;
  int chunk = (n + 1023) / 1024;
  int b = t * chunk, e = b + chunk;
  if (b > n) b = n;
  if (e > n) e = n;
  int s = 0;
  for (int i = b; i < e; i++) s += in[i];
  part[t] = s;
  __syncthreads();
  for (int off = 1; off < 1024; off <<= 1) {
    int v = (t >= off) ? part[t - off] : 0;
    __syncthreads();
    part[t] += v;
    __syncthreads();
  }
  int excl = (t == 0) ? 0 : part[t - 1];
  int total = part[1023];
  for (int i = b; i < e; i++) { out[i] = excl; excl += in[i]; }
  if (t == 0) {
    out[n] = total;
    if (totalDst) *totalDst = total;
  }
}

__global__ void k_bucket_scatter(const int* __restrict__ pE, const int* __restrict__ src,
                                 const int* __restrict__ dst, const int* __restrict__ cluster,
                                 const int* __restrict__ boffs, int* __restrict__ bcursor,
                                 int* __restrict__ bucket) {
  int e = blockIdx.x * 256 + threadIdx.x;
  if (e >= *pE) return;
  int cs = cluster[src[e]], cd = cluster[dst[e]];
  int pos = boffs[cs] + atomicAdd(&bcursor[cs], 1);
  bucket[pos] = cd;
}

// sorted-unique per bucket via per-wave LDS bitmap
__global__ __launch_bounds__(256) void k_dedup_bitmap(
    const int* __restrict__ boffs, int* __restrict__ bucket,
    int* __restrict__ ucount) {
  __shared__ u32 bm[4][960];
  int wid = threadIdx.x >> 6;
  int lane = threadIdx.x & 63;
  int n = blockIdx.x * 4 + wid;
  int b = boffs[n], e = boffs[n + 1];
  for (int w = lane; w < 960; w += 64) bm[wid][w] = 0;
  __syncthreads();
  for (int i = b + lane; i < e; i += 64)
    atomicOr(&bm[wid][bucket[i] >> 5], 1u << (bucket[i] & 31));
  __syncthreads();
  int w0 = lane * 15;
  int w1 = w0 + 15; if (w1 > WPB) w1 = WPB;
  int cnt = 0;
  for (int w = w0; w < w1; w++) cnt += __popc(bm[wid][w]);
  int inc = cnt;
  for (int o = 1; o < 64; o <<= 1) { int v = __shfl_up(inc, o); if (lane >= o) inc += v; }
  int excl = inc - cnt;
  int total = __shfl(inc, 63);
  int pos = b + excl;
  for (int w = w0; w < w1; w++) {
    u32 v = bm[wid][w];
    while (v) { int bit = __ffs(v) - 1; bucket[pos++] = (w << 5) | bit; v &= v - 1; }
  }
  if (lane == 0) ucount[n] = total;
}

// emit compacted edges + zero bcount/bcursor/icnt/icursor/pcnt for next level
__global__ void k_emit(const int* __restrict__ boffs, const int* __restrict__ bucket,
                       const int* __restrict__ bucount, const int* __restrict__ bnoffs,
                       int* __restrict__ srcO, int* __restrict__ dstO,
                       int* __restrict__ b3zero, int* __restrict__ i2zero,
                       int* __restrict__ pcnt) {
  int t = blockIdx.x * 256 + threadIdx.x;
  int stride = gridDim.x * 256;
  for (int z = t; z < 2 * NN; z += stride) { b3zero[z] = 0; i2zero[z] = 0; }
  if (t == 0) *pcnt = 0;
  if (t >= NN) return;
  int u = bucount[t], b = boffs[t], o = bnoffs[t];
  for (int i = 0; i < u; i++) { srcO[o + i] = t; dstO[o + i] = bucket[b + i]; }
}

// ---------------- readout ----------------
__global__ void k_graph_pool(const int* __restrict__ nvb, const int* __restrict__ batch,
                             const float* __restrict__ x, float* __restrict__ gsum,
                             float* __restrict__ gcnt) {
  int t = blockIdx.x * 256 + threadIdx.x;
  int n = t >> 2;
  if (n >= NN) return;
  if (!nvb[n]) return;
  int sub = t & 3;
  int g = batch[n];
  const float* xr = x + (size_t)n * HID + sub * 32;
  float* o = gsum + (size_t)g * HID + sub * 32;
#pragma unroll
  for (int i = 0; i < 8; i++) {
    float4 v = *(const float4*)(xr + i * 4);
    atomicAdd(o + i * 4 + 0, v.x); atomicAdd(o + i * 4 + 1, v.y);
    atomicAdd(o + i * 4 + 2, v.z); atomicAdd(o + i * 4 + 3, v.w);
  }
  if (sub == 0) atomicAdd(&gcnt[g], 1.0f);
}

__global__ __launch_bounds__(128) void k_head1(const float* __restrict__ gsum,
                                               const float* __restrict__ gcnt,
                                               const float* __restrict__ Wf1,
                                               const float* __restrict__ bf1,
                                               float* __restrict__ hfc) {
  int g = blockIdx.x;
  int j = threadIdx.x;
  __shared__ float p[HID];
  float c = fmaxf(gcnt[g], 1.f);
  p[j] = gsum[g * HID + j] / c;
  __syncthreads();
  float s = bf1[j];
  const float* w = Wf1 + (size_t)j * HID;
  for (int k = 0; k < HID; k++) s += p[k] * w[k];
  hfc[g * HID + j] = fmaxf(s, 0.f);
}

__global__ void k_head2(const float* __restrict__ hfc, const float* __restrict__ Wf2,
                        const float* __restrict__ bf2, float* __restrict__ out) {
  int g = blockIdx.x;
  int t = threadIdx.x;
  __shared__ float lg[NC];
  if (t < NC) {
    float s = bf2[t];
    const float* w = Wf2 + (size_t)t * HID;
    const float* h = hfc + (size_t)g * HID;
    for (int k = 0; k < HID; k++) s += h[k] * w[k];
    lg[t] = s;
  }
  __syncthreads();
  if (t == 0) {
    float m = lg[0];
    for (int c = 1; c < NC; c++) m = fmaxf(m, lg[c]);
    float se = 0.f;
    for (int c = 0; c < NC; c++) se += expf(lg[c] - m);
    float lse = m + logf(se);
    for (int c = 0; c < NC; c++) out[g * NC + c] = lg[c] - lse;
  }
}

extern "C" void kernel_launch(void* const* d_in, const int* in_sizes, int n_in,
                              void* d_out, int out_size, void* d_ws, size_t ws_size,
                              hipStream_t stream) {
  const float* x0 = (const float*)d_in[0];
  const int* ei = (const int*)d_in[1];
  const int* batch = (const int*)d_in[2];
  const float* Wl = (const float*)d_in[3];
  const float* bl = (const float*)d_in[4];
  const float* Wr = (const float*)d_in[5];
  const float* gamma = (const float*)d_in[6];
  const float* beta = (const float*)d_in[7];
  const float* Wlin = (const float*)d_in[8];
  const float* blin = (const float*)d_in[9];
  const float* Wp = (const float*)d_in[10];
  const float* bp = (const float*)d_in[11];
  const float* Wf1 = (const float*)d_in[12];
  const float* bf1 = (const float*)d_in[13];
  const float* Wf2 = (const float*)d_in[14];
  const float* bf2 = (const float*)d_in[15];
  float* out = (float*)d_out;

  const int NH = NN * HID;
  size_t off = 0;
  char* base = (char*)d_ws;
  auto carve = [&](size_t bytes) -> char* {
    char* p = base + off;
    off += (bytes + 255) & ~(size_t)255;
    return p;
  };
  float* xa = (float*)carve((size_t)NH * 4);
  float* xb = (float*)carve((size_t)NH * 4);
  float* xc = (float*)carve((size_t)NH * 4);   // ALSO aliased as ielist (same 15.36 MB)
  float* xd = (float*)carve((size_t)NH * 4);
  int* srcA = (int*)carve((size_t)NE * 4);
  int* dstA = (int*)carve((size_t)NE * 4);
  int* srcB = (int*)carve((size_t)NE * 4);
  int* dstB = (int*)carve((size_t)NE * 4);
  float* escore = (float*)carve((size_t)NE * 4);
  int* ebucket = (int*)carve((size_t)NE * 4);
  int* eids = (int*)carve((size_t)NE * 4);
  int* gsrc = (int*)carve((size_t)NE * 4);
  u64* ekey = (u64*)carve((size_t)NE * 8);
  u64* S = (u64*)carve((size_t)NN * 8);
  float* npx1 = (float*)carve((size_t)NN * 4);
  float* npx2 = (float*)carve((size_t)NN * 4);
  int* ncluster = (int*)carve((size_t)NN * 4);
  int* nvb = (int*)carve((size_t)NN * 4);
  int* b3 = (int*)carve((size_t)3 * NN * 4);
  int* bcount = b3;
  int* bcursor = b3 + NN;
  int* bucount = b3 + 2 * NN;
  int* i2 = (int*)carve((size_t)2 * NN * 4);
  int* icnt = i2;
  int* icursor = i2 + NN;
  int* boffs = (int*)carve((size_t)(NN + 1) * 4);
  int* bnoffs = (int*)carve((size_t)(NN + 1) * 4);
  int* csroff = (int*)carve((size_t)(NN + 1) * 4);
  int* ioff = (int*)carve((size_t)(NN + 1) * 4);
  double* bnsum = (double*)carve((size_t)2 * HID * 8);
  float* gbuf = (float*)carve((size_t)(NG * HID + NG) * 4);
  float* gsum = gbuf;
  float* gcnt = gbuf + NG * HID;
  float* ghfc = (float*)carve((size_t)NG * HID * 4);
  int* scal = (int*)carve(64 * 4);
  (void)ws_size; (void)n_in; (void)in_sizes; (void)out_size;

  // ielist aliases xc (2*NE*16 B == NH*4 B): xc is dead after the concat gemm
  // and is rewritten next level only after suitor completes.
  int4* ielist = (int4*)xc;

  int* pE = scal;        // E_cur
  int* pcnt = scal + 1;  // valid node count

  k_init<<<1875, 256, 0, stream>>>(ei, srcA, dstA, nvb, scal, b3, i2, gbuf);

  int* srcC = srcA; int* dstC = dstA; int* srcN = srcB; int* dstN = dstB;
  float* xcur = xa;
  float* xtmp = xd;

  auto sage = [&](const float* xin, float* xout, int L) {
    k_sage_gather<<<3750, 256, 0, stream>>>(csroff, gsrc, xin, xtmp, bnsum);
    gemm_dual2<<<235, 256, 0, stream>>>(xtmp, Wl + (size_t)L * HID * HID, xin,
                                        Wr + (size_t)L * HID * HID, bl + (size_t)L * HID,
                                        xout, NN, HID, 1, nvb, bnsum, 1);
    k_bn_apply<<<15000, 256, 0, stream>>>(xout, bnsum, pcnt, gamma + (size_t)L * HID,
                                          beta + (size_t)L * HID);
  };

  for (int b = 0; b < 3; b++) {
    const float* xin = (b == 0) ? x0 : (const float*)xcur;

    // dst-CSR (sage + softmax) + incidence counts
    k_csr_count<<<1875, 256, 0, stream>>>(pE, srcC, dstC, bcount, icnt, nvb, pcnt);
    k_scan2<<<2, 1024, 0, stream>>>(bcount, csroff, icnt, ioff);
    k_csr_scatter<<<1875, 256, 0, stream>>>(pE, srcC, dstC, csroff, bcursor, eids, gsrc);

    sage(xin, xb, 2 * b);
    sage(xb, xc, 2 * b + 1);
    gemm_dual2<<<235, 256, 0, stream>>>(xc, Wlin + (size_t)b * HID * 2 * HID, xb,
                                        Wlin + (size_t)b * HID * 2 * HID + HID,
                                        blin + (size_t)b * HID, xcur, NN, 2 * HID, 0,
                                        nvb, bnsum, 0);

    // ----- edge pooling: softmax scores -> inline-payload incidence -> suitor -----
    k_node_proj<<<118, 256, 0, stream>>>(xcur, Wp + (size_t)b * 2 * HID, npx1, npx2);
    k_edge_softmax_seed<<<118, 256, 0, stream>>>(csroff, eids, gsrc, npx1, npx2, bp + b,
                                                 escore, ekey, S);
    k_inc_scatter<<<1875, 256, 0, stream>>>(pE, srcC, dstC, ekey, ioff, icursor, ielist);
    k_suitor<<<7500, 256, 0, stream>>>(ioff, ielist, srcC, dstC, S);
    k_new_x<<<3750, 256, 0, stream>>>(S, srcC, dstC, escore, xcur, xtmp,
                                      ncluster, nvb, b3);

    if (b < 2) {  // level-2 coarse edges are never consumed
      k_bucket_count<<<1875, 256, 0, stream>>>(pE, srcC, ncluster, bcount);
      k_scan<<<1, 1024, 0, stream>>>(bcount, boffs, NN, (int*)nullptr);
      k_bucket_scatter<<<1875, 256, 0, stream>>>(pE, srcC, dstC, ncluster, boffs, bcursor,
                                                 ebucket);
      k_dedup_bitmap<<<7500, 256, 0, stream>>>(boffs, ebucket, bucount);
      k_scan<<<1, 1024, 0, stream>>>(bucount, bnoffs, NN, pE);
      k_emit<<<235, 256, 0, stream>>>(boffs, ebucket, bucount, bnoffs, srcN, dstN,
                                      b3, i2, pcnt);
      { int* t = srcC; srcC = srcN; srcN = t; t = dstC; dstC = dstN; dstN = t; }
    }
    { float* t = xcur; xcur = xtmp; xtmp = t; }
  }

  k_graph_pool<<<469, 256, 0, stream>>>(nvb, batch, xcur, gsum, gcnt);
  k_head1<<<NG, 128, 0, stream>>>(gsum, gcnt, Wf1, bf1, ghfc);
  k_head2<<<NG, 32, 0, stream>>>(ghfc, Wf2, bf2, out);
}

// Round 11
// 2525.764 us; speedup vs baseline: 19.5603x; 1.0073x over previous
//
#include <hip/hip_runtime.h>
#include <stdint.h>

#define NN 30000
#define NE 480000
#define HID 128
#define NG 128
#define NC 6
#define BN_EPS 1e-5f
#define WPB 938   // ceil(NN/32) bitmap words
#define SLOTS 4   // reg-resident suitor entries per lane (deg <= 256)
#define GPAD 132

typedef unsigned int u32;
typedef unsigned long long u64;

__device__ __forceinline__ u64 ent_key(int4 ent) {
  return ((u64)(u32)ent.y << 32) | (u32)ent.x;
}

// ---------------- init (also zeroes all per-call state) ----------------
__global__ void k_init(const int* __restrict__ ei, int* srcA, int* dstA, int* nvb,
                       int* scal, int* b3, int* i2, float* gbuf,
                       double* __restrict__ bnsum) {
  int t = blockIdx.x * 256 + threadIdx.x;
  if (t < NE) { srcA[t] = ei[t]; dstA[t] = ei[NE + t]; }
  if (t < NN) nvb[t] = 1;
  if (t < 2 * NN) { b3[t] = 0; i2[t] = 0; }   // bcount,bcursor + icnt,icursor
  if (t < NG * HID + NG) gbuf[t] = 0.f;
  if (t < 2 * HID) bnsum[t] = 0.0;
  if (t == 0) { scal[0] = NE; scal[1] = 0; }
}

// ---------------- CSR build (dst CSR + incidence counts) + valid-node count ----------------
__global__ void k_csr_count(const int* __restrict__ pE, const int* __restrict__ src,
                            const int* __restrict__ dst, int* __restrict__ cnt,
                            int* __restrict__ icnt, const int* __restrict__ nvb,
                            int* __restrict__ pcnt) {
  int t = blockIdx.x * 256 + threadIdx.x;
  if (t < NN && nvb[t]) atomicAdd(pcnt, 1);
  if (t < *pE) {
    int s = src[t], d = dst[t];
    atomicAdd(&cnt[d], 1);
    if (s != d) { atomicAdd(&icnt[s], 1); atomicAdd(&icnt[d], 1); }
  }
}

// two independent single-block scans (block 0: dst-CSR, block 1: incidence)
__global__ __launch_bounds__(1024) void k_scan2(const int* __restrict__ in0, int* __restrict__ out0,
                                                const int* __restrict__ in1, int* __restrict__ out1) {
  const int* in = blockIdx.x ? in1 : in0;
  int* out = blockIdx.x ? out1 : out0;
  __shared__ int part[1024];
  int t = threadIdx.x;
  int chunk = (NN + 1023) / 1024;
  int b = t * chunk, e = b + chunk;
  if (b > NN) b = NN;
  if (e > NN) e = NN;
  int s = 0;
  for (int i = b; i < e; i++) s += in[i];
  part[t] = s;
  __syncthreads();
  for (int off = 1; off < 1024; off <<= 1) {
    int v = (t >= off) ? part[t - off] : 0;
    __syncthreads();
    part[t] += v;
    __syncthreads();
  }
  int excl = (t == 0) ? 0 : part[t - 1];
  for (int i = b; i < e; i++) { out[i] = excl; excl += in[i]; }
  if (t == 0) out[NN] = part[1023];
}

// writes eids (edge id) AND gsrc (resolved src node)
__global__ void k_csr_scatter(const int* __restrict__ pE, const int* __restrict__ src,
                              const int* __restrict__ dst, const int* __restrict__ coff,
                              int* __restrict__ cursor, int* __restrict__ eids,
                              int* __restrict__ gsrc) {
  int e = blockIdx.x * 256 + threadIdx.x;
  if (e >= *pE) return;
  int d = dst[e];
  int pos = coff[d] + atomicAdd(&cursor[d], 1);
  eids[pos] = e;
  gsrc[pos] = src[e];
}

// ---------------- SAGE mean aggregation: CSR gather, 32 lanes/node ----------------
__global__ __launch_bounds__(256) void k_sage_gather(
    const int* __restrict__ coff, const int* __restrict__ gsrc,
    const float* __restrict__ x, float* __restrict__ mean) {
  int grp = threadIdx.x >> 5;           // 8 nodes per block
  int lane = threadIdx.x & 31;
  int n = blockIdx.x * 8 + grp;
  if (n >= NN) return;
  int b = coff[n], e2 = coff[n + 1];
  float4 acc = make_float4(0.f, 0.f, 0.f, 0.f);
  int i = b;
  for (; i + 1 < e2; i += 2) {
    int s0 = gsrc[i], s1 = gsrc[i + 1];
    float4 v0 = *(const float4*)(x + (size_t)s0 * HID + lane * 4);
    float4 v1 = *(const float4*)(x + (size_t)s1 * HID + lane * 4);
    acc.x += v0.x; acc.y += v0.y; acc.z += v0.z; acc.w += v0.w;
    acc.x += v1.x; acc.y += v1.y; acc.z += v1.z; acc.w += v1.w;
  }
  if (i < e2) {
    int s0 = gsrc[i];
    float4 v0 = *(const float4*)(x + (size_t)s0 * HID + lane * 4);
    acc.x += v0.x; acc.y += v0.y; acc.z += v0.z; acc.w += v0.w;
  }
  float inv = 1.0f / fmaxf((float)(e2 - b), 1.0f);
  acc.x *= inv; acc.y *= inv; acc.z *= inv; acc.w *= inv;
  *(float4*)(mean + (size_t)n * HID + lane * 4) = acc;
}

// out[n][0:128] = BNaff(A1)@W1^T + BNaff(A2)@W2^T + bias; optional relu;
// optional fused BN stats; optional fused node-proj (px = out-row . Wp).
// BN is folded as a per-column affine on the A-tile loads (a*x+c), computed by
// k_bnfold from the previous layer's fused stats — removes the 30 MB bn_apply
// passes entirely.
__global__ __launch_bounds__(256) void gemm_dual2(
    const float* __restrict__ A1, const float* __restrict__ W1,
    const float* __restrict__ A2, const float* __restrict__ W2,
    const float* __restrict__ bias, float* __restrict__ out,
    int M, int ldw, int relu, const int* __restrict__ nvb,
    double* __restrict__ bnsum, int dostats,
    const float* __restrict__ a1f, const float* __restrict__ c1f,
    const float* __restrict__ a2f, const float* __restrict__ c2f,
    const float* __restrict__ Wp, float* __restrict__ px1, float* __restrict__ px2) {
  __shared__ float Ast[16][GPAD];   // [kk][row]
  __shared__ float Ws[16][GPAD];    // [kk][col]
  int tid = threadIdx.x;
  int rg = tid >> 4, cg = tid & 15;
  int r0 = rg * 8, c0 = cg * 8;
  int row0 = blockIdx.x * 128;
  float acc[8][8];
#pragma unroll
  for (int a = 0; a < 8; a++)
#pragma unroll
    for (int bq = 0; bq < 8; bq++) acc[a][bq] = 0.f;

  for (int srcI = 0; srcI < 2; srcI++) {
    const float* A = srcI ? A2 : A1;
    const float* W = srcI ? W2 : W1;
    const float* fa = srcI ? a2f : a1f;
    const float* fc = srcI ? c2f : c1f;
    for (int kc = 0; kc < 128; kc += 16) {
#pragma unroll
      for (int i = 0; i < 2; i++) {
        int k = tid + i * 256;
        int r = k >> 2, c4 = (k & 3) << 2;
        int gr = row0 + r;
        float4 v = make_float4(0.f, 0.f, 0.f, 0.f);
        if (gr < M) v = *(const float4*)(A + (size_t)gr * 128 + kc + c4);
        if (fa) {
          float4 av = *(const float4*)(fa + kc + c4);
          float4 cv = *(const float4*)(fc + kc + c4);
          v.x = v.x * av.x + cv.x; v.y = v.y * av.y + cv.y;
          v.z = v.z * av.z + cv.z; v.w = v.w * av.w + cv.w;
        }
        Ast[c4 + 0][r] = v.x; Ast[c4 + 1][r] = v.y;
        Ast[c4 + 2][r] = v.z; Ast[c4 + 3][r] = v.w;
        float4 w = *(const float4*)(W + (size_t)r * ldw + kc + c4);
        Ws[c4 + 0][r] = w.x; Ws[c4 + 1][r] = w.y;
        Ws[c4 + 2][r] = w.z; Ws[c4 + 3][r] = w.w;
      }
      __syncthreads();
#pragma unroll
      for (int kk = 0; kk < 16; kk++) {
        float4 a0 = *(const float4*)(&Ast[kk][r0]);
        float4 a1 = *(const float4*)(&Ast[kk][r0 + 4]);
        float4 b0 = *(const float4*)(&Ws[kk][c0]);
        float4 b1 = *(const float4*)(&Ws[kk][c0 + 4]);
        float av[8] = {a0.x, a0.y, a0.z, a0.w, a1.x, a1.y, a1.z, a1.w};
        float bv[8] = {b0.x, b0.y, b0.z, b0.w, b1.x, b1.y, b1.z, b1.w};
#pragma unroll
        for (int rr = 0; rr < 8; rr++)
#pragma unroll
          for (int cc = 0; cc < 8; cc++) acc[rr][cc] += av[rr] * bv[cc];
      }
      __syncthreads();
    }
  }

  float wp1[8], wp2[8];
  if (Wp) {
#pragma unroll
    for (int cc = 0; cc < 8; cc++) { wp1[cc] = Wp[c0 + cc]; wp2[cc] = Wp[HID + c0 + cc]; }
  }
  float* part1 = (float*)Ast;   // [row][cg] overlay (proj); stats uses Ast too
  float* part2 = (float*)Ws;    // (dostats and Wp are never both set)
  float sCol[8], qCol[8];
#pragma unroll
  for (int cc = 0; cc < 8; cc++) { sCol[cc] = 0.f; qCol[cc] = 0.f; }
#pragma unroll
  for (int rr = 0; rr < 8; rr++) {
    int gr = row0 + r0 + rr;
    float p1 = 0.f, p2 = 0.f;
    if (gr < M) {
      int valid = dostats ? nvb[gr] : 0;
      float vv[8];
#pragma unroll
      for (int cc = 0; cc < 8; cc++) {
        float v = acc[rr][cc] + bias[c0 + cc];
        if (relu) v = fmaxf(v, 0.f);
        vv[cc] = v;
        if (valid) { sCol[cc] += v; qCol[cc] += v * v; }
        if (Wp) { p1 += v * wp1[cc]; p2 += v * wp2[cc]; }
      }
      *(float4*)(out + (size_t)gr * 128 + c0) = make_float4(vv[0], vv[1], vv[2], vv[3]);
      *(float4*)(out + (size_t)gr * 128 + c0 + 4) = make_float4(vv[4], vv[5], vv[6], vv[7]);
    }
    if (Wp) { part1[(r0 + rr) * 16 + cg] = p1; part2[(r0 + rr) * 16 + cg] = p2; }
  }
  if (Wp) {
    __syncthreads();
    if (tid < HID && row0 + tid < M) {
      float s1 = 0.f, s2 = 0.f;
#pragma unroll
      for (int g = 0; g < 16; g++) { s1 += part1[tid * 16 + g]; s2 += part2[tid * 16 + g]; }
      px1[row0 + tid] = s1;
      px2[row0 + tid] = s2;
    }
  }
  if (dostats) {
#pragma unroll
    for (int cc = 0; cc < 8; cc++) { Ast[rg][c0 + cc] = sCol[cc]; Ws[rg][c0 + cc] = qCol[cc]; }
    __syncthreads();
    if (tid < HID) {
      float s = 0.f, q = 0.f;
#pragma unroll
      for (int g = 0; g < 16; g++) { s += Ast[g][tid]; q += Ws[g][tid]; }
      atomicAdd(&bnsum[tid], (double)s);
      atomicAdd(&bnsum[HID + tid], (double)q);
    }
  }
}

// tiny: BN affine (a,c) from fused stats; re-zeroes bnsum for next stats gemm
__global__ void k_bnfold(double* __restrict__ bnsum, const int* __restrict__ cnt,
                         const float* __restrict__ gamma, const float* __restrict__ beta,
                         float* __restrict__ affa, float* __restrict__ affc) {
  int k = threadIdx.x;
  double c = (double)((*cnt > 1) ? *cnt : 1);
  double mu = bnsum[k] / c;
  double var = bnsum[HID + k] / c - mu * mu;
  if (var < 0.0) var = 0.0;
  double inv = 1.0 / sqrt(var + (double)BN_EPS);
  double a = (double)gamma[k] * inv;
  affa[k] = (float)a;
  affc[k] = (float)((double)beta[k] - mu * a);
  bnsum[k] = 0.0;
  bnsum[HID + k] = 0.0;
}

// fused: S init + per-dst softmax + suitor keys
__global__ void k_edge_softmax_seed(
    const int* __restrict__ coff, const int* __restrict__ eids,
    const int* __restrict__ gsrc, const float* __restrict__ px1,
    const float* __restrict__ px2, const float* __restrict__ bp,
    float* __restrict__ score, u64* __restrict__ ekey, u64* __restrict__ S) {
  int n = blockIdx.x * 256 + threadIdx.x;
  if (n >= NN) return;
  S[n] = 0ull;
  int b = coff[n], e2 = coff[n + 1];
  if (b == e2) return;
  float p2 = px2[n] + *bp;
  float mx = -3.4e38f;
  for (int i = b; i < e2; i++) {
    float r = px1[gsrc[i]] + p2;
    mx = fmaxf(mx, r);
  }
  double den = 0.0;
  for (int i = b; i < e2; i++) {
    int eid = eids[i];
    float z = expf(px1[gsrc[i]] + p2 - mx);
    score[eid] = z;
    den += (double)z;
  }
  if (den < 1e-16) den = 1e-16;
  double invd = 1.0 / den;
  for (int i = b; i < e2; i++) {
    int eid = eids[i];
    float sc = (float)((double)score[eid] * invd) + 0.5f;
    score[eid] = sc;
    ekey[eid] = ((u64)__float_as_uint(sc) << 32) | (u64)(0xFFFFFFFFu - (u32)eid);
  }
}

// incidence scatter with INLINE payload {key, partner}
__global__ void k_inc_scatter(const int* __restrict__ pE, const int* __restrict__ src,
                              const int* __restrict__ dst, const u64* __restrict__ ekey,
                              const int* __restrict__ ioff, int* __restrict__ icur,
                              int4* __restrict__ ielist) {
  int e = blockIdx.x * 256 + threadIdx.x;
  if (e >= *pE) return;
  int s = src[e], d = dst[e];
  if (s == d) return;
  u64 k = ekey[e];
  int4 ent;
  ent.x = (int)(u32)(k & 0xFFFFFFFFull);
  ent.y = (int)(u32)(k >> 32);
  ent.w = 0;
  ent.z = d;
  ielist[ioff[s] + atomicAdd(&icur[s], 1)] = ent;
  ent.z = s;
  ielist[ioff[d] + atomicAdd(&icur[d], 1)] = ent;
}

// ---------------- Suitor matching, wave-per-BLOCK (64 thr), register-resident ----------------
// 1-wave blocks so finished waves retire independently (4-wave blocks pinned
// whole blocks on straggler chains). Prune pass runs ONCE per node-visit;
// retries after lost races propose directly from register keys — atomicMax's
// return value is the authoritative kill, the prune is only an optimization.
__global__ __launch_bounds__(64) void k_suitor(
    const int* __restrict__ ioff, const int4* __restrict__ ielist,
    const int* __restrict__ src, const int* __restrict__ dst,
    u64* __restrict__ S) {
  int lane = threadIdx.x;
  int cur = blockIdx.x;
  while (cur >= 0) {
    int b = ioff[cur], e2 = ioff[cur + 1];
    int deg = e2 - b;
    if (deg == 0) break;
    if (deg <= 64 * SLOTS) {
      u64 key[SLOTS]; int pv[SLOTS];
#pragma unroll
      for (int s = 0; s < SLOTS; s++) {
        key[s] = 0; pv[s] = 0;
        int i = b + s * 64 + lane;
        if (i < e2) {
          int4 ent = ielist[i];
          key[s] = ent_key(ent);
          pv[s] = ent.z;
        }
      }
      // one prune pass (S monotone -> observed-dead is dead forever)
#pragma unroll
      for (int s = 0; s < SLOTS; s++) {
        if (!key[s]) continue;
        u64 sv = __hip_atomic_load(&S[pv[s]], __ATOMIC_RELAXED, __HIP_MEMORY_SCOPE_AGENT);
        if (sv >= key[s]) key[s] = 0;
      }
      long long res;
      for (;;) {
        u64 bestKey = 0;
#pragma unroll
        for (int s = 0; s < SLOTS; s++)
          if (key[s] > bestKey) bestKey = key[s];
#pragma unroll
        for (int o = 32; o > 0; o >>= 1) {
          u64 other = __shfl_xor(bestKey, o, 64);
          if (other > bestKey) bestKey = other;
        }
        if (bestKey == 0) { res = -1; break; }
        int ms = -1;
#pragma unroll
        for (int s = 0; s < SLOTS; s++)
          if (ms < 0 && key[s] == bestKey) ms = s;
        u64 ball = __ballot(ms >= 0);
        int owner = (int)(__ffsll((long long)ball) - 1);
        long long r0 = -3;
        if (lane == owner) {
          int bv = pv[ms];
          u64 old = atomicMax(&S[bv], bestKey);
          if (old >= bestKey) { key[ms] = 0; r0 = -2; }   // lost; kill slot, re-propose
          else if (old == 0) r0 = -1;                     // accepted, chain ends
          else {
            int eo = (int)(0xFFFFFFFFu - (u32)(old & 0xFFFFFFFFull));
            int so = src[eo], do_ = dst[eo];
            r0 = (so == bv) ? do_ : so;                   // displaced re-seeks
          }
        }
        res = __shfl(r0, owner, 64);
        if (res != -2) break;
      }
      if (res < 0) break;
      cur = (int)res;
    } else {
      u64 bestKey = 0;
      for (int i = b + lane; i < e2; i += 64) {
        int4 ent = ielist[i];
        u64 k = ent_key(ent);
        if (k <= bestKey) continue;
        u64 sv = __hip_atomic_load(&S[ent.z], __ATOMIC_RELAXED, __HIP_MEMORY_SCOPE_AGENT);
        if (k > sv) bestKey = k;
      }
#pragma unroll
      for (int o = 32; o > 0; o >>= 1) {
        u64 other = __shfl_xor(bestKey, o, 64);
        if (other > bestKey) bestKey = other;
      }
      long long r0 = -1;
      if (bestKey != 0 && lane == 0) {
        int e = (int)(0xFFFFFFFFu - (u32)(bestKey & 0xFFFFFFFFull));
        int es = src[e], ed = dst[e];
        int bv = (es == cur) ? ed : es;
        u64 old = atomicMax(&S[bv], bestKey);
        if (old >= bestKey) r0 = cur;
        else if (old != 0) {
          int eo = (int)(0xFFFFFFFFu - (u32)(old & 0xFFFFFFFFull));
          int so = src[eo], do_ = dst[eo];
          r0 = (so == bv) ? do_ : so;
        }
      }
      long long res = (bestKey != 0) ? __shfl(r0, 0, 64) : -1;
      cur = (int)res;
    }
  }
}

// new_x gather + cluster derivation from S + nvb update + zero b3
__global__ __launch_bounds__(256) void k_new_x(
    const u64* __restrict__ S, const int* __restrict__ src, const int* __restrict__ dst,
    const float* __restrict__ score, const float* __restrict__ x,
    float* __restrict__ out, int* __restrict__ cluster,
    int* __restrict__ nvb, int* __restrict__ b3zero) {
  int gt = blockIdx.x * 256 + threadIdx.x;
  if (gt < 2 * NN) b3zero[gt] = 0;
  int grp = threadIdx.x >> 5;
  int lane = threadIdx.x & 31;
  int n = blockIdx.x * 8 + grp;
  if (n >= NN) return;
  u64 k = S[n];
  int partner = -1;
  int rep = n;
  bool isOth = false;
  float sc = 1.f;
  if (k) {
    int e = (int)(0xFFFFFFFFu - (u32)(k & 0xFFFFFFFFull));
    int s = src[e], d = dst[e];
    int other = (s == n) ? d : s;
    if (S[other] == k) {
      if (n > other) { isOth = true; rep = other; }
      else { partner = other; sc = score[e]; }
    }
  }
  float4 v = make_float4(0.f, 0.f, 0.f, 0.f);
  if (!isOth) {
    v = *(const float4*)(x + (size_t)n * HID + lane * 4);
    if (partner >= 0) {
      float4 w = *(const float4*)(x + (size_t)partner * HID + lane * 4);
      v.x = (v.x + w.x) * sc; v.y = (v.y + w.y) * sc;
      v.z = (v.z + w.z) * sc; v.w = (v.w + w.w) * sc;
    }
  }
  *(float4*)(out + (size_t)n * HID + lane * 4) = v;
  if (lane == 0) {
    cluster[n] = rep;
    nvb[n] = (nvb[n] && !isOth) ? 1 : 0;
  }
}

// ---------------- dedup (sorted unique of (cs,cd)) ----------------
__global__ void k_bucket_count(const int* __restrict__ pE, const int* __restrict__ src,
                               const int* __restrict__ cluster, int* __restrict__ bcount) {
  int e = blockIdx.x * 256 + threadIdx.x;
  if (e >= *pE) return;
  atomicAdd(&bcount[cluster[src[e]]], 1);
}

__global__ __launch_bounds__(1024) void k_scan(const int* __restrict__ in, int* __restrict__ out,
                                               int n, int* totalDst) {
  __shared__ int part[1024];
  int t = threadIdx.x;
  int chunk = (n + 1023) / 1024;
  int b = t * chunk, e = b + chunk;
  if (b > n) b = n;
  if (e > n) e = n;
  int s = 0;
  for (int i = b; i < e; i++) s += in[i];
  part[t] = s;
  __syncthreads();
  for (int off = 1; off < 1024; off <<= 1) {
    int v = (t >= off) ? part[t - off] : 0;
    __syncthreads();
    part[t] += v;
    __syncthreads();
  }
  int excl = (t == 0) ? 0 : part[t - 1];
  int total = part[1023];
  for (int i = b; i < e; i++) { out[i] = excl; excl += in[i]; }
  if (t == 0) {
    out[n] = total;
    if (totalDst) *totalDst = total;
  }
}

__global__ void k_bucket_scatter(const int* __restrict__ pE, const int* __restrict__ src,
                                 const int* __restrict__ dst, const int* __restrict__ cluster,
                                 const int* __restrict__ boffs, int* __restrict__ bcursor,
                                 int* __restrict__ bucket) {
  int e = blockIdx.x * 256 + threadIdx.x;
  if (e >= *pE) return;
  int cs = cluster[src[e]], cd = cluster[dst[e]];
  int pos = boffs[cs] + atomicAdd(&bcursor[cs], 1);
  bucket[pos] = cd;
}

// sorted-unique per bucket via per-wave LDS bitmap
__global__ __launch_bounds__(256) void k_dedup_bitmap(
    const int* __restrict__ boffs, int* __restrict__ bucket,
    int* __restrict__ ucount) {
  __shared__ u32 bm[4][960];
  int wid = threadIdx.x >> 6;
  int lane = threadIdx.x & 63;
  int n = blockIdx.x * 4 + wid;
  int b = boffs[n], e = boffs[n + 1];
  for (int w = lane; w < 960; w += 64) bm[wid][w] = 0;
  __syncthreads();
  for (int i = b + lane; i < e; i += 64)
    atomicOr(&bm[wid][bucket[i] >> 5], 1u << (bucket[i] & 31));
  __syncthreads();
  int w0 = lane * 15;
  int w1 = w0 + 15; if (w1 > WPB) w1 = WPB;
  int cnt = 0;
  for (int w = w0; w < w1; w++) cnt += __popc(bm[wid][w]);
  int inc = cnt;
  for (int o = 1; o < 64; o <<= 1) { int v = __shfl_up(inc, o); if (lane >= o) inc += v; }
  int excl = inc - cnt;
  int total = __shfl(inc, 63);
  int pos = b + excl;
  for (int w = w0; w < w1; w++) {
    u32 v = bm[wid][w];
    while (v) { int bit = __ffs(v) - 1; bucket[pos++] = (w << 5) | bit; v &= v - 1; }
  }
  if (lane == 0) ucount[n] = total;
}

// emit compacted edges + zero bcount/bcursor/icnt/icursor/pcnt for next level
__global__ void k_emit(const int* __restrict__ boffs, const int* __restrict__ bucket,
                       const int* __restrict__ bucount, const int* __restrict__ bnoffs,
                       int* __restrict__ srcO, int* __restrict__ dstO,
                       int* __restrict__ b3zero, int* __restrict__ i2zero,
                       int* __restrict__ pcnt) {
  int t = blockIdx.x * 256 + threadIdx.x;
  int stride = gridDim.x * 256;
  for (int z = t; z < 2 * NN; z += stride) { b3zero[z] = 0; i2zero[z] = 0; }
  if (t == 0) *pcnt = 0;
  if (t >= NN) return;
  int u = bucount[t], b = boffs[t], o = bnoffs[t];
  for (int i = 0; i < u; i++) { srcO[o + i] = t; dstO[o + i] = bucket[b + i]; }
}

// ---------------- readout ----------------
__global__ void k_graph_pool(const int* __restrict__ nvb, const int* __restrict__ batch,
                             const float* __restrict__ x, float* __restrict__ gsum,
                             float* __restrict__ gcnt) {
  int t = blockIdx.x * 256 + threadIdx.x;
  int n = t >> 2;
  if (n >= NN) return;
  if (!nvb[n]) return;
  int sub = t & 3;
  int g = batch[n];
  const float* xr = x + (size_t)n * HID + sub * 32;
  float* o = gsum + (size_t)g * HID + sub * 32;
#pragma unroll
  for (int i = 0; i < 8; i++) {
    float4 v = *(const float4*)(xr + i * 4);
    atomicAdd(o + i * 4 + 0, v.x); atomicAdd(o + i * 4 + 1, v.y);
    atomicAdd(o + i * 4 + 2, v.z); atomicAdd(o + i * 4 + 3, v.w);
  }
  if (sub == 0) atomicAdd(&gcnt[g], 1.0f);
}

__global__ __launch_bounds__(128) void k_head1(const float* __restrict__ gsum,
                                               const float* __restrict__ gcnt,
                                               const float* __restrict__ Wf1,
                                               const float* __restrict__ bf1,
                                               float* __restrict__ hfc) {
  int g = blockIdx.x;
  int j = threadIdx.x;
  __shared__ float p[HID];
  float c = fmaxf(gcnt[g], 1.f);
  p[j] = gsum[g * HID + j] / c;
  __syncthreads();
  float s = bf1[j];
  const float* w = Wf1 + (size_t)j * HID;
  for (int k = 0; k < HID; k++) s += p[k] * w[k];
  hfc[g * HID + j] = fmaxf(s, 0.f);
}

__global__ void k_head2(const float* __restrict__ hfc, const float* __restrict__ Wf2,
                        const float* __restrict__ bf2, float* __restrict__ out) {
  int g = blockIdx.x;
  int t = threadIdx.x;
  __shared__ float lg[NC];
  if (t < NC) {
    float s = bf2[t];
    const float* w = Wf2 + (size_t)t * HID;
    const float* h = hfc + (size_t)g * HID;
    for (int k = 0; k < HID; k++) s += h[k] * w[k];
    lg[t] = s;
  }
  __syncthreads();
  if (t == 0) {
    float m = lg[0];
    for (int c = 1; c < NC; c++) m = fmaxf(m, lg[c]);
    float se = 0.f;
    for (int c = 0; c < NC; c++) se += expf(lg[c] - m);
    float lse = m + logf(se);
    for (int c = 0; c < NC; c++) out[g * NC + c] = lg[c] - lse;
  }
}

extern "C" void kernel_launch(void* const* d_in, const int* in_sizes, int n_in,
                              void* d_out, int out_size, void* d_ws, size_t ws_size,
                              hipStream_t stream) {
  const float* x0 = (const float*)d_in[0];
  const int* ei = (const int*)d_in[1];
  const int* batch = (const int*)d_in[2];
  const float* Wl = (const float*)d_in[3];
  const float* bl = (const float*)d_in[4];
  const float* Wr = (const float*)d_in[5];
  const float* gamma = (const float*)d_in[6];
  const float* beta = (const float*)d_in[7];
  const float* Wlin = (const float*)d_in[8];
  const float* blin = (const float*)d_in[9];
  const float* Wp = (const float*)d_in[10];
  const float* bp = (const float*)d_in[11];
  const float* Wf1 = (const float*)d_in[12];
  const float* bf1 = (const float*)d_in[13];
  const float* Wf2 = (const float*)d_in[14];
  const float* bf2 = (const float*)d_in[15];
  float* out = (float*)d_out;

  const int NH = NN * HID;
  size_t off = 0;
  char* base = (char*)d_ws;
  auto carve = [&](size_t bytes) -> char* {
    char* p = base + off;
    off += (bytes + 255) & ~(size_t)255;
    return p;
  };
  float* xa = (float*)carve((size_t)NH * 4);
  float* xb = (float*)carve((size_t)NH * 4);
  float* xc = (float*)carve((size_t)NH * 4);   // ALSO aliased as ielist (same 15.36 MB)
  float* xd = (float*)carve((size_t)NH * 4);
  int* srcA = (int*)carve((size_t)NE * 4);
  int* dstA = (int*)carve((size_t)NE * 4);
  int* srcB = (int*)carve((size_t)NE * 4);
  int* dstB = (int*)carve((size_t)NE * 4);
  float* escore = (float*)carve((size_t)NE * 4);
  int* ebucket = (int*)carve((size_t)NE * 4);
  int* eids = (int*)carve((size_t)NE * 4);
  int* gsrc = (int*)carve((size_t)NE * 4);
  u64* ekey = (u64*)carve((size_t)NE * 8);
  u64* S = (u64*)carve((size_t)NN * 8);
  float* npx1 = (float*)carve((size_t)NN * 4);
  float* npx2 = (float*)carve((size_t)NN * 4);
  int* ncluster = (int*)carve((size_t)NN * 4);
  int* nvb = (int*)carve((size_t)NN * 4);
  int* b3 = (int*)carve((size_t)3 * NN * 4);
  int* bcount = b3;
  int* bcursor = b3 + NN;
  int* bucount = b3 + 2 * NN;
  int* i2 = (int*)carve((size_t)2 * NN * 4);
  int* icnt = i2;
  int* icursor = i2 + NN;
  int* boffs = (int*)carve((size_t)(NN + 1) * 4);
  int* bnoffs = (int*)carve((size_t)(NN + 1) * 4);
  int* csroff = (int*)carve((size_t)(NN + 1) * 4);
  int* ioff = (int*)carve((size_t)(NN + 1) * 4);
  double* bnsum = (double*)carve((size_t)2 * HID * 8);
  float* affa1 = (float*)carve((size_t)HID * 4);
  float* affc1 = (float*)carve((size_t)HID * 4);
  float* affa2 = (float*)carve((size_t)HID * 4);
  float* affc2 = (float*)carve((size_t)HID * 4);
  float* gbuf = (float*)carve((size_t)(NG * HID + NG) * 4);
  float* gsum = gbuf;
  float* gcnt = gbuf + NG * HID;
  float* ghfc = (float*)carve((size_t)NG * HID * 4);
  int* scal = (int*)carve(64 * 4);
  (void)ws_size; (void)n_in; (void)in_sizes; (void)out_size;

  // ielist aliases xc (2*NE*16 B == NH*4 B): xc is dead after the concat gemm
  // and is rewritten next level only after suitor completes.
  int4* ielist = (int4*)xc;

  int* pE = scal;        // E_cur
  int* pcnt = scal + 1;  // valid node count

  k_init<<<1875, 256, 0, stream>>>(ei, srcA, dstA, nvb, scal, b3, i2, gbuf, bnsum);

  int* srcC = srcA; int* dstC = dstA; int* srcN = srcB; int* dstN = dstB;
  float* xcur = xa;
  float* xtmp = xd;

  // sage layer: gather mean_raw, gemm with optional input-side BN affine + fused stats
  auto sage = [&](const float* xin, float* xout, int L, const float* fa, const float* fc) {
    k_sage_gather<<<3750, 256, 0, stream>>>(csroff, gsrc, xin, xtmp);
    gemm_dual2<<<235, 256, 0, stream>>>(xtmp, Wl + (size_t)L * HID * HID, xin,
                                        Wr + (size_t)L * HID * HID, bl + (size_t)L * HID,
                                        xout, NN, HID, 1, nvb, bnsum, 1,
                                        fa, fc, fa, fc, nullptr, nullptr, nullptr);
  };

  for (int b = 0; b < 3; b++) {
    const float* xin = (b == 0) ? x0 : (const float*)xcur;

    // dst-CSR (sage + softmax) + incidence counts
    k_csr_count<<<1875, 256, 0, stream>>>(pE, srcC, dstC, bcount, icnt, nvb, pcnt);
    k_scan2<<<2, 1024, 0, stream>>>(bcount, csroff, icnt, ioff);
    k_csr_scatter<<<1875, 256, 0, stream>>>(pE, srcC, dstC, csroff, bcursor, eids, gsrc);

    sage(xin, xb, 2 * b, nullptr, nullptr);
    k_bnfold<<<1, 128, 0, stream>>>(bnsum, pcnt, gamma + (size_t)(2 * b) * HID,
                                    beta + (size_t)(2 * b) * HID, affa1, affc1);
    sage(xb, xc, 2 * b + 1, affa1, affc1);
    k_bnfold<<<1, 128, 0, stream>>>(bnsum, pcnt, gamma + (size_t)(2 * b + 1) * HID,
                                    beta + (size_t)(2 * b + 1) * HID, affa2, affc2);
    // concat gemm: A1=h2_raw w/ (a2,c2), A2=h_raw w/ (a1,c1); fused node-proj
    gemm_dual2<<<235, 256, 0, stream>>>(xc, Wlin + (size_t)b * HID * 2 * HID, xb,
                                        Wlin + (size_t)b * HID * 2 * HID + HID,
                                        blin + (size_t)b * HID, xcur, NN, 2 * HID, 0,
                                        nvb, bnsum, 0, affa2, affc2, affa1, affc1,
                                        Wp + (size_t)b * 2 * HID, npx1, npx2);

    // ----- edge pooling: softmax scores -> inline-payload incidence -> suitor -----
    k_edge_softmax_seed<<<118, 256, 0, stream>>>(csroff, eids, gsrc, npx1, npx2, bp + b,
                                                 escore, ekey, S);
    k_inc_scatter<<<1875, 256, 0, stream>>>(pE, srcC, dstC, ekey, ioff, icursor, ielist);
    k_suitor<<<30000, 64, 0, stream>>>(ioff, ielist, srcC, dstC, S);
    k_new_x<<<3750, 256, 0, stream>>>(S, srcC, dstC, escore, xcur, xtmp,
                                      ncluster, nvb, b3);

    if (b < 2) {  // level-2 coarse edges are never consumed
      k_bucket_count<<<1875, 256, 0, stream>>>(pE, srcC, ncluster, bcount);
      k_scan<<<1, 1024, 0, stream>>>(bcount, boffs, NN, (int*)nullptr);
      k_bucket_scatter<<<1875, 256, 0, stream>>>(pE, srcC, dstC, ncluster, boffs, bcursor,
                                                 ebucket);
      k_dedup_bitmap<<<7500, 256, 0, stream>>>(boffs, ebucket, bucount);
      k_scan<<<1, 1024, 0, stream>>>(bucount, bnoffs, NN, pE);
      k_emit<<<235, 256, 0, stream>>>(boffs, ebucket, bucount, bnoffs, srcN, dstN,
                                      b3, i2, pcnt);
      { int* t = srcC; srcC = srcN; srcN = t; t = dstC; dstC = dstN; dstN = t; }
    }
    { float* t = xcur; xcur = xtmp; xtmp = t; }
  }

  k_graph_pool<<<469, 256, 0, stream>>>(nvb, batch, xcur, gsum, gcnt);
  k_head1<<<NG, 128, 0, stream>>>(gsum, gcnt, Wf1, bf1, ghfc);
  k_head2<<<NG, 32, 0, stream>>>(ghfc, Wf2, bf2, out);
}

// Round 12
// 2503.881 us; speedup vs baseline: 19.7312x; 1.0087x over previous
//
#include <hip/hip_runtime.h>
#include <stdint.h>

#define NN 30000
#define NE 480000
#define HID 128
#define NG 128
#define NC 6
#define BN_EPS 1e-5f
#define WPB 938   // ceil(NN/32) bitmap words
#define SLOTS 4   // reg-resident suitor entries per lane (deg <= 256)
#define GPAD 132

typedef unsigned int u32;
typedef unsigned long long u64;

__device__ __forceinline__ u64 ent_key(int4 ent) {
  return ((u64)(u32)ent.y << 32) | (u32)ent.x;
}

// ---------------- init (also zeroes all per-call state) ----------------
__global__ void k_init(const int* __restrict__ ei, int* srcA, int* dstA, int* nvb,
                       int* scal, int* b3, int* i2, float* gbuf,
                       double* __restrict__ bnsum) {
  int t = blockIdx.x * 256 + threadIdx.x;
  if (t < NE) { srcA[t] = ei[t]; dstA[t] = ei[NE + t]; }
  if (t < NN) nvb[t] = 1;
  if (t < 2 * NN) { b3[t] = 0; i2[t] = 0; }   // bcount,bcursor + icnt,icursor
  if (t < NG * HID + NG) gbuf[t] = 0.f;
  if (t < 2 * HID) bnsum[t] = 0.0;
  if (t == 0) { scal[0] = NE; scal[1] = 0; }
}

// ---------------- CSR build (dst CSR + incidence counts) + valid-node count ----------------
__global__ void k_csr_count(const int* __restrict__ pE, const int* __restrict__ src,
                            const int* __restrict__ dst, int* __restrict__ cnt,
                            int* __restrict__ icnt, const int* __restrict__ nvb,
                            int* __restrict__ pcnt) {
  int t = blockIdx.x * 256 + threadIdx.x;
  if (t < NN && nvb[t]) atomicAdd(pcnt, 1);
  if (t < *pE) {
    int s = src[t], d = dst[t];
    atomicAdd(&cnt[d], 1);
    if (s != d) { atomicAdd(&icnt[s], 1); atomicAdd(&icnt[d], 1); }
  }
}

// two independent single-block scans (block 0: dst-CSR, block 1: incidence)
__global__ __launch_bounds__(1024) void k_scan2(const int* __restrict__ in0, int* __restrict__ out0,
                                                const int* __restrict__ in1, int* __restrict__ out1) {
  const int* in = blockIdx.x ? in1 : in0;
  int* out = blockIdx.x ? out1 : out0;
  __shared__ int part[1024];
  int t = threadIdx.x;
  int chunk = (NN + 1023) / 1024;
  int b = t * chunk, e = b + chunk;
  if (b > NN) b = NN;
  if (e > NN) e = NN;
  int s = 0;
  for (int i = b; i < e; i++) s += in[i];
  part[t] = s;
  __syncthreads();
  for (int off = 1; off < 1024; off <<= 1) {
    int v = (t >= off) ? part[t - off] : 0;
    __syncthreads();
    part[t] += v;
    __syncthreads();
  }
  int excl = (t == 0) ? 0 : part[t - 1];
  for (int i = b; i < e; i++) { out[i] = excl; excl += in[i]; }
  if (t == 0) out[NN] = part[1023];
}

// writes eids (edge id) AND gsrc (resolved src node)
__global__ void k_csr_scatter(const int* __restrict__ pE, const int* __restrict__ src,
                              const int* __restrict__ dst, const int* __restrict__ coff,
                              int* __restrict__ cursor, int* __restrict__ eids,
                              int* __restrict__ gsrc) {
  int e = blockIdx.x * 256 + threadIdx.x;
  if (e >= *pE) return;
  int d = dst[e];
  int pos = coff[d] + atomicAdd(&cursor[d], 1);
  eids[pos] = e;
  gsrc[pos] = src[e];
}

// ---------------- SAGE mean aggregation: CSR gather, 32 lanes/node ----------------
__global__ __launch_bounds__(256) void k_sage_gather(
    const int* __restrict__ coff, const int* __restrict__ gsrc,
    const float* __restrict__ x, float* __restrict__ mean) {
  int grp = threadIdx.x >> 5;           // 8 nodes per block
  int lane = threadIdx.x & 31;
  int n = blockIdx.x * 8 + grp;
  if (n >= NN) return;
  int b = coff[n], e2 = coff[n + 1];
  float4 acc = make_float4(0.f, 0.f, 0.f, 0.f);
  int i = b;
  for (; i + 1 < e2; i += 2) {
    int s0 = gsrc[i], s1 = gsrc[i + 1];
    float4 v0 = *(const float4*)(x + (size_t)s0 * HID + lane * 4);
    float4 v1 = *(const float4*)(x + (size_t)s1 * HID + lane * 4);
    acc.x += v0.x; acc.y += v0.y; acc.z += v0.z; acc.w += v0.w;
    acc.x += v1.x; acc.y += v1.y; acc.z += v1.z; acc.w += v1.w;
  }
  if (i < e2) {
    int s0 = gsrc[i];
    float4 v0 = *(const float4*)(x + (size_t)s0 * HID + lane * 4);
    acc.x += v0.x; acc.y += v0.y; acc.z += v0.z; acc.w += v0.w;
  }
  float inv = 1.0f / fmaxf((float)(e2 - b), 1.0f);
  acc.x *= inv; acc.y *= inv; acc.z *= inv; acc.w *= inv;
  *(float4*)(mean + (size_t)n * HID + lane * 4) = acc;
}

// out[n][0:128] = BNaff(A1)@W1^T + BNaff(A2)@W2^T + bias; optional relu;
// optional fused BN stats; optional fused node-proj (px = out-row . Wp).
__global__ __launch_bounds__(256) void gemm_dual2(
    const float* __restrict__ A1, const float* __restrict__ W1,
    const float* __restrict__ A2, const float* __restrict__ W2,
    const float* __restrict__ bias, float* __restrict__ out,
    int M, int ldw, int relu, const int* __restrict__ nvb,
    double* __restrict__ bnsum, int dostats,
    const float* __restrict__ a1f, const float* __restrict__ c1f,
    const float* __restrict__ a2f, const float* __restrict__ c2f,
    const float* __restrict__ Wp, float* __restrict__ px1, float* __restrict__ px2) {
  __shared__ float Ast[16][GPAD];   // [kk][row]
  __shared__ float Ws[16][GPAD];    // [kk][col]
  int tid = threadIdx.x;
  int rg = tid >> 4, cg = tid & 15;
  int r0 = rg * 8, c0 = cg * 8;
  int row0 = blockIdx.x * 128;
  float acc[8][8];
#pragma unroll
  for (int a = 0; a < 8; a++)
#pragma unroll
    for (int bq = 0; bq < 8; bq++) acc[a][bq] = 0.f;

  for (int srcI = 0; srcI < 2; srcI++) {
    const float* A = srcI ? A2 : A1;
    const float* W = srcI ? W2 : W1;
    const float* fa = srcI ? a2f : a1f;
    const float* fc = srcI ? c2f : c1f;
    for (int kc = 0; kc < 128; kc += 16) {
#pragma unroll
      for (int i = 0; i < 2; i++) {
        int k = tid + i * 256;
        int r = k >> 2, c4 = (k & 3) << 2;
        int gr = row0 + r;
        float4 v = make_float4(0.f, 0.f, 0.f, 0.f);
        if (gr < M) v = *(const float4*)(A + (size_t)gr * 128 + kc + c4);
        if (fa) {
          float4 av = *(const float4*)(fa + kc + c4);
          float4 cv = *(const float4*)(fc + kc + c4);
          v.x = v.x * av.x + cv.x; v.y = v.y * av.y + cv.y;
          v.z = v.z * av.z + cv.z; v.w = v.w * av.w + cv.w;
        }
        Ast[c4 + 0][r] = v.x; Ast[c4 + 1][r] = v.y;
        Ast[c4 + 2][r] = v.z; Ast[c4 + 3][r] = v.w;
        float4 w = *(const float4*)(W + (size_t)r * ldw + kc + c4);
        Ws[c4 + 0][r] = w.x; Ws[c4 + 1][r] = w.y;
        Ws[c4 + 2][r] = w.z; Ws[c4 + 3][r] = w.w;
      }
      __syncthreads();
#pragma unroll
      for (int kk = 0; kk < 16; kk++) {
        float4 a0 = *(const float4*)(&Ast[kk][r0]);
        float4 a1 = *(const float4*)(&Ast[kk][r0 + 4]);
        float4 b0 = *(const float4*)(&Ws[kk][c0]);
        float4 b1 = *(const float4*)(&Ws[kk][c0 + 4]);
        float av[8] = {a0.x, a0.y, a0.z, a0.w, a1.x, a1.y, a1.z, a1.w};
        float bv[8] = {b0.x, b0.y, b0.z, b0.w, b1.x, b1.y, b1.z, b1.w};
#pragma unroll
        for (int rr = 0; rr < 8; rr++)
#pragma unroll
          for (int cc = 0; cc < 8; cc++) acc[rr][cc] += av[rr] * bv[cc];
      }
      __syncthreads();
    }
  }

  float wp1[8], wp2[8];
  if (Wp) {
#pragma unroll
    for (int cc = 0; cc < 8; cc++) { wp1[cc] = Wp[c0 + cc]; wp2[cc] = Wp[HID + c0 + cc]; }
  }
  float* part1 = (float*)Ast;   // [row][cg] overlay (proj); stats uses Ast too
  float* part2 = (float*)Ws;    // (dostats and Wp are never both set)
  float sCol[8], qCol[8];
#pragma unroll
  for (int cc = 0; cc < 8; cc++) { sCol[cc] = 0.f; qCol[cc] = 0.f; }
#pragma unroll
  for (int rr = 0; rr < 8; rr++) {
    int gr = row0 + r0 + rr;
    float p1 = 0.f, p2 = 0.f;
    if (gr < M) {
      int valid = dostats ? nvb[gr] : 0;
      float vv[8];
#pragma unroll
      for (int cc = 0; cc < 8; cc++) {
        float v = acc[rr][cc] + bias[c0 + cc];
        if (relu) v = fmaxf(v, 0.f);
        vv[cc] = v;
        if (valid) { sCol[cc] += v; qCol[cc] += v * v; }
        if (Wp) { p1 += v * wp1[cc]; p2 += v * wp2[cc]; }
      }
      *(float4*)(out + (size_t)gr * 128 + c0) = make_float4(vv[0], vv[1], vv[2], vv[3]);
      *(float4*)(out + (size_t)gr * 128 + c0 + 4) = make_float4(vv[4], vv[5], vv[6], vv[7]);
    }
    if (Wp) { part1[(r0 + rr) * 16 + cg] = p1; part2[(r0 + rr) * 16 + cg] = p2; }
  }
  if (Wp) {
    __syncthreads();
    if (tid < HID && row0 + tid < M) {
      float s1 = 0.f, s2 = 0.f;
#pragma unroll
      for (int g = 0; g < 16; g++) { s1 += part1[tid * 16 + g]; s2 += part2[tid * 16 + g]; }
      px1[row0 + tid] = s1;
      px2[row0 + tid] = s2;
    }
  }
  if (dostats) {
#pragma unroll
    for (int cc = 0; cc < 8; cc++) { Ast[rg][c0 + cc] = sCol[cc]; Ws[rg][c0 + cc] = qCol[cc]; }
    __syncthreads();
    if (tid < HID) {
      float s = 0.f, q = 0.f;
#pragma unroll
      for (int g = 0; g < 16; g++) { s += Ast[g][tid]; q += Ws[g][tid]; }
      atomicAdd(&bnsum[tid], (double)s);
      atomicAdd(&bnsum[HID + tid], (double)q);
    }
  }
}

// tiny: BN affine (a,c) from fused stats; re-zeroes bnsum for next stats gemm
__global__ void k_bnfold(double* __restrict__ bnsum, const int* __restrict__ cnt,
                         const float* __restrict__ gamma, const float* __restrict__ beta,
                         float* __restrict__ affa, float* __restrict__ affc) {
  int k = threadIdx.x;
  double c = (double)((*cnt > 1) ? *cnt : 1);
  double mu = bnsum[k] / c;
  double var = bnsum[HID + k] / c - mu * mu;
  if (var < 0.0) var = 0.0;
  double inv = 1.0 / sqrt(var + (double)BN_EPS);
  double a = (double)gamma[k] * inv;
  affa[k] = (float)a;
  affc[k] = (float)((double)beta[k] - mu * a);
  bnsum[k] = 0.0;
  bnsum[HID + k] = 0.0;
}

// fused: S init + per-dst softmax + suitor keys
__global__ void k_edge_softmax_seed(
    const int* __restrict__ coff, const int* __restrict__ eids,
    const int* __restrict__ gsrc, const float* __restrict__ px1,
    const float* __restrict__ px2, const float* __restrict__ bp,
    float* __restrict__ score, u64* __restrict__ ekey, u64* __restrict__ S) {
  int n = blockIdx.x * 256 + threadIdx.x;
  if (n >= NN) return;
  S[n] = 0ull;
  int b = coff[n], e2 = coff[n + 1];
  if (b == e2) return;
  float p2 = px2[n] + *bp;
  float mx = -3.4e38f;
  for (int i = b; i < e2; i++) {
    float r = px1[gsrc[i]] + p2;
    mx = fmaxf(mx, r);
  }
  double den = 0.0;
  for (int i = b; i < e2; i++) {
    int eid = eids[i];
    float z = expf(px1[gsrc[i]] + p2 - mx);
    score[eid] = z;
    den += (double)z;
  }
  if (den < 1e-16) den = 1e-16;
  double invd = 1.0 / den;
  for (int i = b; i < e2; i++) {
    int eid = eids[i];
    float sc = (float)((double)score[eid] * invd) + 0.5f;
    score[eid] = sc;
    ekey[eid] = ((u64)__float_as_uint(sc) << 32) | (u64)(0xFFFFFFFFu - (u32)eid);
  }
}

// incidence scatter with INLINE payload {key, partner}
__global__ void k_inc_scatter(const int* __restrict__ pE, const int* __restrict__ src,
                              const int* __restrict__ dst, const u64* __restrict__ ekey,
                              const int* __restrict__ ioff, int* __restrict__ icur,
                              int4* __restrict__ ielist) {
  int e = blockIdx.x * 256 + threadIdx.x;
  if (e >= *pE) return;
  int s = src[e], d = dst[e];
  if (s == d) return;
  u64 k = ekey[e];
  int4 ent;
  ent.x = (int)(u32)(k & 0xFFFFFFFFull);
  ent.y = (int)(u32)(k >> 32);
  ent.w = 0;
  ent.z = d;
  ielist[ioff[s] + atomicAdd(&icur[s], 1)] = ent;
  ent.z = s;
  ielist[ioff[d] + atomicAdd(&icur[d], 1)] = ent;
}

// ---------------- Suitor matching, wave-per-node, register-resident ----------------
// REVERTED to the round-10 measured-best config: 256-thr blocks (4 waves,
// wave-per-node), prune pass inside the retry loop (cheap relaxed S-loads kill
// dead slots before each RMW). Round-11's 64-thr blocks + prune-once variant
// REGRESSED 190->230 us/level (WRITE_SIZE 1.46->3.2 MB: more failed atomicMax).
__global__ __launch_bounds__(256) void k_suitor(
    const int* __restrict__ ioff, const int4* __restrict__ ielist,
    const int* __restrict__ src, const int* __restrict__ dst,
    u64* __restrict__ S) {
  int wid = threadIdx.x >> 6;
  int lane = threadIdx.x & 63;
  int n = blockIdx.x * 4 + wid;
  if (n >= NN) return;
  int cur = n;
  while (cur >= 0) {
    int b = ioff[cur], e2 = ioff[cur + 1];
    int deg = e2 - b;
    if (deg == 0) break;
    if (deg <= 64 * SLOTS) {
      u64 key[SLOTS]; int pv[SLOTS];
#pragma unroll
      for (int s = 0; s < SLOTS; s++) {
        key[s] = 0; pv[s] = 0;
        int i = b + s * 64 + lane;
        if (i < e2) {
          int4 ent = ielist[i];
          key[s] = ent_key(ent);
          pv[s] = ent.z;
        }
      }
      long long res;
      for (;;) {
        u64 localBest = 0;
#pragma unroll
        for (int s = 0; s < SLOTS; s++) {
          if (!key[s]) continue;
          u64 sv = __hip_atomic_load(&S[pv[s]], __ATOMIC_RELAXED, __HIP_MEMORY_SCOPE_AGENT);
          if (sv >= key[s]) key[s] = 0;              // permanently dead
          else if (key[s] > localBest) localBest = key[s];
        }
        u64 bestKey = localBest;
#pragma unroll
        for (int o = 32; o > 0; o >>= 1) {
          u64 other = __shfl_xor(bestKey, o, 64);
          if (other > bestKey) bestKey = other;
        }
        if (bestKey == 0) { res = -1; break; }
        int ms = -1;
#pragma unroll
        for (int s = 0; s < SLOTS; s++)
          if (ms < 0 && key[s] == bestKey) ms = s;
        u64 ball = __ballot(ms >= 0);
        int owner = (int)(__ffsll((long long)ball) - 1);
        long long r0 = -3;
        if (lane == owner) {
          int bv = pv[ms];
          u64 old = atomicMax(&S[bv], bestKey);
          if (old >= bestKey) { key[ms] = 0; r0 = -2; }   // lost race; retry cur
          else if (old == 0) r0 = -1;                     // accepted, chain ends
          else {
            int eo = (int)(0xFFFFFFFFu - (u32)(old & 0xFFFFFFFFull));
            int so = src[eo], do_ = dst[eo];
            r0 = (so == bv) ? do_ : so;                   // displaced re-seeks
          }
        }
        res = __shfl(r0, owner, 64);
        if (res != -2) break;
      }
      if (res < 0) break;
      cur = (int)res;
    } else {
      u64 bestKey = 0;
      for (int i = b + lane; i < e2; i += 64) {
        int4 ent = ielist[i];
        u64 k = ent_key(ent);
        if (k <= bestKey) continue;
        u64 sv = __hip_atomic_load(&S[ent.z], __ATOMIC_RELAXED, __HIP_MEMORY_SCOPE_AGENT);
        if (k > sv) bestKey = k;
      }
#pragma unroll
      for (int o = 32; o > 0; o >>= 1) {
        u64 other = __shfl_xor(bestKey, o, 64);
        if (other > bestKey) bestKey = other;
      }
      long long r0 = -1;
      if (bestKey != 0 && lane == 0) {
        int e = (int)(0xFFFFFFFFu - (u32)(bestKey & 0xFFFFFFFFull));
        int es = src[e], ed = dst[e];
        int bv = (es == cur) ? ed : es;
        u64 old = atomicMax(&S[bv], bestKey);
        if (old >= bestKey) r0 = cur;
        else if (old != 0) {
          int eo = (int)(0xFFFFFFFFu - (u32)(old & 0xFFFFFFFFull));
          int so = src[eo], do_ = dst[eo];
          r0 = (so == bv) ? do_ : so;
        }
      }
      long long res = (bestKey != 0) ? __shfl(r0, 0, 64) : -1;
      cur = (int)res;
    }
  }
}

// new_x gather + cluster derivation from S + nvb update + zero b3
__global__ __launch_bounds__(256) void k_new_x(
    const u64* __restrict__ S, const int* __restrict__ src, const int* __restrict__ dst,
    const float* __restrict__ score, const float* __restrict__ x,
    float* __restrict__ out, int* __restrict__ cluster,
    int* __restrict__ nvb, int* __restrict__ b3zero) {
  int gt = blockIdx.x * 256 + threadIdx.x;
  if (gt < 2 * NN) b3zero[gt] = 0;
  int grp = threadIdx.x >> 5;
  int lane = threadIdx.x & 31;
  int n = blockIdx.x * 8 + grp;
  if (n >= NN) return;
  u64 k = S[n];
  int partner = -1;
  int rep = n;
  bool isOth = false;
  float sc = 1.f;
  if (k) {
    int e = (int)(0xFFFFFFFFu - (u32)(k & 0xFFFFFFFFull));
    int s = src[e], d = dst[e];
    int other = (s == n) ? d : s;
    if (S[other] == k) {
      if (n > other) { isOth = true; rep = other; }
      else { partner = other; sc = score[e]; }
    }
  }
  float4 v = make_float4(0.f, 0.f, 0.f, 0.f);
  if (!isOth) {
    v = *(const float4*)(x + (size_t)n * HID + lane * 4);
    if (partner >= 0) {
      float4 w = *(const float4*)(x + (size_t)partner * HID + lane * 4);
      v.x = (v.x + w.x) * sc; v.y = (v.y + w.y) * sc;
      v.z = (v.z + w.z) * sc; v.w = (v.w + w.w) * sc;
    }
  }
  *(float4*)(out + (size_t)n * HID + lane * 4) = v;
  if (lane == 0) {
    cluster[n] = rep;
    nvb[n] = (nvb[n] && !isOth) ? 1 : 0;
  }
}

// ---------------- dedup (sorted unique of (cs,cd)) ----------------
__global__ void k_bucket_count(const int* __restrict__ pE, const int* __restrict__ src,
                               const int* __restrict__ cluster, int* __restrict__ bcount) {
  int e = blockIdx.x * 256 + threadIdx.x;
  if (e >= *pE) return;
  atomicAdd(&bcount[cluster[src[e]]], 1);
}

__global__ __launch_bounds__(1024) void k_scan(const int* __restrict__ in, int* __restrict__ out,
                                               int n, int* totalDst) {
  __shared__ int part[1024];
  int t = threadIdx.x;
  int chunk = (n + 1023) / 1024;
  int b = t * chunk, e = b + chunk;
  if (b > n) b = n;
  if (e > n) e = n;
  int s = 0;
  for (int i = b; i < e; i++) s += in[i];
  part[t] = s;
  __syncthreads();
  for (int off = 1; off < 1024; off <<= 1) {
    int v = (t >= off) ? part[t - off] : 0;
    __syncthreads();
    part[t] += v;
    __syncthreads();
  }
  int excl = (t == 0) ? 0 : part[t - 1];
  int total = part[1023];
  for (int i = b; i < e; i++) { out[i] = excl; excl += in[i]; }
  if (t == 0) {
    out[n] = total;
    if (totalDst) *totalDst = total;
  }
}

__global__ void k_bucket_scatter(const int* __restrict__ pE, const int* __restrict__ src,
                                 const int* __restrict__ dst, const int* __restrict__ cluster,
                                 const int* __restrict__ boffs, int* __restrict__ bcursor,
                                 int* __restrict__ bucket) {
  int e = blockIdx.x * 256 + threadIdx.x;
  if (e >= *pE) return;
  int cs = cluster[src[e]], cd = cluster[dst[e]];
  int pos = boffs[cs] + atomicAdd(&bcursor[cs], 1);
  bucket[pos] = cd;
}

// sorted-unique per bucket via per-wave LDS bitmap
__global__ __launch_bounds__(256) void k_dedup_bitmap(
    const int* __restrict__ boffs, int* __restrict__ bucket,
    int* __restrict__ ucount) {
  __shared__ u32 bm[4][960];
  int wid = threadIdx.x >> 6;
  int lane = threadIdx.x & 63;
  int n = blockIdx.x * 4 + wid;
  int b = boffs[n], e = boffs[n + 1];
  for (int w = lane; w < 960; w += 64) bm[wid][w] = 0;
  __syncthreads();
  for (int i = b + lane; i < e; i += 64)
    atomicOr(&bm[wid][bucket[i] >> 5], 1u << (bucket[i] & 31));
  __syncthreads();
  int w0 = lane * 15;
  int w1 = w0 + 15; if (w1 > WPB) w1 = WPB;
  int cnt = 0;
  for (int w = w0; w < w1; w++) cnt += __popc(bm[wid][w]);
  int inc = cnt;
  for (int o = 1; o < 64; o <<= 1) { int v = __shfl_up(inc, o); if (lane >= o) inc += v; }
  int excl = inc - cnt;
  int total = __shfl(inc, 63);
  int pos = b + excl;
  for (int w = w0; w < w1; w++) {
    u32 v = bm[wid][w];
    while (v) { int bit = __ffs(v) - 1; bucket[pos++] = (w << 5) | bit; v &= v - 1; }
  }
  if (lane == 0) ucount[n] = total;
}

// emit compacted edges + zero bcount/bcursor/icnt/icursor/pcnt for next level
__global__ void k_emit(const int* __restrict__ boffs, const int* __restrict__ bucket,
                       const int* __restrict__ bucount, const int* __restrict__ bnoffs,
                       int* __restrict__ srcO, int* __restrict__ dstO,
                       int* __restrict__ b3zero, int* __restrict__ i2zero,
                       int* __restrict__ pcnt) {
  int t = blockIdx.x * 256 + threadIdx.x;
  int stride = gridDim.x * 256;
  for (int z = t; z < 2 * NN; z += stride) { b3zero[z] = 0; i2zero[z] = 0; }
  if (t == 0) *pcnt = 0;
  if (t >= NN) return;
  int u = bucount[t], b = boffs[t], o = bnoffs[t];
  for (int i = 0; i < u; i++) { srcO[o + i] = t; dstO[o + i] = bucket[b + i]; }
}

// ---------------- readout ----------------
__global__ void k_graph_pool(const int* __restrict__ nvb, const int* __restrict__ batch,
                             const float* __restrict__ x, float* __restrict__ gsum,
                             float* __restrict__ gcnt) {
  int t = blockIdx.x * 256 + threadIdx.x;
  int n = t >> 2;
  if (n >= NN) return;
  if (!nvb[n]) return;
  int sub = t & 3;
  int g = batch[n];
  const float* xr = x + (size_t)n * HID + sub * 32;
  float* o = gsum + (size_t)g * HID + sub * 32;
#pragma unroll
  for (int i = 0; i < 8; i++) {
    float4 v = *(const float4*)(xr + i * 4);
    atomicAdd(o + i * 4 + 0, v.x); atomicAdd(o + i * 4 + 1, v.y);
    atomicAdd(o + i * 4 + 2, v.z); atomicAdd(o + i * 4 + 3, v.w);
  }
  if (sub == 0) atomicAdd(&gcnt[g], 1.0f);
}

__global__ __launch_bounds__(128) void k_head1(const float* __restrict__ gsum,
                                               const float* __restrict__ gcnt,
                                               const float* __restrict__ Wf1,
                                               const float* __restrict__ bf1,
                                               float* __restrict__ hfc) {
  int g = blockIdx.x;
  int j = threadIdx.x;
  __shared__ float p[HID];
  float c = fmaxf(gcnt[g], 1.f);
  p[j] = gsum[g * HID + j] / c;
  __syncthreads();
  float s = bf1[j];
  const float* w = Wf1 + (size_t)j * HID;
  for (int k = 0; k < HID; k++) s += p[k] * w[k];
  hfc[g * HID + j] = fmaxf(s, 0.f);
}

__global__ void k_head2(const float* __restrict__ hfc, const float* __restrict__ Wf2,
                        const float* __restrict__ bf2, float* __restrict__ out) {
  int g = blockIdx.x;
  int t = threadIdx.x;
  __shared__ float lg[NC];
  if (t < NC) {
    float s = bf2[t];
    const float* w = Wf2 + (size_t)t * HID;
    const float* h = hfc + (size_t)g * HID;
    for (int k = 0; k < HID; k++) s += h[k] * w[k];
    lg[t] = s;
  }
  __syncthreads();
  if (t == 0) {
    float m = lg[0];
    for (int c = 1; c < NC; c++) m = fmaxf(m, lg[c]);
    float se = 0.f;
    for (int c = 0; c < NC; c++) se += expf(lg[c] - m);
    float lse = m + logf(se);
    for (int c = 0; c < NC; c++) out[g * NC + c] = lg[c] - lse;
  }
}

extern "C" void kernel_launch(void* const* d_in, const int* in_sizes, int n_in,
                              void* d_out, int out_size, void* d_ws, size_t ws_size,
                              hipStream_t stream) {
  const float* x0 = (const float*)d_in[0];
  const int* ei = (const int*)d_in[1];
  const int* batch = (const int*)d_in[2];
  const float* Wl = (const float*)d_in[3];
  const float* bl = (const float*)d_in[4];
  const float* Wr = (const float*)d_in[5];
  const float* gamma = (const float*)d_in[6];
  const float* beta = (const float*)d_in[7];
  const float* Wlin = (const float*)d_in[8];
  const float* blin = (const float*)d_in[9];
  const float* Wp = (const float*)d_in[10];
  const float* bp = (const float*)d_in[11];
  const float* Wf1 = (const float*)d_in[12];
  const float* bf1 = (const float*)d_in[13];
  const float* Wf2 = (const float*)d_in[14];
  const float* bf2 = (const float*)d_in[15];
  float* out = (float*)d_out;

  const int NH = NN * HID;
  size_t off = 0;
  char* base = (char*)d_ws;
  auto carve = [&](size_t bytes) -> char* {
    char* p = base + off;
    off += (bytes + 255) & ~(size_t)255;
    return p;
  };
  float* xa = (float*)carve((size_t)NH * 4);
  float* xb = (float*)carve((size_t)NH * 4);
  float* xc = (float*)carve((size_t)NH * 4);   // ALSO aliased as ielist (same 15.36 MB)
  float* xd = (float*)carve((size_t)NH * 4);
  int* srcA = (int*)carve((size_t)NE * 4);
  int* dstA = (int*)carve((size_t)NE * 4);
  int* srcB = (int*)carve((size_t)NE * 4);
  int* dstB = (int*)carve((size_t)NE * 4);
  float* escore = (float*)carve((size_t)NE * 4);
  int* ebucket = (int*)carve((size_t)NE * 4);
  int* eids = (int*)carve((size_t)NE * 4);
  int* gsrc = (int*)carve((size_t)NE * 4);
  u64* ekey = (u64*)carve((size_t)NE * 8);
  u64* S = (u64*)carve((size_t)NN * 8);
  float* npx1 = (float*)carve((size_t)NN * 4);
  float* npx2 = (float*)carve((size_t)NN * 4);
  int* ncluster = (int*)carve((size_t)NN * 4);
  int* nvb = (int*)carve((size_t)NN * 4);
  int* b3 = (int*)carve((size_t)3 * NN * 4);
  int* bcount = b3;
  int* bcursor = b3 + NN;
  int* bucount = b3 + 2 * NN;
  int* i2 = (int*)carve((size_t)2 * NN * 4);
  int* icnt = i2;
  int* icursor = i2 + NN;
  int* boffs = (int*)carve((size_t)(NN + 1) * 4);
  int* bnoffs = (int*)carve((size_t)(NN + 1) * 4);
  int* csroff = (int*)carve((size_t)(NN + 1) * 4);
  int* ioff = (int*)carve((size_t)(NN + 1) * 4);
  double* bnsum = (double*)carve((size_t)2 * HID * 8);
  float* affa1 = (float*)carve((size_t)HID * 4);
  float* affc1 = (float*)carve((size_t)HID * 4);
  float* affa2 = (float*)carve((size_t)HID * 4);
  float* affc2 = (float*)carve((size_t)HID * 4);
  float* gbuf = (float*)carve((size_t)(NG * HID + NG) * 4);
  float* gsum = gbuf;
  float* gcnt = gbuf + NG * HID;
  float* ghfc = (float*)carve((size_t)NG * HID * 4);
  int* scal = (int*)carve(64 * 4);
  (void)ws_size; (void)n_in; (void)in_sizes; (void)out_size;

  // ielist aliases xc (2*NE*16 B == NH*4 B): xc is dead after the concat gemm
  // and is rewritten next level only after suitor completes.
  int4* ielist = (int4*)xc;

  int* pE = scal;        // E_cur
  int* pcnt = scal + 1;  // valid node count

  k_init<<<1875, 256, 0, stream>>>(ei, srcA, dstA, nvb, scal, b3, i2, gbuf, bnsum);

  int* srcC = srcA; int* dstC = dstA; int* srcN = srcB; int* dstN = dstB;
  float* xcur = xa;
  float* xtmp = xd;

  // sage layer: gather mean_raw, gemm with optional input-side BN affine + fused stats
  auto sage = [&](const float* xin, float* xout, int L, const float* fa, const float* fc) {
    k_sage_gather<<<3750, 256, 0, stream>>>(csroff, gsrc, xin, xtmp);
    gemm_dual2<<<235, 256, 0, stream>>>(xtmp, Wl + (size_t)L * HID * HID, xin,
                                        Wr + (size_t)L * HID * HID, bl + (size_t)L * HID,
                                        xout, NN, HID, 1, nvb, bnsum, 1,
                                        fa, fc, fa, fc, nullptr, nullptr, nullptr);
  };

  for (int b = 0; b < 3; b++) {
    const float* xin = (b == 0) ? x0 : (const float*)xcur;

    // dst-CSR (sage + softmax) + incidence counts
    k_csr_count<<<1875, 256, 0, stream>>>(pE, srcC, dstC, bcount, icnt, nvb, pcnt);
    k_scan2<<<2, 1024, 0, stream>>>(bcount, csroff, icnt, ioff);
    k_csr_scatter<<<1875, 256, 0, stream>>>(pE, srcC, dstC, csroff, bcursor, eids, gsrc);

    sage(xin, xb, 2 * b, nullptr, nullptr);
    k_bnfold<<<1, 128, 0, stream>>>(bnsum, pcnt, gamma + (size_t)(2 * b) * HID,
                                    beta + (size_t)(2 * b) * HID, affa1, affc1);
    sage(xb, xc, 2 * b + 1, affa1, affc1);
    k_bnfold<<<1, 128, 0, stream>>>(bnsum, pcnt, gamma + (size_t)(2 * b + 1) * HID,
                                    beta + (size_t)(2 * b + 1) * HID, affa2, affc2);
    // concat gemm: A1=h2_raw w/ (a2,c2), A2=h_raw w/ (a1,c1); fused node-proj
    gemm_dual2<<<235, 256, 0, stream>>>(xc, Wlin + (size_t)b * HID * 2 * HID, xb,
                                        Wlin + (size_t)b * HID * 2 * HID + HID,
                                        blin + (size_t)b * HID, xcur, NN, 2 * HID, 0,
                                        nvb, bnsum, 0, affa2, affc2, affa1, affc1,
                                        Wp + (size_t)b * 2 * HID, npx1, npx2);

    // ----- edge pooling: softmax scores -> inline-payload incidence -> suitor -----
    k_edge_softmax_seed<<<118, 256, 0, stream>>>(csroff, eids, gsrc, npx1, npx2, bp + b,
                                                 escore, ekey, S);
    k_inc_scatter<<<1875, 256, 0, stream>>>(pE, srcC, dstC, ekey, ioff, icursor, ielist);
    k_suitor<<<7500, 256, 0, stream>>>(ioff, ielist, srcC, dstC, S);
    k_new_x<<<3750, 256, 0, stream>>>(S, srcC, dstC, escore, xcur, xtmp,
                                      ncluster, nvb, b3);

    if (b < 2) {  // level-2 coarse edges are never consumed
      k_bucket_count<<<1875, 256, 0, stream>>>(pE, srcC, ncluster, bcount);
      k_scan<<<1, 1024, 0, stream>>>(bcount, boffs, NN, (int*)nullptr);
      k_bucket_scatter<<<1875, 256, 0, stream>>>(pE, srcC, dstC, ncluster, boffs, bcursor,
                                                 ebucket);
      k_dedup_bitmap<<<7500, 256, 0, stream>>>(boffs, ebucket, bucount);
      k_scan<<<1, 1024, 0, stream>>>(bucount, bnoffs, NN, pE);
      k_emit<<<235, 256, 0, stream>>>(boffs, ebucket, bucount, bnoffs, srcN, dstN,
                                      b3, i2, pcnt);
      { int* t = srcC; srcC = srcN; srcN = t; t = dstC; dstC = dstN; dstN = t; }
    }
    { float* t = xcur; xcur = xtmp; xtmp = t; }
  }

  k_graph_pool<<<469, 256, 0, stream>>>(nvb, batch, xcur, gsum, gcnt);
  k_head1<<<NG, 128, 0, stream>>>(gsum, gcnt, Wf1, bf1, ghfc);
  k_head2<<<NG, 32, 0, stream>>>(ghfc, Wf2, bf2, out);
}